// Round 1
// baseline (878.952 us; speedup 1.0000x reference)
//
#include <hip/hip_runtime.h>
#include <math.h>

// ---------------------------------------------------------------------------
// FNO-GNO, fp32 reference-faithful implementation.
// G=32, HID=64, M=8 (16 kept modes/axis, 8 in rfft axis), NL=4, NPTS=16384.
//
// Key algorithmic points:
//  * rfftn/irfftn replaced by partial DFTs on the 2048 kept modes only.
//  * irfft semantics: out[z] = Re(g[0]) + sum_{kz=1..7} 2*Re(g[kz] e^{+i th})
//    (imag of kz=0 plane discarded, kz>=8 zero), after exact complex ifft
//    along x and y on the 16 kept (corner) modes per axis.
//  * GNO: compact active edges (d2 <= R^2, in-bounds) -> batched MLP over
//    edges in 16-edge tiles with LDS-staged weights -> atomic scatter to num.
//
// Workspace layout (floats):
//   hA      @ 0         2097152   latent h[x][y][z][c] (updated in place per layer)
//   scratch @ 2097152:
//     FFT view:  Fz(1048576) Fzy(524288) Ft(262144) Gt(262144) G1(524288) G2(1048576)
//     GNO view (used strictly after FNO): counter/eBase/eCnt/eN/eFlat/eAgg/num
//   total = 5767168 floats = 23.07 MB  (must be <= ws_size)
// ---------------------------------------------------------------------------

#define ECAP 196608   // max edges (analytic max is 8/point = 131072)

__device__ __forceinline__ float gelu_f(float x) {
    return 0.5f * x * (1.0f + erff(x * 0.7071067811865475f));
}

// ---------------- lifting: cat([f,in_p]) -> 256 (gelu) -> 64 ----------------
__global__ __launch_bounds__(256) void k_lift(
    const float* __restrict__ f, const float* __restrict__ in_p,
    const float* __restrict__ w1, const float* __restrict__ b1,
    const float* __restrict__ w2, const float* __restrict__ b2,
    float* __restrict__ h)
{
    __shared__ float w1s[6*256];
    __shared__ float w2s[256*64];
    __shared__ float b1s[256];
    __shared__ float b2s[64];
    __shared__ float h1s[4][256];
    int t = threadIdx.x;
    for (int i = t; i < 6*256; i += 256) w1s[i] = w1[i];
    for (int i = t; i < 256*64; i += 256) w2s[i] = w2[i];
    b1s[t] = b1[t];
    if (t < 64) b2s[t] = b2[t];
    __syncthreads();
    int p0 = blockIdx.x * 16;
    int o = t & 63, q = t >> 6;
    for (int pp = 0; pp < 16; pp += 4) {
        for (int qq = 0; qq < 4; ++qq) {
            int p = p0 + pp + qq;
            float x0 = f[p*3+0], x1 = f[p*3+1], x2 = f[p*3+2];
            float x3 = in_p[p*3+0], x4 = in_p[p*3+1], x5 = in_p[p*3+2];
            float a = b1s[t]
                + x0*w1s[0*256+t] + x1*w1s[1*256+t] + x2*w1s[2*256+t]
                + x3*w1s[3*256+t] + x4*w1s[4*256+t] + x5*w1s[5*256+t];
            h1s[qq][t] = gelu_f(a);
        }
        __syncthreads();
        {
            int p = p0 + pp + q;
            float acc = b2s[o];
            #pragma unroll 8
            for (int j = 0; j < 256; ++j) acc += h1s[q][j]*w2s[j*64+o];
            h[p*64+o] = acc;
        }
        __syncthreads();
    }
}

// ---------------- forward partial DFT, stage Z (real -> 8 modes) -----------
// grid 1024 (xy), out Fz[x][y][kz][c], scaled by 1/32768 (norm='forward')
__global__ __launch_bounds__(256) void k_fft_z(const float* __restrict__ h,
                                               float2* __restrict__ Fz)
{
    __shared__ float hs[32][64];
    __shared__ float twc[32], tws[32];
    int t = threadIdx.x;
    int xy = blockIdx.x;
    for (int i = t; i < 2048; i += 256) hs[i>>6][i&63] = h[xy*2048 + i];
    if (t < 32) { float th = (float)t*(6.283185307179586f/32.f); twc[t]=cosf(th); tws[t]=sinf(th); }
    __syncthreads();
    const float inv = 1.0f/32768.0f;
    #pragma unroll
    for (int k = 0; k < 2; ++k) {
        int idx = t + k*256;
        int kz = idx >> 6, c = idx & 63;
        float re = 0.f, im = 0.f;
        for (int z = 0; z < 32; ++z) {
            int ph = (kz*z)&31;
            float v = hs[z][c];
            re += v*twc[ph];
            im -= v*tws[ph];
        }
        Fz[(xy*8+kz)*64 + c] = make_float2(re*inv, im*inv);
    }
}

// ---------------- stage Y: 32 y -> 16 kept ky modes ------------------------
// grid 256 (x*8+kz), out Fzy[x][kyi][kz][c]
__global__ __launch_bounds__(256) void k_fft_y(const float2* __restrict__ Fz,
                                               float2* __restrict__ Fzy)
{
    __shared__ float2 fs[32][64];
    __shared__ float twc[32], tws[32];
    int t = threadIdx.x;
    int x = blockIdx.x >> 3, kz = blockIdx.x & 7;
    for (int i = t; i < 2048; i += 256) {
        int y = i >> 6, c = i & 63;
        fs[y][c] = Fz[((x*32+y)*8 + kz)*64 + c];
    }
    if (t < 32) { float th = (float)t*(6.283185307179586f/32.f); twc[t]=cosf(th); tws[t]=sinf(th); }
    __syncthreads();
    #pragma unroll
    for (int k = 0; k < 4; ++k) {
        int idx = t + k*256;
        int kyi = idx >> 6, c = idx & 63;
        int ky = kyi < 8 ? kyi : kyi + 16;
        float re = 0.f, im = 0.f;
        for (int y = 0; y < 32; ++y) {
            int ph = (ky*y)&31;
            float cc = twc[ph], ss = tws[ph];      // e^{-i th} = (cc, -ss)
            float2 a = fs[y][c];
            re += a.x*cc + a.y*ss;
            im += a.y*cc - a.x*ss;
        }
        Fzy[((x*16+kyi)*8 + kz)*64 + c] = make_float2(re, im);
    }
}

// ---------------- stage X: 32 x -> 16 kept kx modes ------------------------
// grid 128 (kyi*8+kz), out Ft[kxi][kyi][kz][c]
__global__ __launch_bounds__(256) void k_fft_x(const float2* __restrict__ Fzy,
                                               float2* __restrict__ Ft)
{
    __shared__ float2 fs[32][64];
    __shared__ float twc[32], tws[32];
    int t = threadIdx.x;
    int kyi = blockIdx.x >> 3, kz = blockIdx.x & 7;
    for (int i = t; i < 2048; i += 256) {
        int x = i >> 6, c = i & 63;
        fs[x][c] = Fzy[((x*16+kyi)*8 + kz)*64 + c];
    }
    if (t < 32) { float th = (float)t*(6.283185307179586f/32.f); twc[t]=cosf(th); tws[t]=sinf(th); }
    __syncthreads();
    #pragma unroll
    for (int k = 0; k < 4; ++k) {
        int idx = t + k*256;
        int kxi = idx >> 6, c = idx & 63;
        int kx = kxi < 8 ? kxi : kxi + 16;
        float re = 0.f, im = 0.f;
        for (int x = 0; x < 32; ++x) {
            int ph = (kx*x)&31;
            float cc = twc[ph], ss = tws[ph];
            float2 a = fs[x][c];
            re += a.x*cc + a.y*ss;
            im += a.y*cc - a.x*ss;
        }
        Ft[((kxi*16+kyi)*8 + kz)*64 + c] = make_float2(re, im);
    }
}

// ---------------- spectral multiply: Gt[m,o] = sum_i Ft[m,i]*w[l,c,i,o,m] ---
// grid 512: b -> corner(2) mx(3) oc(4 bits); 256 thr: m = t&63, og = t>>6
__global__ __launch_bounds__(256) void k_spectral(const float2* __restrict__ Ft,
                                                  const float2* __restrict__ wp,
                                                  float2* __restrict__ Gt, int l)
{
    __shared__ float2 fts[64][65];
    int t = threadIdx.x;
    int corner = blockIdx.x >> 7;
    int mx = (blockIdx.x >> 4) & 7;
    int oc = blockIdx.x & 15;
    int kxi = mx + ((corner >> 1) << 3);
    int kyB = (corner & 1) << 3;
    {   // load ft tile: 64 modes (my,mz) x 64 i
        int i = t & 63;
        int m0 = (t >> 6) * 16;
        for (int mm = 0; mm < 16; ++mm) {
            int m = m0 + mm;
            int my = m >> 3, mz = m & 7;
            int row = (kxi*16 + (kyB + my))*8 + mz;
            fts[i][m] = Ft[row*64 + i];
        }
    }
    __syncthreads();
    int m = t & 63;
    int og = t >> 6;
    int o = oc*4 + og;
    size_t base = (size_t)(l*4 + corner)*2097152 + (size_t)mx*64 + m;
    float ar = 0.f, ai = 0.f;
    for (int i = 0; i < 64; ++i) {
        float2 ft = fts[i][m];
        float2 w = wp[base + (size_t)i*32768 + (size_t)o*512];
        ar += ft.x*w.x - ft.y*w.y;
        ai += ft.x*w.y + ft.y*w.x;
    }
    int my = m >> 3, mz = m & 7;
    int row = (kxi*16 + (kyB + my))*8 + mz;
    Gt[row*64 + o] = make_float2(ar, ai);
}

// ---------------- inverse stage X: 16 kept kx -> 32 x ----------------------
// grid 128 (kyi*8+kz), out G1[x][kyi][kz][o]
__global__ __launch_bounds__(256) void k_inv_x(const float2* __restrict__ Gt,
                                               float2* __restrict__ G1)
{
    __shared__ float2 gs[16][64];
    __shared__ float twc[32], tws[32];
    int t = threadIdx.x;
    int kyi = blockIdx.x >> 3, kz = blockIdx.x & 7;
    for (int i = t; i < 1024; i += 256) {
        int kxi = i >> 6, o = i & 63;
        gs[kxi][o] = Gt[((kxi*16+kyi)*8 + kz)*64 + o];
    }
    if (t < 32) { float th = (float)t*(6.283185307179586f/32.f); twc[t]=cosf(th); tws[t]=sinf(th); }
    __syncthreads();
    #pragma unroll
    for (int k = 0; k < 8; ++k) {
        int idx = t + k*256;
        int x = idx >> 6, o = idx & 63;
        float re = 0.f, im = 0.f;
        for (int kxi = 0; kxi < 16; ++kxi) {
            int kx = kxi < 8 ? kxi : kxi + 16;
            int ph = (kx*x)&31;
            float cc = twc[ph], ss = tws[ph];      // e^{+i th}
            float2 a = gs[kxi][o];
            re += a.x*cc - a.y*ss;
            im += a.x*ss + a.y*cc;
        }
        G1[((x*16+kyi)*8 + kz)*64 + o] = make_float2(re, im);
    }
}

// ---------------- inverse stage Y: 16 kept ky -> 32 y ----------------------
// grid 256 (x*8+kz), out G2[x][y][kz][o]
__global__ __launch_bounds__(256) void k_inv_y(const float2* __restrict__ G1,
                                               float2* __restrict__ G2)
{
    __shared__ float2 gs[16][64];
    __shared__ float twc[32], tws[32];
    int t = threadIdx.x;
    int x = blockIdx.x >> 3, kz = blockIdx.x & 7;
    for (int i = t; i < 1024; i += 256) {
        int kyi = i >> 6, o = i & 63;
        gs[kyi][o] = G1[((x*16+kyi)*8 + kz)*64 + o];
    }
    if (t < 32) { float th = (float)t*(6.283185307179586f/32.f); twc[t]=cosf(th); tws[t]=sinf(th); }
    __syncthreads();
    #pragma unroll
    for (int k = 0; k < 8; ++k) {
        int idx = t + k*256;
        int y = idx >> 6, o = idx & 63;
        float re = 0.f, im = 0.f;
        for (int kyi = 0; kyi < 16; ++kyi) {
            int ky = kyi < 8 ? kyi : kyi + 16;
            int ph = (ky*y)&31;
            float cc = twc[ph], ss = tws[ph];
            float2 a = gs[kyi][o];
            re += a.x*cc - a.y*ss;
            im += a.x*ss + a.y*cc;
        }
        G2[((x*32+y)*8 + kz)*64 + o] = make_float2(re, im);
    }
}

// ---------------- inverse Z + skip GEMM + bias + (gelu), in-place h --------
// grid 1024 (xy)
__global__ __launch_bounds__(256) void k_inv_z_skip(const float2* __restrict__ G2,
                                                    const float* __restrict__ skw,
                                                    const float* __restrict__ skb,
                                                    float* __restrict__ h,
                                                    int l, int do_gelu)
{
    __shared__ float2 g2s[8][64];
    __shared__ float hs[32][64];
    __shared__ float wsk[64][64];
    __shared__ float twc[32], tws[32];
    __shared__ float bs[64];
    int t = threadIdx.x;
    int xy = blockIdx.x;
    for (int i = t; i < 512; i += 256) {
        int kz = i >> 6, o = i & 63;
        g2s[kz][o] = G2[(xy*8+kz)*64 + o];
    }
    for (int i = t; i < 2048; i += 256) hs[i>>6][i&63] = h[xy*2048 + i];
    for (int i = t; i < 4096; i += 256) wsk[i>>6][i&63] = skw[l*4096 + i];
    if (t < 64) bs[t] = skb[l*64 + t];
    if (t < 32) { float th = (float)t*(6.283185307179586f/32.f); twc[t]=cosf(th); tws[t]=sinf(th); }
    __syncthreads();
    int o = t & 63, z0 = t >> 6;
    for (int zz = 0; zz < 8; ++zz) {
        int z = z0 + zz*4;
        float s = g2s[0][o].x;                        // Re(g[kz=0]) (imag discarded)
        #pragma unroll
        for (int kz = 1; kz < 8; ++kz) {
            int ph = (kz*z)&31;
            s += 2.0f*(g2s[kz][o].x*twc[ph] - g2s[kz][o].y*tws[ph]);
        }
        float a = bs[o];
        #pragma unroll 8
        for (int i = 0; i < 64; ++i) a += hs[z][i]*wsk[i][o];
        float v = s + a;
        if (do_gelu) v = gelu_f(v);
        h[(xy*32+z)*64 + o] = v;
    }
}

// ---------------- GNO edge build (compaction) ------------------------------
// grid 64 x 256 = 16384 threads, one per output point
__global__ __launch_bounds__(256) void k_edges(const float* __restrict__ out_p,
                                               int* __restrict__ counter,
                                               int* __restrict__ eBase,
                                               int* __restrict__ eCnt,
                                               int* __restrict__ eN,
                                               int* __restrict__ eFlat,
                                               float* __restrict__ eAgg)
{
    int n = blockIdx.x*256 + threadIdx.x;
    float px = out_p[n*3+0], py = out_p[n*3+1], pz = out_p[n*3+2];
    int ix = (int)rintf(px*31.f), iy = (int)rintf(py*31.f), iz = (int)rintf(pz*31.f);
    const float hg = 1.0f/31.0f;
    const float r2 = (float)(0.033*0.033);
    unsigned msk = 0; int cnt = 0;
    for (int j = 0; j < 27; ++j) {
        int dx = j/9 - 1, dy = (j/3)%3 - 1, dz = j%3 - 1;
        int cx = ix+dx, cy = iy+dy, cz = iz+dz;
        bool inb = (cx>=0)&&(cx<32)&&(cy>=0)&&(cy<32)&&(cz>=0)&&(cz<32);
        int qx = min(max(cx,0),31), qy = min(max(cy,0),31), qz = min(max(cz,0),31);
        float yx = qx*hg, yy = qy*hg, yz = qz*hg;
        float d2 = (px-yx)*(px-yx) + (py-yy)*(py-yy) + (pz-yz)*(pz-yz);
        if (inb && d2 <= r2) { msk |= 1u<<j; cnt++; }
    }
    int base = atomicAdd(counter, cnt);
    eBase[n] = base; eCnt[n] = cnt;
    int k = 0;
    for (int j = 0; j < 27; ++j) if (msk & (1u<<j)) {
        int dx = j/9 - 1, dy = (j/3)%3 - 1, dz = j%3 - 1;
        int cx = ix+dx, cy = iy+dy, cz = iz+dz;
        int e = base + k;
        if (e < ECAP) {
            eN[e] = n;
            eFlat[e] = (cx*32+cy)*32 + cz;
            eAgg[e*6+0] = cx*hg; eAgg[e*6+1] = cy*hg; eAgg[e*6+2] = cz*hg;
            eAgg[e*6+3] = px;    eAgg[e*6+4] = py;    eAgg[e*6+5] = pz;
        }
        k++;
    }
}

// ---------------- GNO MLP over compacted edges + scatter -------------------
// 16 edges per block; grid ECAP/16; blocks beyond E exit.
__global__ __launch_bounds__(256) void k_gno_mlp(const int* __restrict__ counter,
                                                 const int* __restrict__ eN,
                                                 const int* __restrict__ eFlat,
                                                 const float* __restrict__ eAgg,
                                                 const float* __restrict__ w1,
                                                 const float* __restrict__ b1,
                                                 const float* __restrict__ w2,
                                                 const float* __restrict__ b2,
                                                 const float* __restrict__ w3,
                                                 const float* __restrict__ b3,
                                                 const float* __restrict__ latent,
                                                 float* __restrict__ num)
{
    __shared__ float aggs[16][6];
    __shared__ float h1s[16*520];      // padded rows (520) to spread banks
    __shared__ float h2s[16*264];
    __shared__ float w2s[16*256];
    __shared__ float w3s[16*64];
    int t = threadIdx.x;
    int E = counter[0]; if (E > ECAP) E = ECAP;
    int s = blockIdx.x * 16;
    if (s >= E) return;
    int ne = min(16, E - s);
    if (t < 96) {
        int e = t/6, d = t - (t/6)*6;
        aggs[e][d] = (e < ne) ? eAgg[(s+e)*6 + d] : 0.0f;
    }
    __syncthreads();
    // ---- layer1: 6 -> 512, gelu ----
    for (int r = 0; r < 32; ++r) {
        int idx = t + r*256;
        int e = idx >> 9, j = idx & 511;
        float a = b1[j];
        #pragma unroll
        for (int d = 0; d < 6; ++d) a += aggs[e][d]*w1[d*512+j];
        h1s[e*520 + j] = gelu_f(a);
    }
    __syncthreads();
    // ---- layer2: 512 -> 256, gelu;  thread = (eg: 4 e) x (jg: 4 j) --------
    int eg = t >> 6;          // 0..3  -> e = eg*4 + r
    int jg = t & 63;          // 0..63 -> j = jg*4 + jj
    float acc[4][4];
    #pragma unroll
    for (int r = 0; r < 4; ++r)
        #pragma unroll
        for (int jj = 0; jj < 4; ++jj) acc[r][jj] = b2[jg*4+jj];
    const float4* w2g4 = (const float4*)w2;
    float4* w2s4 = (float4*)w2s;
    for (int kt = 0; kt < 32; ++kt) {
        #pragma unroll
        for (int r = 0; r < 4; ++r) w2s4[t + r*256] = w2g4[kt*1024 + t + r*256];
        __syncthreads();
        #pragma unroll
        for (int kc = 0; kc < 4; ++kc) {
            float4 a0 = *(const float4*)&h1s[(eg*4+0)*520 + kt*16 + kc*4];
            float4 a1 = *(const float4*)&h1s[(eg*4+1)*520 + kt*16 + kc*4];
            float4 a2 = *(const float4*)&h1s[(eg*4+2)*520 + kt*16 + kc*4];
            float4 a3 = *(const float4*)&h1s[(eg*4+3)*520 + kt*16 + kc*4];
            #pragma unroll
            for (int kk = 0; kk < 4; ++kk) {
                float4 b = *(const float4*)&w2s[(kc*4+kk)*256 + jg*4];
                float av0 = (&a0.x)[kk], av1 = (&a1.x)[kk], av2 = (&a2.x)[kk], av3 = (&a3.x)[kk];
                acc[0][0] += av0*b.x; acc[0][1] += av0*b.y; acc[0][2] += av0*b.z; acc[0][3] += av0*b.w;
                acc[1][0] += av1*b.x; acc[1][1] += av1*b.y; acc[1][2] += av1*b.z; acc[1][3] += av1*b.w;
                acc[2][0] += av2*b.x; acc[2][1] += av2*b.y; acc[2][2] += av2*b.z; acc[2][3] += av2*b.w;
                acc[3][0] += av3*b.x; acc[3][1] += av3*b.y; acc[3][2] += av3*b.z; acc[3][3] += av3*b.w;
            }
        }
        __syncthreads();
    }
    #pragma unroll
    for (int r = 0; r < 4; ++r) {
        float4 v = make_float4(gelu_f(acc[r][0]), gelu_f(acc[r][1]),
                               gelu_f(acc[r][2]), gelu_f(acc[r][3]));
        *(float4*)&h2s[(eg*4+r)*264 + jg*4] = v;
    }
    __syncthreads();
    // ---- layer3: 256 -> 64 (no gelu); thread = (e: t>>4) x (oq: t&15) ----
    int e3 = t >> 4, oq = t & 15;
    float acc4[4];
    #pragma unroll
    for (int q = 0; q < 4; ++q) acc4[q] = b3[oq*4+q];
    const float4* w3g4 = (const float4*)w3;
    float4* w3s4 = (float4*)w3s;
    for (int kt = 0; kt < 16; ++kt) {
        if (t < 256) { w3s4[t] = w3g4[kt*256 + t]; }
        __syncthreads();
        #pragma unroll
        for (int kk = 0; kk < 16; ++kk) {
            float h2v = h2s[e3*264 + kt*16 + kk];
            float4 b = *(const float4*)&w3s[kk*64 + oq*4];
            acc4[0] += h2v*b.x; acc4[1] += h2v*b.y; acc4[2] += h2v*b.z; acc4[3] += h2v*b.w;
        }
        __syncthreads();
    }
    // ---- k * latent[flat], scatter-add into num ----
    if (e3 < ne) {
        int n = eN[s+e3], fl = eFlat[s+e3];
        #pragma unroll
        for (int q = 0; q < 4; ++q) {
            int o = oq*4 + q;
            float fy = latent[fl*64 + o];
            atomicAdd(&num[n*64 + o], acc4[q]*fy);
        }
    }
}

// ---------------- projection: num/den -> 256 (gelu) -> 1 -------------------
// grid 512, 32 points per block
__global__ __launch_bounds__(256) void k_project(const float* __restrict__ num,
                                                 const int* __restrict__ eCnt,
                                                 const float* __restrict__ pw1,
                                                 const float* __restrict__ pb1,
                                                 const float* __restrict__ pw2,
                                                 const float* __restrict__ pb2,
                                                 float* __restrict__ outp)
{
    __shared__ float w1s[64*256];
    __shared__ float b1s[256];
    __shared__ float w2s[256];
    __shared__ float xv[64];
    __shared__ float red[4];
    int t = threadIdx.x;
    for (int i = t; i < 64*256; i += 256) w1s[i] = pw1[i];
    b1s[t] = pb1[t];
    w2s[t] = pw2[t];
    __syncthreads();
    for (int p = 0; p < 32; ++p) {
        int n = blockIdx.x*32 + p;
        if (t < 64) {
            float den = (float)max(eCnt[n], 1);
            xv[t] = num[n*64+t] / den;
        }
        __syncthreads();
        float a = b1s[t];
        #pragma unroll 8
        for (int i = 0; i < 64; ++i) a += xv[i]*w1s[i*256+t];
        float v = gelu_f(a) * w2s[t];
        #pragma unroll
        for (int off = 32; off > 0; off >>= 1) v += __shfl_down(v, off, 64);
        if ((t & 63) == 0) red[t>>6] = v;
        __syncthreads();
        if (t == 0) outp[n] = red[0]+red[1]+red[2]+red[3] + pb2[0];
        __syncthreads();
    }
}

// ---------------------------------------------------------------------------
extern "C" void kernel_launch(void* const* d_in, const int* in_sizes, int n_in,
                              void* d_out, int out_size, void* d_ws, size_t ws_size,
                              hipStream_t stream)
{
    const float* in_p = (const float*)d_in[0];
    const float* outp = (const float*)d_in[1];
    const float* f    = (const float*)d_in[2];
    const float* lw1  = (const float*)d_in[3];
    const float* lb1  = (const float*)d_in[4];
    const float* lw2  = (const float*)d_in[5];
    const float* lb2  = (const float*)d_in[6];
    const float* spw  = (const float*)d_in[7];
    const float* skw  = (const float*)d_in[8];
    const float* skb  = (const float*)d_in[9];
    const float* gw1  = (const float*)d_in[10];
    const float* gb1  = (const float*)d_in[11];
    const float* gw2  = (const float*)d_in[12];
    const float* gb2  = (const float*)d_in[13];
    const float* gw3  = (const float*)d_in[14];
    const float* gb3  = (const float*)d_in[15];
    const float* pw1  = (const float*)d_in[16];
    const float* pb1  = (const float*)d_in[17];
    const float* pw2  = (const float*)d_in[18];
    const float* pb2  = (const float*)d_in[19];

    float* ws = (float*)d_ws;
    float* hA = ws;                       // 2097152 floats
    float* SC = ws + 2097152;
    float2* Fz  = (float2*)(SC);
    float2* Fzy = (float2*)(SC + 1048576);
    float2* Ft  = (float2*)(SC + 1572864);
    float2* Gt  = (float2*)(SC + 1835008);
    float2* G1  = (float2*)(SC + 2097152);
    float2* G2  = (float2*)(SC + 2621440);
    // GNO overlay (used only after all FNO kernels completed)
    int*   counter = (int*)SC;
    int*   eBase   = (int*)(SC + 64);
    int*   eCnt    = (int*)(SC + 64 + 16384);
    int*   eN      = (int*)(SC + 64 + 32768);
    int*   eFlat   = (int*)(SC + 64 + 32768 + ECAP);
    float* eAgg    = SC + 64 + 32768 + 2*ECAP;
    float* numb    = SC + 64 + 32768 + 8*ECAP;     // 16384*64 floats

    k_lift<<<2048, 256, 0, stream>>>(f, in_p, lw1, lb1, lw2, lb2, hA);

    for (int l = 0; l < 4; ++l) {
        k_fft_z<<<1024, 256, 0, stream>>>(hA, Fz);
        k_fft_y<<<256, 256, 0, stream>>>(Fz, Fzy);
        k_fft_x<<<128, 256, 0, stream>>>(Fzy, Ft);
        k_spectral<<<512, 256, 0, stream>>>(Ft, (const float2*)spw, Gt, l);
        k_inv_x<<<128, 256, 0, stream>>>(Gt, G1);
        k_inv_y<<<256, 256, 0, stream>>>(G1, G2);
        k_inv_z_skip<<<1024, 256, 0, stream>>>(G2, skw, skb, hA, l, (l < 3) ? 1 : 0);
    }

    hipMemsetAsync(counter, 0, sizeof(int), stream);
    hipMemsetAsync(numb, 0, (size_t)16384*64*sizeof(float), stream);
    k_edges<<<64, 256, 0, stream>>>(outp, counter, eBase, eCnt, eN, eFlat, eAgg);
    k_gno_mlp<<<ECAP/16, 256, 0, stream>>>(counter, eN, eFlat, eAgg,
                                           gw1, gb1, gw2, gb2, gw3, gb3,
                                           hA, numb);
    k_project<<<512, 256, 0, stream>>>(numb, eCnt, pw1, pb1, pw2, pb2, (float*)d_out);
}

// Round 2
// 766.657 us; speedup vs baseline: 1.1465x; 1.1465x over previous
//
#include <hip/hip_runtime.h>
#include <math.h>

// ---------------------------------------------------------------------------
// FNO-GNO. Round 2: GNO edge-MLP layers 2/3 moved to fp16 MFMA (fp32 accum).
// G=32, HID=64, M=8 (16 kept modes/axis, 8 in rfft axis), NL=4, NPTS=16384.
//
// Workspace layout (floats), total 5767168 floats = 23.07 MB (same as r1):
//   hA      @ 0         2097152   latent h[x][y][z][c]
//   SC = ws + 2097152:
//     FFT view:  Fz(1048576) Fzy(524288) Ft(262144) Gt(262144) G1(524288) G2(1048576)
//     GNO view (after FNO): counter/eBase/eCnt/eN/eFlat/eAgg/num  (ends 2654272)
//     fp16 weights @ SC+2654272 (73728 floats) -- inside FFT-only G2 region,
//     written by k_prep_w AFTER the FNO loop completes.
// ---------------------------------------------------------------------------

#define ECAP 196608

typedef _Float16 f16x8 __attribute__((ext_vector_type(8)));
typedef float f32x4 __attribute__((ext_vector_type(4)));

__device__ __forceinline__ float gelu_f(float x) {
    return 0.5f * x * (1.0f + erff(x * 0.7071067811865475f));
}

// ---------------- lifting: cat([f,in_p]) -> 256 (gelu) -> 64 ----------------
__global__ __launch_bounds__(256) void k_lift(
    const float* __restrict__ f, const float* __restrict__ in_p,
    const float* __restrict__ w1, const float* __restrict__ b1,
    const float* __restrict__ w2, const float* __restrict__ b2,
    float* __restrict__ h)
{
    __shared__ float w1s[6*256];
    __shared__ float w2s[256*64];
    __shared__ float b1s[256];
    __shared__ float b2s[64];
    __shared__ float h1s[4][256];
    int t = threadIdx.x;
    for (int i = t; i < 6*256; i += 256) w1s[i] = w1[i];
    for (int i = t; i < 256*64; i += 256) w2s[i] = w2[i];
    b1s[t] = b1[t];
    if (t < 64) b2s[t] = b2[t];
    __syncthreads();
    int p0 = blockIdx.x * 16;
    int o = t & 63, q = t >> 6;
    for (int pp = 0; pp < 16; pp += 4) {
        for (int qq = 0; qq < 4; ++qq) {
            int p = p0 + pp + qq;
            float x0 = f[p*3+0], x1 = f[p*3+1], x2 = f[p*3+2];
            float x3 = in_p[p*3+0], x4 = in_p[p*3+1], x5 = in_p[p*3+2];
            float a = b1s[t]
                + x0*w1s[0*256+t] + x1*w1s[1*256+t] + x2*w1s[2*256+t]
                + x3*w1s[3*256+t] + x4*w1s[4*256+t] + x5*w1s[5*256+t];
            h1s[qq][t] = gelu_f(a);
        }
        __syncthreads();
        {
            int p = p0 + pp + q;
            float acc = b2s[o];
            #pragma unroll 8
            for (int j = 0; j < 256; ++j) acc += h1s[q][j]*w2s[j*64+o];
            h[p*64+o] = acc;
        }
        __syncthreads();
    }
}

// ---------------- forward partial DFT, stage Z (real -> 8 modes) -----------
__global__ __launch_bounds__(256) void k_fft_z(const float* __restrict__ h,
                                               float2* __restrict__ Fz)
{
    __shared__ float hs[32][64];
    __shared__ float twc[32], tws[32];
    int t = threadIdx.x;
    int xy = blockIdx.x;
    for (int i = t; i < 2048; i += 256) hs[i>>6][i&63] = h[xy*2048 + i];
    if (t < 32) { float th = (float)t*(6.283185307179586f/32.f); twc[t]=cosf(th); tws[t]=sinf(th); }
    __syncthreads();
    const float inv = 1.0f/32768.0f;
    #pragma unroll
    for (int k = 0; k < 2; ++k) {
        int idx = t + k*256;
        int kz = idx >> 6, c = idx & 63;
        float re = 0.f, im = 0.f;
        for (int z = 0; z < 32; ++z) {
            int ph = (kz*z)&31;
            float v = hs[z][c];
            re += v*twc[ph];
            im -= v*tws[ph];
        }
        Fz[(xy*8+kz)*64 + c] = make_float2(re*inv, im*inv);
    }
}

// ---------------- stage Y: 32 y -> 16 kept ky modes ------------------------
__global__ __launch_bounds__(256) void k_fft_y(const float2* __restrict__ Fz,
                                               float2* __restrict__ Fzy)
{
    __shared__ float2 fs[32][64];
    __shared__ float twc[32], tws[32];
    int t = threadIdx.x;
    int x = blockIdx.x >> 3, kz = blockIdx.x & 7;
    for (int i = t; i < 2048; i += 256) {
        int y = i >> 6, c = i & 63;
        fs[y][c] = Fz[((x*32+y)*8 + kz)*64 + c];
    }
    if (t < 32) { float th = (float)t*(6.283185307179586f/32.f); twc[t]=cosf(th); tws[t]=sinf(th); }
    __syncthreads();
    #pragma unroll
    for (int k = 0; k < 4; ++k) {
        int idx = t + k*256;
        int kyi = idx >> 6, c = idx & 63;
        int ky = kyi < 8 ? kyi : kyi + 16;
        float re = 0.f, im = 0.f;
        for (int y = 0; y < 32; ++y) {
            int ph = (ky*y)&31;
            float cc = twc[ph], ss = tws[ph];
            float2 a = fs[y][c];
            re += a.x*cc + a.y*ss;
            im += a.y*cc - a.x*ss;
        }
        Fzy[((x*16+kyi)*8 + kz)*64 + c] = make_float2(re, im);
    }
}

// ---------------- stage X: 32 x -> 16 kept kx modes ------------------------
__global__ __launch_bounds__(256) void k_fft_x(const float2* __restrict__ Fzy,
                                               float2* __restrict__ Ft)
{
    __shared__ float2 fs[32][64];
    __shared__ float twc[32], tws[32];
    int t = threadIdx.x;
    int kyi = blockIdx.x >> 3, kz = blockIdx.x & 7;
    for (int i = t; i < 2048; i += 256) {
        int x = i >> 6, c = i & 63;
        fs[x][c] = Fzy[((x*16+kyi)*8 + kz)*64 + c];
    }
    if (t < 32) { float th = (float)t*(6.283185307179586f/32.f); twc[t]=cosf(th); tws[t]=sinf(th); }
    __syncthreads();
    #pragma unroll
    for (int k = 0; k < 4; ++k) {
        int idx = t + k*256;
        int kxi = idx >> 6, c = idx & 63;
        int kx = kxi < 8 ? kxi : kxi + 16;
        float re = 0.f, im = 0.f;
        for (int x = 0; x < 32; ++x) {
            int ph = (kx*x)&31;
            float cc = twc[ph], ss = tws[ph];
            float2 a = fs[x][c];
            re += a.x*cc + a.y*ss;
            im += a.y*cc - a.x*ss;
        }
        Ft[((kxi*16+kyi)*8 + kz)*64 + c] = make_float2(re, im);
    }
}

// ---------------- spectral multiply ----------------------------------------
__global__ __launch_bounds__(256) void k_spectral(const float2* __restrict__ Ft,
                                                  const float2* __restrict__ wp,
                                                  float2* __restrict__ Gt, int l)
{
    __shared__ float2 fts[64][65];
    int t = threadIdx.x;
    int corner = blockIdx.x >> 7;
    int mx = (blockIdx.x >> 4) & 7;
    int oc = blockIdx.x & 15;
    int kxi = mx + ((corner >> 1) << 3);
    int kyB = (corner & 1) << 3;
    {
        int i = t & 63;
        int m0 = (t >> 6) * 16;
        for (int mm = 0; mm < 16; ++mm) {
            int m = m0 + mm;
            int my = m >> 3, mz = m & 7;
            int row = (kxi*16 + (kyB + my))*8 + mz;
            fts[i][m] = Ft[row*64 + i];
        }
    }
    __syncthreads();
    int m = t & 63;
    int og = t >> 6;
    int o = oc*4 + og;
    size_t base = (size_t)(l*4 + corner)*2097152 + (size_t)mx*64 + m;
    float ar = 0.f, ai = 0.f;
    for (int i = 0; i < 64; ++i) {
        float2 ft = fts[i][m];
        float2 w = wp[base + (size_t)i*32768 + (size_t)o*512];
        ar += ft.x*w.x - ft.y*w.y;
        ai += ft.x*w.y + ft.y*w.x;
    }
    int my = m >> 3, mz = m & 7;
    int row = (kxi*16 + (kyB + my))*8 + mz;
    Gt[row*64 + o] = make_float2(ar, ai);
}

// ---------------- inverse stage X ------------------------------------------
__global__ __launch_bounds__(256) void k_inv_x(const float2* __restrict__ Gt,
                                               float2* __restrict__ G1)
{
    __shared__ float2 gs[16][64];
    __shared__ float twc[32], tws[32];
    int t = threadIdx.x;
    int kyi = blockIdx.x >> 3, kz = blockIdx.x & 7;
    for (int i = t; i < 1024; i += 256) {
        int kxi = i >> 6, o = i & 63;
        gs[kxi][o] = Gt[((kxi*16+kyi)*8 + kz)*64 + o];
    }
    if (t < 32) { float th = (float)t*(6.283185307179586f/32.f); twc[t]=cosf(th); tws[t]=sinf(th); }
    __syncthreads();
    #pragma unroll
    for (int k = 0; k < 8; ++k) {
        int idx = t + k*256;
        int x = idx >> 6, o = idx & 63;
        float re = 0.f, im = 0.f;
        for (int kxi = 0; kxi < 16; ++kxi) {
            int kx = kxi < 8 ? kxi : kxi + 16;
            int ph = (kx*x)&31;
            float cc = twc[ph], ss = tws[ph];
            float2 a = gs[kxi][o];
            re += a.x*cc - a.y*ss;
            im += a.x*ss + a.y*cc;
        }
        G1[((x*16+kyi)*8 + kz)*64 + o] = make_float2(re, im);
    }
}

// ---------------- inverse stage Y ------------------------------------------
__global__ __launch_bounds__(256) void k_inv_y(const float2* __restrict__ G1,
                                               float2* __restrict__ G2)
{
    __shared__ float2 gs[16][64];
    __shared__ float twc[32], tws[32];
    int t = threadIdx.x;
    int x = blockIdx.x >> 3, kz = blockIdx.x & 7;
    for (int i = t; i < 1024; i += 256) {
        int kyi = i >> 6, o = i & 63;
        gs[kyi][o] = G1[((x*16+kyi)*8 + kz)*64 + o];
    }
    if (t < 32) { float th = (float)t*(6.283185307179586f/32.f); twc[t]=cosf(th); tws[t]=sinf(th); }
    __syncthreads();
    #pragma unroll
    for (int k = 0; k < 8; ++k) {
        int idx = t + k*256;
        int y = idx >> 6, o = idx & 63;
        float re = 0.f, im = 0.f;
        for (int kyi = 0; kyi < 16; ++kyi) {
            int ky = kyi < 8 ? kyi : kyi + 16;
            int ph = (ky*y)&31;
            float cc = twc[ph], ss = tws[ph];
            float2 a = gs[kyi][o];
            re += a.x*cc - a.y*ss;
            im += a.x*ss + a.y*cc;
        }
        G2[((x*32+y)*8 + kz)*64 + o] = make_float2(re, im);
    }
}

// ---------------- inverse Z + skip GEMM + bias + (gelu) --------------------
__global__ __launch_bounds__(256) void k_inv_z_skip(const float2* __restrict__ G2,
                                                    const float* __restrict__ skw,
                                                    const float* __restrict__ skb,
                                                    float* __restrict__ h,
                                                    int l, int do_gelu)
{
    __shared__ float2 g2s[8][64];
    __shared__ float hs[32][64];
    __shared__ float wsk[64][64];
    __shared__ float twc[32], tws[32];
    __shared__ float bs[64];
    int t = threadIdx.x;
    int xy = blockIdx.x;
    for (int i = t; i < 512; i += 256) {
        int kz = i >> 6, o = i & 63;
        g2s[kz][o] = G2[(xy*8+kz)*64 + o];
    }
    for (int i = t; i < 2048; i += 256) hs[i>>6][i&63] = h[xy*2048 + i];
    for (int i = t; i < 4096; i += 256) wsk[i>>6][i&63] = skw[l*4096 + i];
    if (t < 64) bs[t] = skb[l*64 + t];
    if (t < 32) { float th = (float)t*(6.283185307179586f/32.f); twc[t]=cosf(th); tws[t]=sinf(th); }
    __syncthreads();
    int o = t & 63, z0 = t >> 6;
    for (int zz = 0; zz < 8; ++zz) {
        int z = z0 + zz*4;
        float s = g2s[0][o].x;
        #pragma unroll
        for (int kz = 1; kz < 8; ++kz) {
            int ph = (kz*z)&31;
            s += 2.0f*(g2s[kz][o].x*twc[ph] - g2s[kz][o].y*tws[ph]);
        }
        float a = bs[o];
        #pragma unroll 8
        for (int i = 0; i < 64; ++i) a += hs[z][i]*wsk[i][o];
        float v = s + a;
        if (do_gelu) v = gelu_f(v);
        h[(xy*32+z)*64 + o] = v;
    }
}

// ---------------- GNO weight prep: fp32 -> fp16 transposed -----------------
__global__ __launch_bounds__(256) void k_prep_w(const float* __restrict__ w2,
                                                const float* __restrict__ w3,
                                                _Float16* __restrict__ w2T,
                                                _Float16* __restrict__ w3T)
{
    int idx = blockIdx.x*256 + threadIdx.x;
    if (idx < 512*256) {
        int k = idx >> 8, n = idx & 255;
        w2T[n*512 + k] = (_Float16)w2[idx];
    } else {
        int j = idx - 512*256;
        if (j < 256*64) {
            int k = j >> 6, o = j & 63;
            w3T[o*256 + k] = (_Float16)w3[j];
        }
    }
}

// ---------------- GNO edge build (compaction) ------------------------------
__global__ __launch_bounds__(256) void k_edges(const float* __restrict__ out_p,
                                               int* __restrict__ counter,
                                               int* __restrict__ eBase,
                                               int* __restrict__ eCnt,
                                               int* __restrict__ eN,
                                               int* __restrict__ eFlat,
                                               float* __restrict__ eAgg)
{
    int n = blockIdx.x*256 + threadIdx.x;
    float px = out_p[n*3+0], py = out_p[n*3+1], pz = out_p[n*3+2];
    int ix = (int)rintf(px*31.f), iy = (int)rintf(py*31.f), iz = (int)rintf(pz*31.f);
    const float hg = 1.0f/31.0f;
    const float r2 = (float)(0.033*0.033);
    unsigned msk = 0; int cnt = 0;
    for (int j = 0; j < 27; ++j) {
        int dx = j/9 - 1, dy = (j/3)%3 - 1, dz = j%3 - 1;
        int cx = ix+dx, cy = iy+dy, cz = iz+dz;
        bool inb = (cx>=0)&&(cx<32)&&(cy>=0)&&(cy<32)&&(cz>=0)&&(cz<32);
        int qx = min(max(cx,0),31), qy = min(max(cy,0),31), qz = min(max(cz,0),31);
        float yx = qx*hg, yy = qy*hg, yz = qz*hg;
        float d2 = (px-yx)*(px-yx) + (py-yy)*(py-yy) + (pz-yz)*(pz-yz);
        if (inb && d2 <= r2) { msk |= 1u<<j; cnt++; }
    }
    int base = atomicAdd(counter, cnt);
    eBase[n] = base; eCnt[n] = cnt;
    int k = 0;
    for (int j = 0; j < 27; ++j) if (msk & (1u<<j)) {
        int dx = j/9 - 1, dy = (j/3)%3 - 1, dz = j%3 - 1;
        int cx = ix+dx, cy = iy+dy, cz = iz+dz;
        int e = base + k;
        if (e < ECAP) {
            eN[e] = n;
            eFlat[e] = (cx*32+cy)*32 + cz;
            eAgg[e*6+0] = cx*hg; eAgg[e*6+1] = cy*hg; eAgg[e*6+2] = cz*hg;
            eAgg[e*6+3] = px;    eAgg[e*6+4] = py;    eAgg[e*6+5] = pz;
        }
        k++;
    }
}

// ---------------- GNO MLP via fp16 MFMA, 32 edges/block --------------------
// layer1 fp32 VALU (6->512) -> gelu -> fp16 LDS (XOR-swizzled 16B chunks)
// layer2 MFMA [32x512]x[512x256], gelu -> fp16 LDS
// layer3 MFMA [32x256]x[256x64], epilogue k*latent -> atomicAdd num
__global__ __launch_bounds__(256) void k_gno_mlp(
    const int* __restrict__ counter,
    const int* __restrict__ eN,
    const int* __restrict__ eFlat,
    const float* __restrict__ eAgg,
    const float* __restrict__ w1,      // [6][512]
    const float* __restrict__ b1,      // [512]
    const _Float16* __restrict__ w2T,  // [256][512]
    const float* __restrict__ b2,      // [256]
    const _Float16* __restrict__ w3T,  // [64][256]
    const float* __restrict__ b3,      // [64]
    const float* __restrict__ latent,  // [32768][64]
    float* __restrict__ num)           // [16384][64]
{
    __shared__ _Float16 h1h[32*512];   // 32 KB, chunk-swizzled
    __shared__ _Float16 h2h[32*256];   // 16 KB, chunk-swizzled
    __shared__ float aggs[32][8];
    int t = threadIdx.x;
    int E = counter[0]; if (E > ECAP) E = ECAP;
    int s = blockIdx.x * 32;
    if (s >= E) return;
    int ne = min(32, E - s);
    if (t < 192) {
        int e = t/6, d = t - (t/6)*6;
        aggs[e][d] = (e < ne) ? eAgg[(s+e)*6 + d] : 0.0f;
    }
    __syncthreads();

    // ---- layer1 ----
    {
        int m = t >> 3;
        float a0 = aggs[m][0], a1 = aggs[m][1], a2 = aggs[m][2];
        float a3 = aggs[m][3], a4 = aggs[m][4], a5 = aggs[m][5];
        for (int r = 0; r < 8; ++r) {
            int c = (t & 7) + r*8;              // chunk 0..63 (8 halves each)
            int j0 = c*8;
            f16x8 v;
            #pragma unroll
            for (int jj = 0; jj < 8; ++jj) {
                int j = j0 + jj;
                float a = b1[j] + a0*w1[j] + a1*w1[512+j] + a2*w1[1024+j]
                        + a3*w1[1536+j] + a4*w1[2048+j] + a5*w1[2560+j];
                v[jj] = (_Float16)gelu_f(a);
            }
            *(f16x8*)&h1h[m*512 + ((c ^ (m & 7))*8)] = v;
        }
    }
    __syncthreads();

    int w = t >> 6;
    int lane = t & 63;
    int l15 = lane & 15, g = lane >> 4;

    // ---- layer2: wave w owns n in [w*64, w*64+64) ----
    f32x4 acc2[2][4];
    #pragma unroll
    for (int nt = 0; nt < 4; ++nt) {
        float bb = b2[w*64 + nt*16 + l15];
        acc2[0][nt] = (f32x4){bb, bb, bb, bb};
        acc2[1][nt] = (f32x4){bb, bb, bb, bb};
    }
    for (int kk = 0; kk < 16; ++kk) {
        int chunk = (kk*4 + g);
        f16x8 a0 = *(const f16x8*)&h1h[(l15     )*512 + ((chunk ^ (l15 & 7))*8)];
        f16x8 a1 = *(const f16x8*)&h1h[(16 + l15)*512 + ((chunk ^ (l15 & 7))*8)];
        #pragma unroll
        for (int nt = 0; nt < 4; ++nt) {
            int n = w*64 + nt*16 + l15;
            f16x8 b = *(const f16x8*)&w2T[(size_t)n*512 + kk*32 + g*8];
            acc2[0][nt] = __builtin_amdgcn_mfma_f32_16x16x32_f16(a0, b, acc2[0][nt], 0, 0, 0);
            acc2[1][nt] = __builtin_amdgcn_mfma_f32_16x16x32_f16(a1, b, acc2[1][nt], 0, 0, 0);
        }
    }
    // gelu + transpose-store h2 to LDS (fp16, swizzled)
    #pragma unroll
    for (int mt = 0; mt < 2; ++mt)
      #pragma unroll
      for (int nt = 0; nt < 4; ++nt) {
        int n = w*64 + nt*16 + l15;
        #pragma unroll
        for (int r = 0; r < 4; ++r) {
            int m = mt*16 + g*4 + r;
            h2h[m*256 + (((n >> 3) ^ (m & 7))*8) + (n & 7)] =
                (_Float16)gelu_f(acc2[mt][nt][r]);
        }
      }
    __syncthreads();

    // ---- layer3: wave w owns o-tile w (o = w*16 + l15) ----
    int o = w*16 + l15;
    f32x4 acc3[2];
    { float bb = b3[o]; acc3[0] = (f32x4){bb, bb, bb, bb}; acc3[1] = acc3[0]; }
    for (int kk = 0; kk < 8; ++kk) {
        f16x8 b = *(const f16x8*)&w3T[(size_t)o*256 + kk*32 + g*8];
        #pragma unroll
        for (int mt = 0; mt < 2; ++mt) {
            int chunk = (kk*4 + g);
            f16x8 a = *(const f16x8*)&h2h[(mt*16 + l15)*256 + ((chunk ^ (l15 & 7))*8)];
            acc3[mt] = __builtin_amdgcn_mfma_f32_16x16x32_f16(a, b, acc3[mt], 0, 0, 0);
        }
    }

    // ---- epilogue: k * latent[flat], scatter ----
    #pragma unroll
    for (int mt = 0; mt < 2; ++mt) {
        #pragma unroll
        for (int r = 0; r < 4; ++r) {
            int el = mt*16 + g*4 + r;
            if (el < ne) {
                int e = s + el;
                int nn = eN[e], fl = eFlat[e];
                float fy = latent[(size_t)fl*64 + o];
                atomicAdd(&num[(size_t)nn*64 + o], acc3[mt][r] * fy);
            }
        }
    }
}

// ---------------- projection: num/den -> 256 (gelu) -> 1 -------------------
__global__ __launch_bounds__(256) void k_project(const float* __restrict__ num,
                                                 const int* __restrict__ eCnt,
                                                 const float* __restrict__ pw1,
                                                 const float* __restrict__ pb1,
                                                 const float* __restrict__ pw2,
                                                 const float* __restrict__ pb2,
                                                 float* __restrict__ outp)
{
    __shared__ float w1s[64*256];
    __shared__ float b1s[256];
    __shared__ float w2s[256];
    __shared__ float xv[64];
    __shared__ float red[4];
    int t = threadIdx.x;
    for (int i = t; i < 64*256; i += 256) w1s[i] = pw1[i];
    b1s[t] = pb1[t];
    w2s[t] = pw2[t];
    __syncthreads();
    for (int p = 0; p < 32; ++p) {
        int n = blockIdx.x*32 + p;
        if (t < 64) {
            float den = (float)max(eCnt[n], 1);
            xv[t] = num[n*64+t] / den;
        }
        __syncthreads();
        float a = b1s[t];
        #pragma unroll 8
        for (int i = 0; i < 64; ++i) a += xv[i]*w1s[i*256+t];
        float v = gelu_f(a) * w2s[t];
        #pragma unroll
        for (int off = 32; off > 0; off >>= 1) v += __shfl_down(v, off, 64);
        if ((t & 63) == 0) red[t>>6] = v;
        __syncthreads();
        if (t == 0) outp[n] = red[0]+red[1]+red[2]+red[3] + pb2[0];
        __syncthreads();
    }
}

// ---------------------------------------------------------------------------
extern "C" void kernel_launch(void* const* d_in, const int* in_sizes, int n_in,
                              void* d_out, int out_size, void* d_ws, size_t ws_size,
                              hipStream_t stream)
{
    const float* in_p = (const float*)d_in[0];
    const float* outp = (const float*)d_in[1];
    const float* f    = (const float*)d_in[2];
    const float* lw1  = (const float*)d_in[3];
    const float* lb1  = (const float*)d_in[4];
    const float* lw2  = (const float*)d_in[5];
    const float* lb2  = (const float*)d_in[6];
    const float* spw  = (const float*)d_in[7];
    const float* skw  = (const float*)d_in[8];
    const float* skb  = (const float*)d_in[9];
    const float* gw1  = (const float*)d_in[10];
    const float* gb1  = (const float*)d_in[11];
    const float* gw2  = (const float*)d_in[12];
    const float* gb2  = (const float*)d_in[13];
    const float* gw3  = (const float*)d_in[14];
    const float* gb3  = (const float*)d_in[15];
    const float* pw1  = (const float*)d_in[16];
    const float* pb1  = (const float*)d_in[17];
    const float* pw2  = (const float*)d_in[18];
    const float* pb2  = (const float*)d_in[19];

    float* ws = (float*)d_ws;
    float* hA = ws;                       // 2097152 floats
    float* SC = ws + 2097152;
    float2* Fz  = (float2*)(SC);
    float2* Fzy = (float2*)(SC + 1048576);
    float2* Ft  = (float2*)(SC + 1572864);
    float2* Gt  = (float2*)(SC + 1835008);
    float2* G1  = (float2*)(SC + 2097152);
    float2* G2  = (float2*)(SC + 2621440);
    // GNO overlay (used only after all FNO kernels completed)
    int*   counter = (int*)SC;
    int*   eBase   = (int*)(SC + 64);
    int*   eCnt    = (int*)(SC + 64 + 16384);
    int*   eN      = (int*)(SC + 64 + 32768);
    int*   eFlat   = (int*)(SC + 64 + 32768 + ECAP);
    float* eAgg    = SC + 64 + 32768 + 2*ECAP;
    float* numb    = SC + 64 + 32768 + 8*ECAP;      // ends at SC+2654272
    _Float16* w2T  = (_Float16*)(SC + 2654272);     // 131072 halves
    _Float16* w3T  = w2T + 512*256;                 // 16384 halves (ends < FFT max)

    k_lift<<<2048, 256, 0, stream>>>(f, in_p, lw1, lb1, lw2, lb2, hA);

    for (int l = 0; l < 4; ++l) {
        k_fft_z<<<1024, 256, 0, stream>>>(hA, Fz);
        k_fft_y<<<256, 256, 0, stream>>>(Fz, Fzy);
        k_fft_x<<<128, 256, 0, stream>>>(Fzy, Ft);
        k_spectral<<<512, 256, 0, stream>>>(Ft, (const float2*)spw, Gt, l);
        k_inv_x<<<128, 256, 0, stream>>>(Gt, G1);
        k_inv_y<<<256, 256, 0, stream>>>(G1, G2);
        k_inv_z_skip<<<1024, 256, 0, stream>>>(G2, skw, skb, hA, l, (l < 3) ? 1 : 0);
    }

    // GNO (strictly after FNO; fp16 weight buffers live inside former G2 space)
    k_prep_w<<<576, 256, 0, stream>>>(gw2, gw3, w2T, w3T);
    hipMemsetAsync(counter, 0, sizeof(int), stream);
    hipMemsetAsync(numb, 0, (size_t)16384*64*sizeof(float), stream);
    k_edges<<<64, 256, 0, stream>>>(outp, counter, eBase, eCnt, eN, eFlat, eAgg);
    k_gno_mlp<<<ECAP/32, 256, 0, stream>>>(counter, eN, eFlat, eAgg,
                                           gw1, gb1, w2T, gb2, w3T, gb3,
                                           hA, numb);
    k_project<<<512, 256, 0, stream>>>(numb, eCnt, pw1, pb1, pw2, pb2, (float*)d_out);
}

// Round 3
// 728.175 us; speedup vs baseline: 1.2071x; 1.0528x over previous
//
#include <hip/hip_runtime.h>
#include <math.h>

// ---------------------------------------------------------------------------
// FNO-GNO. Round 3: GNO made point-owned, global atomics eliminated.
//   r2 post-mortem: atomicAdd scatter to num[] resolved at the coherence
//   point (WRITE_SIZE 20MB ~= atomic cachelines), ~300us floor. Now each
//   block owns 16 points, builds its own edge list in LDS, runs the MFMA
//   MLP over <=4 tiles of 32 edges, reduces into LDS (ds_add_f32), and
//   writes num once with plain stores.
// ---------------------------------------------------------------------------

typedef _Float16 f16x8 __attribute__((ext_vector_type(8)));
typedef float f32x4 __attribute__((ext_vector_type(4)));

__device__ __forceinline__ float gelu_f(float x) {
    return 0.5f * x * (1.0f + erff(x * 0.7071067811865475f));
}

// ---------------- lifting: cat([f,in_p]) -> 256 (gelu) -> 64 ----------------
__global__ __launch_bounds__(256) void k_lift(
    const float* __restrict__ f, const float* __restrict__ in_p,
    const float* __restrict__ w1, const float* __restrict__ b1,
    const float* __restrict__ w2, const float* __restrict__ b2,
    float* __restrict__ h)
{
    __shared__ float w1s[6*256];
    __shared__ float w2s[256*64];
    __shared__ float b1s[256];
    __shared__ float b2s[64];
    __shared__ float h1s[4][256];
    int t = threadIdx.x;
    for (int i = t; i < 6*256; i += 256) w1s[i] = w1[i];
    for (int i = t; i < 256*64; i += 256) w2s[i] = w2[i];
    b1s[t] = b1[t];
    if (t < 64) b2s[t] = b2[t];
    __syncthreads();
    int p0 = blockIdx.x * 16;
    int o = t & 63, q = t >> 6;
    for (int pp = 0; pp < 16; pp += 4) {
        for (int qq = 0; qq < 4; ++qq) {
            int p = p0 + pp + qq;
            float x0 = f[p*3+0], x1 = f[p*3+1], x2 = f[p*3+2];
            float x3 = in_p[p*3+0], x4 = in_p[p*3+1], x5 = in_p[p*3+2];
            float a = b1s[t]
                + x0*w1s[0*256+t] + x1*w1s[1*256+t] + x2*w1s[2*256+t]
                + x3*w1s[3*256+t] + x4*w1s[4*256+t] + x5*w1s[5*256+t];
            h1s[qq][t] = gelu_f(a);
        }
        __syncthreads();
        {
            int p = p0 + pp + q;
            float acc = b2s[o];
            #pragma unroll 8
            for (int j = 0; j < 256; ++j) acc += h1s[q][j]*w2s[j*64+o];
            h[p*64+o] = acc;
        }
        __syncthreads();
    }
}

// ---------------- forward partial DFT, stage Z (real -> 8 modes) -----------
__global__ __launch_bounds__(256) void k_fft_z(const float* __restrict__ h,
                                               float2* __restrict__ Fz)
{
    __shared__ float hs[32][64];
    __shared__ float twc[32], tws[32];
    int t = threadIdx.x;
    int xy = blockIdx.x;
    for (int i = t; i < 2048; i += 256) hs[i>>6][i&63] = h[xy*2048 + i];
    if (t < 32) { float th = (float)t*(6.283185307179586f/32.f); twc[t]=cosf(th); tws[t]=sinf(th); }
    __syncthreads();
    const float inv = 1.0f/32768.0f;
    #pragma unroll
    for (int k = 0; k < 2; ++k) {
        int idx = t + k*256;
        int kz = idx >> 6, c = idx & 63;
        float re = 0.f, im = 0.f;
        for (int z = 0; z < 32; ++z) {
            int ph = (kz*z)&31;
            float v = hs[z][c];
            re += v*twc[ph];
            im -= v*tws[ph];
        }
        Fz[(xy*8+kz)*64 + c] = make_float2(re*inv, im*inv);
    }
}

// ---------------- stage Y: 32 y -> 16 kept ky modes ------------------------
__global__ __launch_bounds__(256) void k_fft_y(const float2* __restrict__ Fz,
                                               float2* __restrict__ Fzy)
{
    __shared__ float2 fs[32][64];
    __shared__ float twc[32], tws[32];
    int t = threadIdx.x;
    int x = blockIdx.x >> 3, kz = blockIdx.x & 7;
    for (int i = t; i < 2048; i += 256) {
        int y = i >> 6, c = i & 63;
        fs[y][c] = Fz[((x*32+y)*8 + kz)*64 + c];
    }
    if (t < 32) { float th = (float)t*(6.283185307179586f/32.f); twc[t]=cosf(th); tws[t]=sinf(th); }
    __syncthreads();
    #pragma unroll
    for (int k = 0; k < 4; ++k) {
        int idx = t + k*256;
        int kyi = idx >> 6, c = idx & 63;
        int ky = kyi < 8 ? kyi : kyi + 16;
        float re = 0.f, im = 0.f;
        for (int y = 0; y < 32; ++y) {
            int ph = (ky*y)&31;
            float cc = twc[ph], ss = tws[ph];
            float2 a = fs[y][c];
            re += a.x*cc + a.y*ss;
            im += a.y*cc - a.x*ss;
        }
        Fzy[((x*16+kyi)*8 + kz)*64 + c] = make_float2(re, im);
    }
}

// ---------------- stage X: 32 x -> 16 kept kx modes ------------------------
__global__ __launch_bounds__(256) void k_fft_x(const float2* __restrict__ Fzy,
                                               float2* __restrict__ Ft)
{
    __shared__ float2 fs[32][64];
    __shared__ float twc[32], tws[32];
    int t = threadIdx.x;
    int kyi = blockIdx.x >> 3, kz = blockIdx.x & 7;
    for (int i = t; i < 2048; i += 256) {
        int x = i >> 6, c = i & 63;
        fs[x][c] = Fzy[((x*16+kyi)*8 + kz)*64 + c];
    }
    if (t < 32) { float th = (float)t*(6.283185307179586f/32.f); twc[t]=cosf(th); tws[t]=sinf(th); }
    __syncthreads();
    #pragma unroll
    for (int k = 0; k < 4; ++k) {
        int idx = t + k*256;
        int kxi = idx >> 6, c = idx & 63;
        int kx = kxi < 8 ? kxi : kxi + 16;
        float re = 0.f, im = 0.f;
        for (int x = 0; x < 32; ++x) {
            int ph = (kx*x)&31;
            float cc = twc[ph], ss = tws[ph];
            float2 a = fs[x][c];
            re += a.x*cc + a.y*ss;
            im += a.y*cc - a.x*ss;
        }
        Ft[((kxi*16+kyi)*8 + kz)*64 + c] = make_float2(re, im);
    }
}

// ---------------- spectral multiply ----------------------------------------
__global__ __launch_bounds__(256) void k_spectral(const float2* __restrict__ Ft,
                                                  const float2* __restrict__ wp,
                                                  float2* __restrict__ Gt, int l)
{
    __shared__ float2 fts[64][65];
    int t = threadIdx.x;
    int corner = blockIdx.x >> 7;
    int mx = (blockIdx.x >> 4) & 7;
    int oc = blockIdx.x & 15;
    int kxi = mx + ((corner >> 1) << 3);
    int kyB = (corner & 1) << 3;
    {
        int i = t & 63;
        int m0 = (t >> 6) * 16;
        for (int mm = 0; mm < 16; ++mm) {
            int m = m0 + mm;
            int my = m >> 3, mz = m & 7;
            int row = (kxi*16 + (kyB + my))*8 + mz;
            fts[i][m] = Ft[row*64 + i];
        }
    }
    __syncthreads();
    int m = t & 63;
    int og = t >> 6;
    int o = oc*4 + og;
    size_t base = (size_t)(l*4 + corner)*2097152 + (size_t)mx*64 + m;
    float ar = 0.f, ai = 0.f;
    for (int i = 0; i < 64; ++i) {
        float2 ft = fts[i][m];
        float2 w = wp[base + (size_t)i*32768 + (size_t)o*512];
        ar += ft.x*w.x - ft.y*w.y;
        ai += ft.x*w.y + ft.y*w.x;
    }
    int my = m >> 3, mz = m & 7;
    int row = (kxi*16 + (kyB + my))*8 + mz;
    Gt[row*64 + o] = make_float2(ar, ai);
}

// ---------------- inverse stage X ------------------------------------------
__global__ __launch_bounds__(256) void k_inv_x(const float2* __restrict__ Gt,
                                               float2* __restrict__ G1)
{
    __shared__ float2 gs[16][64];
    __shared__ float twc[32], tws[32];
    int t = threadIdx.x;
    int kyi = blockIdx.x >> 3, kz = blockIdx.x & 7;
    for (int i = t; i < 1024; i += 256) {
        int kxi = i >> 6, o = i & 63;
        gs[kxi][o] = Gt[((kxi*16+kyi)*8 + kz)*64 + o];
    }
    if (t < 32) { float th = (float)t*(6.283185307179586f/32.f); twc[t]=cosf(th); tws[t]=sinf(th); }
    __syncthreads();
    #pragma unroll
    for (int k = 0; k < 8; ++k) {
        int idx = t + k*256;
        int x = idx >> 6, o = idx & 63;
        float re = 0.f, im = 0.f;
        for (int kxi = 0; kxi < 16; ++kxi) {
            int kx = kxi < 8 ? kxi : kxi + 16;
            int ph = (kx*x)&31;
            float cc = twc[ph], ss = tws[ph];
            float2 a = gs[kxi][o];
            re += a.x*cc - a.y*ss;
            im += a.x*ss + a.y*cc;
        }
        G1[((x*16+kyi)*8 + kz)*64 + o] = make_float2(re, im);
    }
}

// ---------------- inverse stage Y ------------------------------------------
__global__ __launch_bounds__(256) void k_inv_y(const float2* __restrict__ G1,
                                               float2* __restrict__ G2)
{
    __shared__ float2 gs[16][64];
    __shared__ float twc[32], tws[32];
    int t = threadIdx.x;
    int x = blockIdx.x >> 3, kz = blockIdx.x & 7;
    for (int i = t; i < 1024; i += 256) {
        int kyi = i >> 6, o = i & 63;
        gs[kyi][o] = G1[((x*16+kyi)*8 + kz)*64 + o];
    }
    if (t < 32) { float th = (float)t*(6.283185307179586f/32.f); twc[t]=cosf(th); tws[t]=sinf(th); }
    __syncthreads();
    #pragma unroll
    for (int k = 0; k < 8; ++k) {
        int idx = t + k*256;
        int y = idx >> 6, o = idx & 63;
        float re = 0.f, im = 0.f;
        for (int kyi = 0; kyi < 16; ++kyi) {
            int ky = kyi < 8 ? kyi : kyi + 16;
            int ph = (ky*y)&31;
            float cc = twc[ph], ss = tws[ph];
            float2 a = gs[kyi][o];
            re += a.x*cc - a.y*ss;
            im += a.x*ss + a.y*cc;
        }
        G2[((x*32+y)*8 + kz)*64 + o] = make_float2(re, im);
    }
}

// ---------------- inverse Z + skip GEMM + bias + (gelu) --------------------
__global__ __launch_bounds__(256) void k_inv_z_skip(const float2* __restrict__ G2,
                                                    const float* __restrict__ skw,
                                                    const float* __restrict__ skb,
                                                    float* __restrict__ h,
                                                    int l, int do_gelu)
{
    __shared__ float2 g2s[8][64];
    __shared__ float hs[32][64];
    __shared__ float wsk[64][64];
    __shared__ float twc[32], tws[32];
    __shared__ float bs[64];
    int t = threadIdx.x;
    int xy = blockIdx.x;
    for (int i = t; i < 512; i += 256) {
        int kz = i >> 6, o = i & 63;
        g2s[kz][o] = G2[(xy*8+kz)*64 + o];
    }
    for (int i = t; i < 2048; i += 256) hs[i>>6][i&63] = h[xy*2048 + i];
    for (int i = t; i < 4096; i += 256) wsk[i>>6][i&63] = skw[l*4096 + i];
    if (t < 64) bs[t] = skb[l*64 + t];
    if (t < 32) { float th = (float)t*(6.283185307179586f/32.f); twc[t]=cosf(th); tws[t]=sinf(th); }
    __syncthreads();
    int o = t & 63, z0 = t >> 6;
    for (int zz = 0; zz < 8; ++zz) {
        int z = z0 + zz*4;
        float s = g2s[0][o].x;
        #pragma unroll
        for (int kz = 1; kz < 8; ++kz) {
            int ph = (kz*z)&31;
            s += 2.0f*(g2s[kz][o].x*twc[ph] - g2s[kz][o].y*tws[ph]);
        }
        float a = bs[o];
        #pragma unroll 8
        for (int i = 0; i < 64; ++i) a += hs[z][i]*wsk[i][o];
        float v = s + a;
        if (do_gelu) v = gelu_f(v);
        h[(xy*32+z)*64 + o] = v;
    }
}

// ---------------- GNO weight prep: fp32 -> fp16 transposed -----------------
__global__ __launch_bounds__(256) void k_prep_w(const float* __restrict__ w2,
                                                const float* __restrict__ w3,
                                                _Float16* __restrict__ w2T,
                                                _Float16* __restrict__ w3T)
{
    int idx = blockIdx.x*256 + threadIdx.x;
    if (idx < 512*256) {
        int k = idx >> 8, n = idx & 255;
        w2T[n*512 + k] = (_Float16)w2[idx];
    } else {
        int j = idx - 512*256;
        if (j < 256*64) {
            int k = j >> 6, o = j & 63;
            w3T[o*256 + k] = (_Float16)w3[j];
        }
    }
}

// ---------------- GNO: point-owned, no global atomics ----------------------
// block = 16 points. Build edge list in LDS (<=112 edges), MLP per 32-edge
// tile (layer1 VALU, layers 2/3 fp16 MFMA), reduce k*latent into LDS, write
// num once with plain stores. Also writes per-point neighbor count (den).
__global__ __launch_bounds__(256) void k_gno(
    const float* __restrict__ out_p,
    const float* __restrict__ w1,      // [6][512]
    const float* __restrict__ b1,      // [512]
    const _Float16* __restrict__ w2T,  // [256][512]
    const float* __restrict__ b2,      // [256]
    const _Float16* __restrict__ w3T,  // [64][256]
    const float* __restrict__ b3,      // [64]
    const float* __restrict__ latent,  // [32768][64]
    float* __restrict__ numG,          // [16384][64]
    int* __restrict__ cntG)            // [16384]
{
    __shared__ _Float16 h1h[32*512];   // 32 KB
    __shared__ _Float16 h2h[32*256];   // 16 KB
    __shared__ float w1s[6*512];       // 12 KB
    __shared__ float b1s[512];         // 2 KB
    __shared__ float eAgg[128][6];     // 3 KB
    __shared__ int   eP[128];
    __shared__ int   eFlat[128];
    __shared__ float numL[16*64];      // 4 KB
    __shared__ int   cntS[16];
    __shared__ int   baseS[16];
    __shared__ int   EBs;

    int t = threadIdx.x;
    const float hg = 1.0f/31.0f;
    const float r2 = (float)(0.033*0.033);

    for (int i = t; i < 3072; i += 256) w1s[i] = w1[i];
    for (int i = t; i < 512;  i += 256) b1s[i] = b1[i];
    for (int i = t; i < 1024; i += 256) numL[i] = 0.f;

    // per-point candidate scan (deterministic, one thread per point)
    unsigned msk = 0;
    float px = 0.f, py = 0.f, pz = 0.f;
    int ix = 0, iy = 0, iz = 0;
    if (t < 16) {
        int n = blockIdx.x*16 + t;
        px = out_p[n*3+0]; py = out_p[n*3+1]; pz = out_p[n*3+2];
        ix = (int)rintf(px*31.f); iy = (int)rintf(py*31.f); iz = (int)rintf(pz*31.f);
        int cnt = 0;
        for (int j = 0; j < 27; ++j) {
            int dx = j/9 - 1, dy = (j/3)%3 - 1, dz = j%3 - 1;
            int cx = ix+dx, cy = iy+dy, cz = iz+dz;
            bool inb = (cx>=0)&&(cx<32)&&(cy>=0)&&(cy<32)&&(cz>=0)&&(cz<32);
            int qx = min(max(cx,0),31), qy = min(max(cy,0),31), qz = min(max(cz,0),31);
            float yx = qx*hg, yy = qy*hg, yz = qz*hg;
            float d2 = (px-yx)*(px-yx) + (py-yy)*(py-yy) + (pz-yz)*(pz-yz);
            if (inb && d2 <= r2) { msk |= 1u<<j; cnt++; }
        }
        cntS[t] = cnt;
        cntG[n] = cnt;
    }
    __syncthreads();
    if (t == 0) {
        int run = 0;
        for (int i = 0; i < 16; ++i) { baseS[i] = run; run += cntS[i]; }
        EBs = run;
    }
    __syncthreads();
    int EB = EBs;                      // <= 112 (max 7 edges/point)
    if (t < 16) {
        int k = baseS[t];
        for (int j = 0; j < 27; ++j) if (msk & (1u<<j)) {
            int dx = j/9 - 1, dy = (j/3)%3 - 1, dz = j%3 - 1;
            int cx = ix+dx, cy = iy+dy, cz = iz+dz;
            eP[k] = t;
            eFlat[k] = (cx*32+cy)*32 + cz;
            eAgg[k][0] = cx*hg; eAgg[k][1] = cy*hg; eAgg[k][2] = cz*hg;
            eAgg[k][3] = px;    eAgg[k][4] = py;    eAgg[k][5] = pz;
            ++k;
        }
    }
    if (t >= EB && t < 128) {          // zero padding edges (avoid NaN garbage)
        #pragma unroll
        for (int d = 0; d < 6; ++d) eAgg[t][d] = 0.f;
    }
    __syncthreads();

    int NT = (EB + 31) >> 5;
    int w = t >> 6, lane = t & 63;
    int l15 = lane & 15, g = lane >> 4;

    for (int tile = 0; tile < NT; ++tile) {
        int e0 = tile*32;
        // ---- layer1: 6 -> 512, gelu, fp16 swizzled into LDS ----
        {
            int m = t >> 3;
            int el = e0 + m;
            float a0 = eAgg[el][0], a1 = eAgg[el][1], a2 = eAgg[el][2];
            float a3 = eAgg[el][3], a4 = eAgg[el][4], a5 = eAgg[el][5];
            for (int r = 0; r < 8; ++r) {
                int c = (t & 7) + r*8;
                int j0 = c*8;
                f16x8 v;
                #pragma unroll
                for (int jj = 0; jj < 8; ++jj) {
                    int j = j0 + jj;
                    float a = b1s[j] + a0*w1s[j] + a1*w1s[512+j] + a2*w1s[1024+j]
                            + a3*w1s[1536+j] + a4*w1s[2048+j] + a5*w1s[2560+j];
                    v[jj] = (_Float16)gelu_f(a);
                }
                *(f16x8*)&h1h[m*512 + ((c ^ (m & 7))*8)] = v;
            }
        }
        __syncthreads();

        // ---- layer2: [32x512]x[512x256] MFMA, gelu -> h2h ----
        f32x4 acc2[2][4];
        #pragma unroll
        for (int nt = 0; nt < 4; ++nt) {
            float bb = b2[w*64 + nt*16 + l15];
            acc2[0][nt] = (f32x4){bb, bb, bb, bb};
            acc2[1][nt] = (f32x4){bb, bb, bb, bb};
        }
        for (int kk = 0; kk < 16; ++kk) {
            int chunk = kk*4 + g;
            f16x8 a0 = *(const f16x8*)&h1h[(l15     )*512 + ((chunk ^ (l15 & 7))*8)];
            f16x8 a1 = *(const f16x8*)&h1h[(16 + l15)*512 + ((chunk ^ (l15 & 7))*8)];
            #pragma unroll
            for (int nt = 0; nt < 4; ++nt) {
                int n = w*64 + nt*16 + l15;
                f16x8 b = *(const f16x8*)&w2T[(size_t)n*512 + kk*32 + g*8];
                acc2[0][nt] = __builtin_amdgcn_mfma_f32_16x16x32_f16(a0, b, acc2[0][nt], 0, 0, 0);
                acc2[1][nt] = __builtin_amdgcn_mfma_f32_16x16x32_f16(a1, b, acc2[1][nt], 0, 0, 0);
            }
        }
        #pragma unroll
        for (int mt = 0; mt < 2; ++mt)
          #pragma unroll
          for (int nt = 0; nt < 4; ++nt) {
            int n = w*64 + nt*16 + l15;
            #pragma unroll
            for (int r = 0; r < 4; ++r) {
                int m = mt*16 + g*4 + r;
                h2h[m*256 + (((n >> 3) ^ (m & 7))*8) + (n & 7)] =
                    (_Float16)gelu_f(acc2[mt][nt][r]);
            }
          }
        __syncthreads();

        // ---- layer3: [32x256]x[256x64] MFMA ----
        int o = w*16 + l15;
        f32x4 acc3[2];
        { float bb = b3[o]; acc3[0] = (f32x4){bb, bb, bb, bb}; acc3[1] = acc3[0]; }
        for (int kk = 0; kk < 8; ++kk) {
            f16x8 b = *(const f16x8*)&w3T[(size_t)o*256 + kk*32 + g*8];
            #pragma unroll
            for (int mt = 0; mt < 2; ++mt) {
                int chunk = kk*4 + g;
                f16x8 a = *(const f16x8*)&h2h[(mt*16 + l15)*256 + ((chunk ^ (l15 & 7))*8)];
                acc3[mt] = __builtin_amdgcn_mfma_f32_16x16x32_f16(a, b, acc3[mt], 0, 0, 0);
            }
        }

        // ---- epilogue: k * latent[flat] -> LDS reduce (ds_add_f32) ----
        #pragma unroll
        for (int mt = 0; mt < 2; ++mt) {
            #pragma unroll
            for (int r = 0; r < 4; ++r) {
                int el = e0 + mt*16 + g*4 + r;
                if (el < EB) {
                    int p = eP[el], fl = eFlat[el];
                    float fy = latent[(size_t)fl*64 + o];
                    atomicAdd(&numL[p*64 + o], acc3[mt][r] * fy);
                }
            }
        }
        __syncthreads();
    }

    // ---- write num once, coalesced ----
    for (int i = t; i < 1024; i += 256)
        numG[(size_t)blockIdx.x*1024 + i] = numL[i];
}

// ---------------- projection: num/den -> 256 (gelu) -> 1 -------------------
__global__ __launch_bounds__(256) void k_project(const float* __restrict__ num,
                                                 const int* __restrict__ eCnt,
                                                 const float* __restrict__ pw1,
                                                 const float* __restrict__ pb1,
                                                 const float* __restrict__ pw2,
                                                 const float* __restrict__ pb2,
                                                 float* __restrict__ outp)
{
    __shared__ float w1s[64*256];
    __shared__ float b1s[256];
    __shared__ float w2s[256];
    __shared__ float xv[64];
    __shared__ float red[4];
    int t = threadIdx.x;
    for (int i = t; i < 64*256; i += 256) w1s[i] = pw1[i];
    b1s[t] = pb1[t];
    w2s[t] = pw2[t];
    __syncthreads();
    for (int p = 0; p < 32; ++p) {
        int n = blockIdx.x*32 + p;
        if (t < 64) {
            float den = (float)max(eCnt[n], 1);
            xv[t] = num[n*64+t] / den;
        }
        __syncthreads();
        float a = b1s[t];
        #pragma unroll 8
        for (int i = 0; i < 64; ++i) a += xv[i]*w1s[i*256+t];
        float v = gelu_f(a) * w2s[t];
        #pragma unroll
        for (int off = 32; off > 0; off >>= 1) v += __shfl_down(v, off, 64);
        if ((t & 63) == 0) red[t>>6] = v;
        __syncthreads();
        if (t == 0) outp[n] = red[0]+red[1]+red[2]+red[3] + pb2[0];
        __syncthreads();
    }
}

// ---------------------------------------------------------------------------
extern "C" void kernel_launch(void* const* d_in, const int* in_sizes, int n_in,
                              void* d_out, int out_size, void* d_ws, size_t ws_size,
                              hipStream_t stream)
{
    const float* in_p = (const float*)d_in[0];
    const float* outp = (const float*)d_in[1];
    const float* f    = (const float*)d_in[2];
    const float* lw1  = (const float*)d_in[3];
    const float* lb1  = (const float*)d_in[4];
    const float* lw2  = (const float*)d_in[5];
    const float* lb2  = (const float*)d_in[6];
    const float* spw  = (const float*)d_in[7];
    const float* skw  = (const float*)d_in[8];
    const float* skb  = (const float*)d_in[9];
    const float* gw1  = (const float*)d_in[10];
    const float* gb1  = (const float*)d_in[11];
    const float* gw2  = (const float*)d_in[12];
    const float* gb2  = (const float*)d_in[13];
    const float* gw3  = (const float*)d_in[14];
    const float* gb3  = (const float*)d_in[15];
    const float* pw1  = (const float*)d_in[16];
    const float* pb1  = (const float*)d_in[17];
    const float* pw2  = (const float*)d_in[18];
    const float* pb2  = (const float*)d_in[19];

    float* ws = (float*)d_ws;
    float* hA = ws;                       // 2097152 floats
    float* SC = ws + 2097152;
    float2* Fz  = (float2*)(SC);
    float2* Fzy = (float2*)(SC + 1048576);
    float2* Ft  = (float2*)(SC + 1572864);
    float2* Gt  = (float2*)(SC + 1835008);
    float2* G1  = (float2*)(SC + 2097152);
    float2* G2  = (float2*)(SC + 2621440);
    // GNO overlay (used only after all FNO kernels completed)
    int*   cntG = (int*)SC;                          // 16384 ints
    float* numG = SC + 16384;                        // 1048576 floats
    _Float16* w2T  = (_Float16*)(SC + 2654272);      // 131072 halves
    _Float16* w3T  = w2T + 512*256;                  // 16384 halves

    k_lift<<<2048, 256, 0, stream>>>(f, in_p, lw1, lb1, lw2, lb2, hA);

    for (int l = 0; l < 4; ++l) {
        k_fft_z<<<1024, 256, 0, stream>>>(hA, Fz);
        k_fft_y<<<256, 256, 0, stream>>>(Fz, Fzy);
        k_fft_x<<<128, 256, 0, stream>>>(Fzy, Ft);
        k_spectral<<<512, 256, 0, stream>>>(Ft, (const float2*)spw, Gt, l);
        k_inv_x<<<128, 256, 0, stream>>>(Gt, G1);
        k_inv_y<<<256, 256, 0, stream>>>(G1, G2);
        k_inv_z_skip<<<1024, 256, 0, stream>>>(G2, skw, skb, hA, l, (l < 3) ? 1 : 0);
    }

    // GNO (strictly after FNO)
    k_prep_w<<<576, 256, 0, stream>>>(gw2, gw3, w2T, w3T);
    k_gno<<<1024, 256, 0, stream>>>(outp, gw1, gb1, w2T, gb2, w3T, gb3,
                                    hA, numG, cntG);
    k_project<<<512, 256, 0, stream>>>(numG, cntG, pw1, pb1, pw2, pb2, (float*)d_out);
}

// Round 4
// 544.738 us; speedup vs baseline: 1.6135x; 1.3367x over previous
//
#include <hip/hip_runtime.h>
#include <math.h>

// ---------------------------------------------------------------------------
// FNO-GNO round 4: full restructure.
//  FNO: 4 kernels/layer. h stored channel-major [64][32768], ping-pong buf0/1.
//   kA  k_fwd_zy : fused z+y partial DFT  -> F1[kyi][kz][x][c]
//   kAx k_fwd_x  : x DFT                  -> Ft[kxi][kyi][kz][i]   (r3 layout)
//   kB  k_spec   : spectral multiply, spec_w read ONCE, fully coalesced
//                  (contig axis [mx][my][mz][2] = lane axis) -> Gt
//   kC  k_inv_skip: fused inv-x + inv-y + inv-z + skip GEMM + gelu
//                  l<3 -> other c-major buffer ; l==3 -> latent point-major
//  GNO: k_gno, one kernel, deterministic, no atomics: 8 points/block, 8 slots
//   each (max neighbors=7) = M=64 MFMA tile; fp16 MFMA layers 2/3; 4 barriers;
//   wave-uniform w1 broadcast reads; padded+XOR LDS (kills 1.3e7 conflicts);
//   writes num pre-divided once, coalesced.
//
// Workspace (floats): buf0 2097152 | buf1 2097152 | SC:
//   FNO view:  F1 524288 | Ft 262144 | Gt 262144           (1048576)
//   GNO view:  num 1048576 | w2T 65536 | w3T 8192 | w1p 2048 (1124352)
// total 4194304 + 1124352 = 5318656 floats = 21.3 MB (< r1-r3's proven 23.07)
// ---------------------------------------------------------------------------

typedef _Float16 f16x8 __attribute__((ext_vector_type(8)));
typedef float f32x4 __attribute__((ext_vector_type(4)));

// fast gelu: exact-gelu via A&S 7.1.26 erf (|err| <= 1.5e-7), ~14 VALU ops
__device__ __forceinline__ float gelu_f(float x) {
    float t = fabsf(x) * 0.7071067811865475f;
    float k = __builtin_amdgcn_rcpf(1.0f + 0.3275911f * t);
    float e = __expf(-t * t);
    float y = k*(0.254829592f + k*(-0.284496736f + k*(1.421413741f +
              k*(-1.453152027f + k*1.061405429f))));
    float erfv = 1.0f - y * e;
    return 0.5f * x * (1.0f + copysignf(erfv, x));
}

// ---------------- weight prep: w2T/w3T/w1p fp16 ----------------------------
__global__ __launch_bounds__(256) void k_prep_w(const float* __restrict__ w2,
                                                const float* __restrict__ w3,
                                                const float* __restrict__ w1,
                                                const float* __restrict__ b1,
                                                _Float16* __restrict__ w2T,
                                                _Float16* __restrict__ w3T,
                                                _Float16* __restrict__ w1p)
{
    int idx = blockIdx.x*256 + threadIdx.x;
    if (idx < 131072) {                       // w2 [512][256] -> w2T [256][512]
        int k = idx >> 8, n = idx & 255;
        w2T[n*512 + k] = (_Float16)w2[idx];
    } else if (idx < 147456) {                // w3 [256][64] -> w3T [64][256]
        int j = idx - 131072;
        int k = j >> 6, o = j & 63;
        w3T[o*256 + k] = (_Float16)w3[j];
    } else if (idx < 151552) {                // w1 [6][512]+b1 -> w1p [512][8]
        int j = idx - 147456;
        int k = j >> 3, d = j & 7;
        float v = d < 6 ? w1[d*512 + k] : (d == 6 ? b1[k] : 0.0f);
        w1p[k*8 + d] = (_Float16)v;
    }
}

// ---------------- lifting -> h channel-major [64][32768] -------------------
__global__ __launch_bounds__(256) void k_lift(
    const float* __restrict__ f, const float* __restrict__ in_p,
    const float* __restrict__ w1, const float* __restrict__ b1,
    const float* __restrict__ w2, const float* __restrict__ b2,
    float* __restrict__ h)
{
    __shared__ float w1s[6*256];
    __shared__ float w2s[256*64];
    __shared__ float b1s[256];
    __shared__ float b2s[64];
    __shared__ float h1s[4][256];
    __shared__ float h2s[32*65];
    int t = threadIdx.x;
    for (int i = t; i < 6*256; i += 256) w1s[i] = w1[i];
    for (int i = t; i < 256*64; i += 256) w2s[i] = w2[i];
    b1s[t] = b1[t];
    if (t < 64) b2s[t] = b2[t];
    __syncthreads();
    int xy = blockIdx.x;                       // 1024 blocks, 32 z-points each
    int o = t & 63, q = t >> 6;
    for (int zz = 0; zz < 32; zz += 4) {
        for (int qq = 0; qq < 4; ++qq) {
            int p = xy*32 + zz + qq;
            float x0 = f[p*3+0], x1 = f[p*3+1], x2 = f[p*3+2];
            float x3 = in_p[p*3+0], x4 = in_p[p*3+1], x5 = in_p[p*3+2];
            float a = b1s[t]
                + x0*w1s[0*256+t] + x1*w1s[1*256+t] + x2*w1s[2*256+t]
                + x3*w1s[3*256+t] + x4*w1s[4*256+t] + x5*w1s[5*256+t];
            h1s[qq][t] = gelu_f(a);
        }
        __syncthreads();
        {
            float acc = b2s[o];
            #pragma unroll 8
            for (int j = 0; j < 256; ++j) acc += h1s[q][j]*w2s[j*64+o];
            h2s[(zz + q)*65 + o] = acc;
        }
        __syncthreads();
    }
    for (int i = t; i < 2048; i += 256) {
        int c = i >> 5, z = i & 31;
        h[c*32768 + xy*32 + z] = h2s[z*65 + c];
    }
}

// ---------------- kA: fused z+y forward DFT --------------------------------
// grid 256 = (x 32) x (cg 8). out F1[kyi16][kz8][x32][c64]
__global__ __launch_bounds__(256) void k_fwd_zy(const float* __restrict__ h,
                                                float2* __restrict__ F1)
{
    __shared__ float pl[8*1056];        // [c][y 32][z 33-pad]
    __shared__ float2 fz[32*73];        // idx y*73 + kz*9 + c
    __shared__ float twc[32], tws[32];
    int t = threadIdx.x;
    int x = blockIdx.x >> 3, cg = blockIdx.x & 7;
    for (int i = t; i < 8192; i += 256) {
        int c = i >> 10, yz = i & 1023;
        pl[c*1056 + (yz>>5)*33 + (yz&31)] = h[(cg*8 + c)*32768 + x*1024 + yz];
    }
    if (t < 32) { float th = (float)t*(6.283185307179586f/32.f); twc[t]=cosf(th); tws[t]=sinf(th); }
    __syncthreads();
    {   // z-stage (real -> 8 modes), applies 1/32768 (norm='forward')
        int c = t >> 5, y = t & 31;
        float zv[32];
        #pragma unroll
        for (int z = 0; z < 32; ++z) zv[z] = pl[c*1056 + y*33 + z];
        const float inv = 1.0f/32768.0f;
        #pragma unroll
        for (int kz = 0; kz < 8; ++kz) {
            float re = 0.f, im = 0.f;
            #pragma unroll
            for (int z = 0; z < 32; ++z) {
                int ph = (kz*z)&31;
                re += zv[z]*twc[ph];
                im -= zv[z]*tws[ph];
            }
            fz[y*73 + kz*9 + c] = make_float2(re*inv, im*inv);
        }
    }
    __syncthreads();
    // y-stage: 32 y -> 16 kept ky
    #pragma unroll
    for (int ko = 0; ko < 4; ++ko) {
        int idx = ko*256 + t;
        int kyi = idx >> 6, kz = (idx >> 3) & 7, c = idx & 7;
        int ky = kyi < 8 ? kyi : kyi + 16;
        float re = 0.f, im = 0.f;
        for (int y = 0; y < 32; ++y) {
            int ph = (ky*y)&31;
            float cc = twc[ph], ss = tws[ph];
            float2 a = fz[y*73 + kz*9 + c];
            re += a.x*cc + a.y*ss;
            im += a.y*cc - a.x*ss;
        }
        F1[((kyi*8 + kz)*32 + x)*64 + cg*8 + c] = make_float2(re, im);
    }
}

// ---------------- kAx: x forward DFT ---------------------------------------
// grid 128 = (kyi 16) x (kz 8). out Ft[(kxi*16+kyi)*8+kz][i]
__global__ __launch_bounds__(256) void k_fwd_x(const float2* __restrict__ F1,
                                               float2* __restrict__ Ft)
{
    __shared__ float2 fs[32*65];
    __shared__ float twc[32], tws[32];
    int t = threadIdx.x;
    int kyi = blockIdx.x >> 3, kz = blockIdx.x & 7;
    const float2* src = &F1[(size_t)((kyi*8 + kz)*32)*64];
    for (int i = t; i < 2048; i += 256) fs[(i>>6)*65 + (i&63)] = src[i];
    if (t < 32) { float th = (float)t*(6.283185307179586f/32.f); twc[t]=cosf(th); tws[t]=sinf(th); }
    __syncthreads();
    #pragma unroll
    for (int ko = 0; ko < 4; ++ko) {
        int idx = ko*256 + t;
        int kxi = idx >> 6, ii = idx & 63;
        int kx = kxi < 8 ? kxi : kxi + 16;
        float re = 0.f, im = 0.f;
        for (int xx = 0; xx < 32; ++xx) {
            int ph = (kx*xx)&31;
            float cc = twc[ph], ss = tws[ph];
            float2 a = fs[xx*65 + ii];
            re += a.x*cc + a.y*ss;
            im += a.y*cc - a.x*ss;
        }
        Ft[((kxi*16 + kyi)*8 + kz)*64 + ii] = make_float2(re, im);
    }
}

// ---------------- kB: spectral multiply, W read once & coalesced -----------
// grid 512 = (og 16) x (corner 4) x (mx 8); thread = (o = t>>6 of 4, mode = t&63)
// Gt layout: [og][corner][mx][mode(my*8+mz)][o] complex
__global__ __launch_bounds__(256) void k_spec(const float2* __restrict__ Ft,
                                              const float* __restrict__ spw,
                                              float2* __restrict__ Gt, int l)
{
    __shared__ float2 ft[64*65];        // [i][mode] pad
    int t = threadIdx.x;
    int og = blockIdx.x >> 5, corner = (blockIdx.x >> 3) & 3, mx = blockIdx.x & 7;
    int kxi = mx + (corner >> 1)*8;
    int kyB = (corner & 1)*8;
    {   // stage Ft rows -> [i][mode] transposed
        int m = t >> 2, iq = t & 3;
        int my = m >> 3, mz = m & 7;
        const float2* src = &Ft[(size_t)((kxi*16 + kyB + my)*8 + mz)*64];
        #pragma unroll
        for (int ii = 0; ii < 16; ++ii) {
            int i = iq*16 + ii;
            ft[i*65 + m] = src[i];
        }
    }
    __syncthreads();
    int mode = t & 63, o = t >> 6;
    size_t wbase = (size_t)(l*4 + corner)*4194304 + (size_t)(og*4 + o)*1024
                 + (size_t)mx*128 + mode*2;
    float ar = 0.f, ai = 0.f;
    for (int i8 = 0; i8 < 64; i8 += 8) {
        float2 wv[8];
        #pragma unroll
        for (int u = 0; u < 8; ++u)
            wv[u] = *(const float2*)&spw[wbase + (size_t)(i8+u)*65536];
        #pragma unroll
        for (int u = 0; u < 8; ++u) {
            float2 fv = ft[(i8+u)*65 + mode];
            ar += fv.x*wv[u].x - fv.y*wv[u].y;
            ai += fv.x*wv[u].y + fv.y*wv[u].x;
        }
    }
    Gt[(size_t)(((og*4 + corner)*8 + mx)*64 + mode)*4 + o] = make_float2(ar, ai);
}

// ---------------- kC: fused inv-x + inv-y + inv-z + skip + gelu ------------
// grid 512 = (x 32) x (og 16)
__global__ __launch_bounds__(256) void k_inv_skip(const float2* __restrict__ Gt,
                                                  const float* __restrict__ hold,
                                                  const float* __restrict__ skw,
                                                  const float* __restrict__ skb,
                                                  float* __restrict__ hnew,
                                                  float* __restrict__ latent,
                                                  int l)
{
    __shared__ float2 gt[8192];         // 64 KB  [corner][mx][mode][o]
    __shared__ float2 s1[16*8*4];       // [kyi][kz][o]
    __shared__ float2 s2[32*8*4];       // [y][kz][o]
    __shared__ float  skws[256];        // [i][o]
    __shared__ float twc[32], tws[32];
    int t = threadIdx.x;
    int x = blockIdx.x >> 4, og = blockIdx.x & 15;
    const float2* gsrc = &Gt[(size_t)og*8192];
    for (int i = t; i < 8192; i += 256) gt[i] = gsrc[i];
    skws[t] = skw[l*4096 + (t>>2)*64 + og*4 + (t&3)];
    if (t < 32) { float th = (float)t*(6.283185307179586f/32.f); twc[t]=cosf(th); tws[t]=sinf(th); }
    __syncthreads();
    // phase A: inv-x (16 kx -> this x) : S1[kyi][kz][o]
    #pragma unroll
    for (int ko = 0; ko < 2; ++ko) {
        int idx = ko*256 + t;
        int kyi = idx >> 5, kz = (idx >> 2) & 7, o = idx & 3;
        int cy = kyi >> 3, my = kyi & 7;
        float re = 0.f, im = 0.f;
        #pragma unroll
        for (int cxh = 0; cxh < 2; ++cxh) {
            int corner = cxh*2 + cy;
            #pragma unroll
            for (int mxx = 0; mxx < 8; ++mxx) {
                int kxi = cxh*8 + mxx;
                int kx = kxi < 8 ? kxi : kxi + 16;
                int ph = (kx * x) & 31;
                float cc = twc[ph], ss = tws[ph];
                float2 a = gt[((corner*8 + mxx)*64 + my*8 + kz)*4 + o];
                re += a.x*cc - a.y*ss;
                im += a.x*ss + a.y*cc;
            }
        }
        s1[(kyi*8 + kz)*4 + o] = make_float2(re, im);
    }
    __syncthreads();
    // phase B: inv-y : S2[y][kz][o]
    #pragma unroll
    for (int ko = 0; ko < 4; ++ko) {
        int idx = ko*256 + t;
        int y = idx >> 5, kz = (idx >> 2) & 7, o = idx & 3;
        float re = 0.f, im = 0.f;
        #pragma unroll
        for (int kyi = 0; kyi < 16; ++kyi) {
            int ky = kyi < 8 ? kyi : kyi + 16;
            int ph = (ky*y) & 31;
            float cc = twc[ph], ss = tws[ph];
            float2 a = s1[(kyi*8 + kz)*4 + o];
            re += a.x*cc - a.y*ss;
            im += a.x*ss + a.y*cc;
        }
        s2[(y*8 + kz)*4 + o] = make_float2(re, im);
    }
    __syncthreads();
    // phase C: skip GEMM (64 i) + inv-z + gelu + write (thread owns 4 points)
    float acc[4][4];
    #pragma unroll
    for (int pp = 0; pp < 4; ++pp)
        #pragma unroll
        for (int o = 0; o < 4; ++o) acc[pp][o] = skb[l*64 + og*4 + o];
    const float* hsrc = &hold[x*1024 + t*4];
    for (int i = 0; i < 64; ++i) {
        float4 hv = *(const float4*)&hsrc[(size_t)i*32768];
        #pragma unroll
        for (int o = 0; o < 4; ++o) {
            float wv = skws[i*4 + o];
            acc[0][o] += hv.x*wv; acc[1][o] += hv.y*wv;
            acc[2][o] += hv.z*wv; acc[3][o] += hv.w*wv;
        }
    }
    float outv[4][4];
    #pragma unroll
    for (int pp = 0; pp < 4; ++pp) {
        int pt = t*4 + pp;
        int y = pt >> 5, z = pt & 31;
        #pragma unroll
        for (int o = 0; o < 4; ++o) {
            float s = s2[(y*8)*4 + o].x;       // kz=0: Re only (imag discarded)
            #pragma unroll
            for (int kz = 1; kz < 8; ++kz) {
                int ph = (kz*z) & 31;
                float2 a = s2[(y*8 + kz)*4 + o];
                s += 2.0f*(a.x*twc[ph] - a.y*tws[ph]);
            }
            float v = s + acc[pp][o];
            outv[pp][o] = (l < 3) ? gelu_f(v) : v;
        }
    }
    if (l < 3) {
        #pragma unroll
        for (int o = 0; o < 4; ++o) {
            float4 w4 = make_float4(outv[0][o], outv[1][o], outv[2][o], outv[3][o]);
            *(float4*)&hnew[(size_t)(og*4 + o)*32768 + x*1024 + t*4] = w4;
        }
    } else {
        #pragma unroll
        for (int pp = 0; pp < 4; ++pp) {
            float4 w4 = make_float4(outv[pp][0], outv[pp][1], outv[pp][2], outv[pp][3]);
            *(float4*)&latent[(size_t)(x*1024 + t*4 + pp)*64 + og*4] = w4;
        }
    }
}

// ---------------- k_gno: point-owned, padded-slot, no atomics --------------
// block = 8 points x 8 slots = M=64 MFMA tile; 256 thr (4 waves);
// wave w owns n-range w*64 (L2) and o-range w*16 (L3). Writes num pre-divided.
__global__ __launch_bounds__(256, 2) void k_gno(
    const float* __restrict__ out_p,
    const _Float16* __restrict__ w1p,  // [512][8] {w0..w5,b,0}
    const _Float16* __restrict__ w2T,  // [256][512]
    const float* __restrict__ b2,      // [256]
    const _Float16* __restrict__ w3T,  // [64][256]
    const float* __restrict__ b3,      // [64]
    const float* __restrict__ latent,  // [32768][64]
    float* __restrict__ num)           // [16384][64] (pre-divided)
{
    __shared__ __align__(16) _Float16 h1pool[64*520];  // h1 [64][512]+pad, aliased by h2 [64][256]+pad
    __shared__ __align__(16) _Float16 w1s[512*8];
    __shared__ int   flatS[64];
    __shared__ float validS[64];
    __shared__ float cntS[8];
    _Float16* h2h = h1pool;

    int t = threadIdx.x;
    const float hg = 1.0f/31.0f;
    const float r2 = (float)(0.033*0.033);

    for (int i = t; i < 512; i += 256)
        ((int4*)w1s)[i] = ((const int4*)w1p)[i];

    // slot scan: e = t&63 -> point blockIdx*8 + e>>3, slot e&7 (max cnt = 7)
    int e = t & 63;
    int p = blockIdx.x*8 + (e >> 3);
    int slot = e & 7;
    float px = out_p[p*3+0], py = out_p[p*3+1], pz = out_p[p*3+2];
    int ix = (int)rintf(px*31.f), iy = (int)rintf(py*31.f), iz = (int)rintf(pz*31.f);
    int found = -1, cnt = 0;
    for (int j = 0; j < 27; ++j) {
        int dx = j/9 - 1, dy = (j/3)%3 - 1, dz = j%3 - 1;
        int cx = ix+dx, cy = iy+dy, cz = iz+dz;
        bool inb = (cx>=0)&&(cx<32)&&(cy>=0)&&(cy<32)&&(cz>=0)&&(cz<32);
        int qx = min(max(cx,0),31), qy = min(max(cy,0),31), qz = min(max(cz,0),31);
        float yx = qx*hg, yy = qy*hg, yz = qz*hg;
        float d2 = (px-yx)*(px-yx) + (py-yy)*(py-yy) + (pz-yz)*(pz-yz);
        if (inb && d2 <= r2) { if (cnt == slot) found = j; cnt++; }
    }
    float a0=0.f,a1=0.f,a2=0.f,a3=0.f,a4=0.f,a5=0.f;
    int fl = 0; float val = 0.f;
    if (found >= 0) {
        int dx = found/9 - 1, dy = (found/3)%3 - 1, dz = found%3 - 1;
        int cx = ix+dx, cy = iy+dy, cz = iz+dz;
        fl = (cx*32 + cy)*32 + cz;
        a0 = cx*hg; a1 = cy*hg; a2 = cz*hg; a3 = px; a4 = py; a5 = pz;
        val = 1.f;
    }
    if (t < 64) {
        flatS[e] = fl; validS[e] = val;
        if (slot == 0) cntS[e >> 3] = (float)cnt;
    }
    __syncthreads();

    int w = t >> 6;                 // wave id
    // ---- layer1: lane owns edge e, wave owns k-quarter; w1 reads broadcast
    {
        int xk = (e >> 3) & 7;      // row XOR key
        #pragma unroll
        for (int ci = 0; ci < 16; ++ci) {
            int c = w*16 + ci;
            f16x8 v;
            #pragma unroll
            for (int jj = 0; jj < 8; ++jj) {
                int k = c*8 + jj;
                f16x8 wv = *(const f16x8*)&w1s[k*8];
                float pre = (float)wv[6]
                    + a0*(float)wv[0] + a1*(float)wv[1] + a2*(float)wv[2]
                    + a3*(float)wv[3] + a4*(float)wv[4] + a5*(float)wv[5];
                v[jj] = (_Float16)gelu_f(pre);
            }
            *(f16x8*)&h1pool[e*520 + ((c ^ xk)*8)] = v;
        }
    }
    __syncthreads();

    int lane = t & 63;
    int l15 = lane & 15, g = lane >> 4;

    // ---- layer2: [64 x 512] x [512 x 64-per-wave] fp16 MFMA
    f32x4 acc2[4][4];
    #pragma unroll
    for (int nt = 0; nt < 4; ++nt) {
        float bb = b2[w*64 + nt*16 + l15];
        #pragma unroll
        for (int mt = 0; mt < 4; ++mt) acc2[mt][nt] = (f32x4){bb, bb, bb, bb};
    }
    #pragma unroll 4
    for (int kk = 0; kk < 16; ++kk) {
        f16x8 af[4];
        #pragma unroll
        for (int mt = 0; mt < 4; ++mt) {
            int ee = mt*16 + l15;
            af[mt] = *(const f16x8*)&h1pool[ee*520 + (((kk*4 + g) ^ ((ee>>3)&7))*8)];
        }
        #pragma unroll
        for (int nt = 0; nt < 4; ++nt) {
            f16x8 bf = *(const f16x8*)&w2T[(size_t)(w*64 + nt*16 + l15)*512 + kk*32 + g*8];
            #pragma unroll
            for (int mt = 0; mt < 4; ++mt)
                acc2[mt][nt] = __builtin_amdgcn_mfma_f32_16x16x32_f16(af[mt], bf, acc2[mt][nt], 0, 0, 0);
        }
    }
    __syncthreads();   // h1 reads done; h2 aliases h1
    // gelu + transpose-store h2 (XOR-swizzled, row pad 264)
    #pragma unroll
    for (int mt = 0; mt < 4; ++mt)
      #pragma unroll
      for (int nt = 0; nt < 4; ++nt) {
        int n = w*64 + nt*16 + l15;
        #pragma unroll
        for (int r = 0; r < 4; ++r) {
            int m = mt*16 + g*4 + r;
            h2h[m*264 + (((n>>3) ^ (m&7))*8) + (n&7)] = (_Float16)gelu_f(acc2[mt][nt][r]);
        }
      }
    __syncthreads();

    // ---- layer3: [64 x 256] x [256 x 16-per-wave]
    int o = w*16 + l15;
    f32x4 acc3[4];
    { float bb = b3[o];
      #pragma unroll
      for (int mt = 0; mt < 4; ++mt) acc3[mt] = (f32x4){bb, bb, bb, bb}; }
    #pragma unroll 2
    for (int kk2 = 0; kk2 < 8; ++kk2) {
        f16x8 bf = *(const f16x8*)&w3T[(size_t)o*256 + kk2*32 + g*8];
        #pragma unroll
        for (int mt = 0; mt < 4; ++mt) {
            int ee = mt*16 + l15;
            f16x8 af = *(const f16x8*)&h2h[ee*264 + (((kk2*4 + g) ^ (ee&7))*8)];
            acc3[mt] = __builtin_amdgcn_mfma_f32_16x16x32_f16(af, bf, acc3[mt], 0, 0, 0);
        }
    }

    // ---- epilogue: k*latent, per-point reduce (in-wave), write pre-divided
    #pragma unroll
    for (int mt = 0; mt < 4; ++mt) {
        float psum = 0.f;
        #pragma unroll
        for (int r = 0; r < 4; ++r) {
            int ee = mt*16 + g*4 + r;
            float fy = latent[(size_t)flatS[ee]*64 + o];
            psum += acc3[mt][r] * fy * validS[ee];
        }
        psum += __shfl_xor(psum, 16, 64);     // g0+g1 (even pt), g2+g3 (odd pt)
        if ((g & 1) == 0) {
            int pt = mt*2 + (g >> 1);
            float den = fmaxf(cntS[pt], 1.0f);
            num[(size_t)(blockIdx.x*8 + pt)*64 + o] = psum / den;
        }
    }
}

// ---------------- projection: num -> 256 (gelu) -> 1 -----------------------
__global__ __launch_bounds__(256) void k_project(const float* __restrict__ num,
                                                 const float* __restrict__ pw1,
                                                 const float* __restrict__ pb1,
                                                 const float* __restrict__ pw2,
                                                 const float* __restrict__ pb2,
                                                 float* __restrict__ outp)
{
    __shared__ float w1s[64*256];
    __shared__ float b1s[256];
    __shared__ float w2s[256];
    __shared__ float xv[64];
    __shared__ float red[4];
    int t = threadIdx.x;
    for (int i = t; i < 64*256; i += 256) w1s[i] = pw1[i];
    b1s[t] = pb1[t];
    w2s[t] = pw2[t];
    __syncthreads();
    for (int pq = 0; pq < 32; ++pq) {
        int n = blockIdx.x*32 + pq;
        if (t < 64) xv[t] = num[n*64 + t];
        __syncthreads();
        float a = b1s[t];
        #pragma unroll 8
        for (int i = 0; i < 64; ++i) a += xv[i]*w1s[i*256+t];
        float v = gelu_f(a) * w2s[t];
        #pragma unroll
        for (int off = 32; off > 0; off >>= 1) v += __shfl_down(v, off, 64);
        if ((t & 63) == 0) red[t>>6] = v;
        __syncthreads();
        if (t == 0) outp[n] = red[0]+red[1]+red[2]+red[3] + pb2[0];
        __syncthreads();
    }
}

// ---------------------------------------------------------------------------
extern "C" void kernel_launch(void* const* d_in, const int* in_sizes, int n_in,
                              void* d_out, int out_size, void* d_ws, size_t ws_size,
                              hipStream_t stream)
{
    const float* in_p = (const float*)d_in[0];
    const float* outp = (const float*)d_in[1];
    const float* f    = (const float*)d_in[2];
    const float* lw1  = (const float*)d_in[3];
    const float* lb1  = (const float*)d_in[4];
    const float* lw2  = (const float*)d_in[5];
    const float* lb2  = (const float*)d_in[6];
    const float* spw  = (const float*)d_in[7];
    const float* skw  = (const float*)d_in[8];
    const float* skb  = (const float*)d_in[9];
    const float* gw1  = (const float*)d_in[10];
    const float* gb1  = (const float*)d_in[11];
    const float* gw2  = (const float*)d_in[12];
    const float* gb2  = (const float*)d_in[13];
    const float* gw3  = (const float*)d_in[14];
    const float* gb3  = (const float*)d_in[15];
    const float* pw1  = (const float*)d_in[16];
    const float* pb1  = (const float*)d_in[17];
    const float* pw2  = (const float*)d_in[18];
    const float* pb2  = (const float*)d_in[19];

    float* ws   = (float*)d_ws;
    float* buf0 = ws;                          // 2097152 f (c-major h / final latent point-major)
    float* buf1 = ws + 2097152;                // 2097152 f
    float* SC   = ws + 4194304;
    float2* F1 = (float2*)SC;                  // 262144 c64
    float2* Ft = (float2*)(SC + 524288);       // 131072 c64
    float2* Gt = (float2*)(SC + 786432);       // 131072 c64
    float* numb = SC;                          // 1048576 f (aliases F1/Ft/Gt, GNO phase only)
    _Float16* w2T = (_Float16*)(SC + 1048576); // 131072 h
    _Float16* w3T = (_Float16*)(SC + 1114112); // 16384 h
    _Float16* w1p = (_Float16*)(SC + 1122304); // 4096 h

    k_prep_w<<<592, 256, 0, stream>>>(gw2, gw3, gw1, gb1, w2T, w3T, w1p);
    k_lift<<<1024, 256, 0, stream>>>(f, in_p, lw1, lb1, lw2, lb2, buf0);

    for (int l = 0; l < 4; ++l) {
        const float* hin = (l & 1) ? buf1 : buf0;
        float* hout = (l & 1) ? buf0 : buf1;
        k_fwd_zy<<<256, 256, 0, stream>>>(hin, F1);
        k_fwd_x<<<128, 256, 0, stream>>>(F1, Ft);
        k_spec<<<512, 256, 0, stream>>>(Ft, spw, Gt, l);
        k_inv_skip<<<512, 256, 0, stream>>>(Gt, hin, skw, skb, hout, buf0, l);
    }
    // latent = buf0 (point-major, written by kC at l=3)

    k_gno<<<2048, 256, 0, stream>>>(outp, w1p, w2T, gb2, w3T, gb3, buf0, numb);
    k_project<<<512, 256, 0, stream>>>(numb, pw1, pb1, pw2, pb2, (float*)d_out);
}

// Round 5
// 430.224 us; speedup vs baseline: 2.0430x; 1.2662x over previous
//
#include <hip/hip_runtime.h>
#include <math.h>

// ---------------------------------------------------------------------------
// FNO-GNO round 5: r4 + lift/project de-bottlenecked.
//  - k_lift: split-fp16 (hi+lo) MFMA GEMM for the K=256 layer (3 MFMA per
//    fragment, error ~2^-22 => fp32-equivalent). Was LDS-throughput-bound
//    fp32 (1 ds_read_b32 per FMA).
//  - k_project: fp32 register-blocked 4x4 (float4 LDS reads, broadcast
//    banks). Exact fp32.
//  - FNO chain and k_gno identical to round 4 (passing, absmax 2.44e-4).
//
// Workspace (floats): buf0 2097152 | buf1 2097152 | SC:
//   FNO view:  F1 524288 | Ft 262144 | Gt 262144            (1048576)
//   GNO view:  num 1048576
//   weights:   w2T @1048576 (65536f) | w3T @1114112 (8192f) | w1p @1122304
//              (2048f) | l2hi @1124352 (8192f) | l2lo @1132544 (8192f)
// total = 4194304 + 1140736 = 5335040 floats = 21.34 MB
// ---------------------------------------------------------------------------

typedef _Float16 f16x8 __attribute__((ext_vector_type(8)));
typedef float f32x4 __attribute__((ext_vector_type(4)));

// fast gelu: exact-gelu via A&S 7.1.26 erf (|err| <= 1.5e-7)
__device__ __forceinline__ float gelu_f(float x) {
    float t = fabsf(x) * 0.7071067811865475f;
    float k = __builtin_amdgcn_rcpf(1.0f + 0.3275911f * t);
    float e = __expf(-t * t);
    float y = k*(0.254829592f + k*(-0.284496736f + k*(1.421413741f +
              k*(-1.453152027f + k*1.061405429f))));
    float erfv = 1.0f - y * e;
    return 0.5f * x * (1.0f + copysignf(erfv, x));
}

// ---------------- weight prep: w2T/w3T/w1p fp16, lift-W2 split-fp16 --------
__global__ __launch_bounds__(256) void k_prep_w(const float* __restrict__ w2,
                                                const float* __restrict__ w3,
                                                const float* __restrict__ w1,
                                                const float* __restrict__ b1,
                                                const float* __restrict__ lw2,
                                                _Float16* __restrict__ w2T,
                                                _Float16* __restrict__ w3T,
                                                _Float16* __restrict__ w1p,
                                                _Float16* __restrict__ l2hi,
                                                _Float16* __restrict__ l2lo)
{
    int idx = blockIdx.x*256 + threadIdx.x;
    if (idx < 131072) {                       // w2 [512][256] -> w2T [256][512]
        int k = idx >> 8, n = idx & 255;
        w2T[n*512 + k] = (_Float16)w2[idx];
    } else if (idx < 147456) {                // w3 [256][64] -> w3T [64][256]
        int j = idx - 131072;
        int k = j >> 6, o = j & 63;
        w3T[o*256 + k] = (_Float16)w3[j];
    } else if (idx < 151552) {                // w1 [6][512]+b1 -> w1p [512][8]
        int j = idx - 147456;
        int k = j >> 3, d = j & 7;
        float v = d < 6 ? w1[d*512 + k] : (d == 6 ? b1[k] : 0.0f);
        w1p[k*8 + d] = (_Float16)v;
    } else if (idx < 167936) {                // lw2 [256][64] -> split [64][256]
        int j = idx - 151552;
        int o = j >> 8, k = j & 255;
        float v = lw2[k*64 + o];
        _Float16 hi = (_Float16)v;
        l2hi[j] = hi;
        l2lo[j] = (_Float16)(v - (float)hi);
    }
}

// ---------------- lifting via split-fp16 MFMA ------------------------------
// grid 512 x 64 points; wave w owns pts w*16..+15. Output h c-major [64][32768].
__global__ __launch_bounds__(256) void k_lift(
    const float* __restrict__ f, const float* __restrict__ in_p,
    const float* __restrict__ w1, const float* __restrict__ b1,   // [6][256],[256]
    const _Float16* __restrict__ l2hi,  // [64][256] (o-major)
    const _Float16* __restrict__ l2lo,
    const float* __restrict__ b2,       // [64]
    float* __restrict__ h)
{
    __shared__ __align__(16) _Float16 h1hi[64*264];   // 33.8 KB
    __shared__ __align__(16) _Float16 h1lo[64*264];   // 33.8 KB
    __shared__ float w1s[6*256];
    __shared__ float b1s[256];
    float* oT = (float*)h1hi;          // aliased after barrier: [64][68] fp32
    int t = threadIdx.x;
    for (int i = t; i < 1536; i += 256) w1s[i] = w1[i];
    b1s[t] = b1[t];
    int p0 = blockIdx.x * 64;
    int pt = t >> 2, jq = t & 3;
    int p = p0 + pt;
    float x0 = f[p*3+0], x1 = f[p*3+1], x2 = f[p*3+2];
    float x3 = in_p[p*3+0], x4 = in_p[p*3+1], x5 = in_p[p*3+2];
    __syncthreads();
    // layer1 (K=6) fp32 + gelu + split-fp16 store
    for (int r = 0; r < 8; ++r) {
        int j0 = jq*64 + r*8;
        f16x8 vh, vl;
        #pragma unroll
        for (int jj = 0; jj < 8; ++jj) {
            int j = j0 + jj;
            float a = b1s[j] + x0*w1s[j] + x1*w1s[256+j] + x2*w1s[512+j]
                    + x3*w1s[768+j] + x4*w1s[1024+j] + x5*w1s[1280+j];
            float g = gelu_f(a);
            _Float16 hi = (_Float16)g;
            vh[jj] = hi;
            vl[jj] = (_Float16)(g - (float)hi);
        }
        *(f16x8*)&h1hi[pt*264 + j0] = vh;
        *(f16x8*)&h1lo[pt*264 + j0] = vl;
    }
    __syncthreads();
    // GEMM2: M=64 (16/wave), N=64, K=256, split-fp16 (3 MFMA)
    int w = t >> 6, lane = t & 63, l15 = lane & 15, g = lane >> 4;
    f32x4 acc[4];
    #pragma unroll
    for (int nt = 0; nt < 4; ++nt) {
        float bb = b2[nt*16 + l15];
        acc[nt] = (f32x4){bb, bb, bb, bb};
    }
    for (int kk = 0; kk < 8; ++kk) {
        f16x8 ah = *(const f16x8*)&h1hi[(w*16+l15)*264 + kk*32 + g*8];
        f16x8 al = *(const f16x8*)&h1lo[(w*16+l15)*264 + kk*32 + g*8];
        #pragma unroll
        for (int nt = 0; nt < 4; ++nt) {
            f16x8 bh = *(const f16x8*)&l2hi[(nt*16+l15)*256 + kk*32 + g*8];
            f16x8 bl = *(const f16x8*)&l2lo[(nt*16+l15)*256 + kk*32 + g*8];
            acc[nt] = __builtin_amdgcn_mfma_f32_16x16x32_f16(al, bh, acc[nt], 0, 0, 0);
            acc[nt] = __builtin_amdgcn_mfma_f32_16x16x32_f16(ah, bl, acc[nt], 0, 0, 0);
            acc[nt] = __builtin_amdgcn_mfma_f32_16x16x32_f16(ah, bh, acc[nt], 0, 0, 0);
        }
    }
    __syncthreads();   // all MFMA A-reads done; oT aliases h1hi
    #pragma unroll
    for (int nt = 0; nt < 4; ++nt)
        #pragma unroll
        for (int r = 0; r < 4; ++r)
            oT[(nt*16 + l15)*68 + w*16 + g*4 + r] = acc[nt][r];
    __syncthreads();
    for (int i = t; i < 4096; i += 256) {
        int c = i >> 6, ptl = i & 63;
        h[(size_t)c*32768 + p0 + ptl] = oT[c*68 + ptl];
    }
}

// ---------------- kA: fused z+y forward DFT --------------------------------
__global__ __launch_bounds__(256) void k_fwd_zy(const float* __restrict__ h,
                                                float2* __restrict__ F1)
{
    __shared__ float pl[8*1056];
    __shared__ float2 fz[32*73];
    __shared__ float twc[32], tws[32];
    int t = threadIdx.x;
    int x = blockIdx.x >> 3, cg = blockIdx.x & 7;
    for (int i = t; i < 8192; i += 256) {
        int c = i >> 10, yz = i & 1023;
        pl[c*1056 + (yz>>5)*33 + (yz&31)] = h[(cg*8 + c)*32768 + x*1024 + yz];
    }
    if (t < 32) { float th = (float)t*(6.283185307179586f/32.f); twc[t]=cosf(th); tws[t]=sinf(th); }
    __syncthreads();
    {
        int c = t >> 5, y = t & 31;
        float zv[32];
        #pragma unroll
        for (int z = 0; z < 32; ++z) zv[z] = pl[c*1056 + y*33 + z];
        const float inv = 1.0f/32768.0f;
        #pragma unroll
        for (int kz = 0; kz < 8; ++kz) {
            float re = 0.f, im = 0.f;
            #pragma unroll
            for (int z = 0; z < 32; ++z) {
                int ph = (kz*z)&31;
                re += zv[z]*twc[ph];
                im -= zv[z]*tws[ph];
            }
            fz[y*73 + kz*9 + c] = make_float2(re*inv, im*inv);
        }
    }
    __syncthreads();
    #pragma unroll
    for (int ko = 0; ko < 4; ++ko) {
        int idx = ko*256 + t;
        int kyi = idx >> 6, kz = (idx >> 3) & 7, c = idx & 7;
        int ky = kyi < 8 ? kyi : kyi + 16;
        float re = 0.f, im = 0.f;
        for (int y = 0; y < 32; ++y) {
            int ph = (ky*y)&31;
            float cc = twc[ph], ss = tws[ph];
            float2 a = fz[y*73 + kz*9 + c];
            re += a.x*cc + a.y*ss;
            im += a.y*cc - a.x*ss;
        }
        F1[((kyi*8 + kz)*32 + x)*64 + cg*8 + c] = make_float2(re, im);
    }
}

// ---------------- kAx: x forward DFT ---------------------------------------
__global__ __launch_bounds__(256) void k_fwd_x(const float2* __restrict__ F1,
                                               float2* __restrict__ Ft)
{
    __shared__ float2 fs[32*65];
    __shared__ float twc[32], tws[32];
    int t = threadIdx.x;
    int kyi = blockIdx.x >> 3, kz = blockIdx.x & 7;
    const float2* src = &F1[(size_t)((kyi*8 + kz)*32)*64];
    for (int i = t; i < 2048; i += 256) fs[(i>>6)*65 + (i&63)] = src[i];
    if (t < 32) { float th = (float)t*(6.283185307179586f/32.f); twc[t]=cosf(th); tws[t]=sinf(th); }
    __syncthreads();
    #pragma unroll
    for (int ko = 0; ko < 4; ++ko) {
        int idx = ko*256 + t;
        int kxi = idx >> 6, ii = idx & 63;
        int kx = kxi < 8 ? kxi : kxi + 16;
        float re = 0.f, im = 0.f;
        for (int xx = 0; xx < 32; ++xx) {
            int ph = (kx*xx)&31;
            float cc = twc[ph], ss = tws[ph];
            float2 a = fs[xx*65 + ii];
            re += a.x*cc + a.y*ss;
            im += a.y*cc - a.x*ss;
        }
        Ft[((kxi*16 + kyi)*8 + kz)*64 + ii] = make_float2(re, im);
    }
}

// ---------------- kB: spectral multiply, W read once & coalesced -----------
__global__ __launch_bounds__(256) void k_spec(const float2* __restrict__ Ft,
                                              const float* __restrict__ spw,
                                              float2* __restrict__ Gt, int l)
{
    __shared__ float2 ft[64*65];
    int t = threadIdx.x;
    int og = blockIdx.x >> 5, corner = (blockIdx.x >> 3) & 3, mx = blockIdx.x & 7;
    int kxi = mx + (corner >> 1)*8;
    int kyB = (corner & 1)*8;
    {
        int m = t >> 2, iq = t & 3;
        int my = m >> 3, mz = m & 7;
        const float2* src = &Ft[(size_t)((kxi*16 + kyB + my)*8 + mz)*64];
        #pragma unroll
        for (int ii = 0; ii < 16; ++ii) {
            int i = iq*16 + ii;
            ft[i*65 + m] = src[i];
        }
    }
    __syncthreads();
    int mode = t & 63, o = t >> 6;
    size_t wbase = (size_t)(l*4 + corner)*4194304 + (size_t)(og*4 + o)*1024
                 + (size_t)mx*128 + mode*2;
    float ar = 0.f, ai = 0.f;
    for (int i8 = 0; i8 < 64; i8 += 8) {
        float2 wv[8];
        #pragma unroll
        for (int u = 0; u < 8; ++u)
            wv[u] = *(const float2*)&spw[wbase + (size_t)(i8+u)*65536];
        #pragma unroll
        for (int u = 0; u < 8; ++u) {
            float2 fv = ft[(i8+u)*65 + mode];
            ar += fv.x*wv[u].x - fv.y*wv[u].y;
            ai += fv.x*wv[u].y + fv.y*wv[u].x;
        }
    }
    Gt[(size_t)(((og*4 + corner)*8 + mx)*64 + mode)*4 + o] = make_float2(ar, ai);
}

// ---------------- kC: fused inv-x + inv-y + inv-z + skip + gelu ------------
__global__ __launch_bounds__(256) void k_inv_skip(const float2* __restrict__ Gt,
                                                  const float* __restrict__ hold,
                                                  const float* __restrict__ skw,
                                                  const float* __restrict__ skb,
                                                  float* __restrict__ hnew,
                                                  float* __restrict__ latent,
                                                  int l)
{
    __shared__ float2 gt[8192];
    __shared__ float2 s1[16*8*4];
    __shared__ float2 s2[32*8*4];
    __shared__ float  skws[256];
    __shared__ float twc[32], tws[32];
    int t = threadIdx.x;
    int x = blockIdx.x >> 4, og = blockIdx.x & 15;
    const float2* gsrc = &Gt[(size_t)og*8192];
    for (int i = t; i < 8192; i += 256) gt[i] = gsrc[i];
    skws[t] = skw[l*4096 + (t>>2)*64 + og*4 + (t&3)];
    if (t < 32) { float th = (float)t*(6.283185307179586f/32.f); twc[t]=cosf(th); tws[t]=sinf(th); }
    __syncthreads();
    #pragma unroll
    for (int ko = 0; ko < 2; ++ko) {
        int idx = ko*256 + t;
        int kyi = idx >> 5, kz = (idx >> 2) & 7, o = idx & 3;
        int cy = kyi >> 3, my = kyi & 7;
        float re = 0.f, im = 0.f;
        #pragma unroll
        for (int cxh = 0; cxh < 2; ++cxh) {
            int corner = cxh*2 + cy;
            #pragma unroll
            for (int mxx = 0; mxx < 8; ++mxx) {
                int kxi = cxh*8 + mxx;
                int kx = kxi < 8 ? kxi : kxi + 16;
                int ph = (kx * x) & 31;
                float cc = twc[ph], ss = tws[ph];
                float2 a = gt[((corner*8 + mxx)*64 + my*8 + kz)*4 + o];
                re += a.x*cc - a.y*ss;
                im += a.x*ss + a.y*cc;
            }
        }
        s1[(kyi*8 + kz)*4 + o] = make_float2(re, im);
    }
    __syncthreads();
    #pragma unroll
    for (int ko = 0; ko < 4; ++ko) {
        int idx = ko*256 + t;
        int y = idx >> 5, kz = (idx >> 2) & 7, o = idx & 3;
        float re = 0.f, im = 0.f;
        #pragma unroll
        for (int kyi = 0; kyi < 16; ++kyi) {
            int ky = kyi < 8 ? kyi : kyi + 16;
            int ph = (ky*y) & 31;
            float cc = twc[ph], ss = tws[ph];
            float2 a = s1[(kyi*8 + kz)*4 + o];
            re += a.x*cc - a.y*ss;
            im += a.x*ss + a.y*cc;
        }
        s2[(y*8 + kz)*4 + o] = make_float2(re, im);
    }
    __syncthreads();
    float acc[4][4];
    #pragma unroll
    for (int pp = 0; pp < 4; ++pp)
        #pragma unroll
        for (int o = 0; o < 4; ++o) acc[pp][o] = skb[l*64 + og*4 + o];
    const float* hsrc = &hold[x*1024 + t*4];
    for (int i = 0; i < 64; ++i) {
        float4 hv = *(const float4*)&hsrc[(size_t)i*32768];
        #pragma unroll
        for (int o = 0; o < 4; ++o) {
            float wv = skws[i*4 + o];
            acc[0][o] += hv.x*wv; acc[1][o] += hv.y*wv;
            acc[2][o] += hv.z*wv; acc[3][o] += hv.w*wv;
        }
    }
    float outv[4][4];
    #pragma unroll
    for (int pp = 0; pp < 4; ++pp) {
        int pt = t*4 + pp;
        int y = pt >> 5, z = pt & 31;
        #pragma unroll
        for (int o = 0; o < 4; ++o) {
            float s = s2[(y*8)*4 + o].x;
            #pragma unroll
            for (int kz = 1; kz < 8; ++kz) {
                int ph = (kz*z) & 31;
                float2 a = s2[(y*8 + kz)*4 + o];
                s += 2.0f*(a.x*twc[ph] - a.y*tws[ph]);
            }
            float v = s + acc[pp][o];
            outv[pp][o] = (l < 3) ? gelu_f(v) : v;
        }
    }
    if (l < 3) {
        #pragma unroll
        for (int o = 0; o < 4; ++o) {
            float4 w4 = make_float4(outv[0][o], outv[1][o], outv[2][o], outv[3][o]);
            *(float4*)&hnew[(size_t)(og*4 + o)*32768 + x*1024 + t*4] = w4;
        }
    } else {
        #pragma unroll
        for (int pp = 0; pp < 4; ++pp) {
            float4 w4 = make_float4(outv[pp][0], outv[pp][1], outv[pp][2], outv[pp][3]);
            *(float4*)&latent[(size_t)(x*1024 + t*4 + pp)*64 + og*4] = w4;
        }
    }
}

// ---------------- k_gno: point-owned, padded-slot, no atomics --------------
__global__ __launch_bounds__(256, 2) void k_gno(
    const float* __restrict__ out_p,
    const _Float16* __restrict__ w1p,  // [512][8] {w0..w5,b,0}
    const _Float16* __restrict__ w2T,  // [256][512]
    const float* __restrict__ b2,      // [256]
    const _Float16* __restrict__ w3T,  // [64][256]
    const float* __restrict__ b3,      // [64]
    const float* __restrict__ latent,  // [32768][64]
    float* __restrict__ num)           // [16384][64] (pre-divided)
{
    __shared__ __align__(16) _Float16 h1pool[64*520];
    __shared__ __align__(16) _Float16 w1s[512*8];
    __shared__ int   flatS[64];
    __shared__ float validS[64];
    __shared__ float cntS[8];
    _Float16* h2h = h1pool;

    int t = threadIdx.x;
    const float hg = 1.0f/31.0f;
    const float r2 = (float)(0.033*0.033);

    for (int i = t; i < 512; i += 256)
        ((int4*)w1s)[i] = ((const int4*)w1p)[i];

    int e = t & 63;
    int p = blockIdx.x*8 + (e >> 3);
    int slot = e & 7;
    float px = out_p[p*3+0], py = out_p[p*3+1], pz = out_p[p*3+2];
    int ix = (int)rintf(px*31.f), iy = (int)rintf(py*31.f), iz = (int)rintf(pz*31.f);
    int found = -1, cnt = 0;
    for (int j = 0; j < 27; ++j) {
        int dx = j/9 - 1, dy = (j/3)%3 - 1, dz = j%3 - 1;
        int cx = ix+dx, cy = iy+dy, cz = iz+dz;
        bool inb = (cx>=0)&&(cx<32)&&(cy>=0)&&(cy<32)&&(cz>=0)&&(cz<32);
        int qx = min(max(cx,0),31), qy = min(max(cy,0),31), qz = min(max(cz,0),31);
        float yx = qx*hg, yy = qy*hg, yz = qz*hg;
        float d2 = (px-yx)*(px-yx) + (py-yy)*(py-yy) + (pz-yz)*(pz-yz);
        if (inb && d2 <= r2) { if (cnt == slot) found = j; cnt++; }
    }
    float a0=0.f,a1=0.f,a2=0.f,a3=0.f,a4=0.f,a5=0.f;
    int fl = 0; float val = 0.f;
    if (found >= 0) {
        int dx = found/9 - 1, dy = (found/3)%3 - 1, dz = found%3 - 1;
        int cx = ix+dx, cy = iy+dy, cz = iz+dz;
        fl = (cx*32 + cy)*32 + cz;
        a0 = cx*hg; a1 = cy*hg; a2 = cz*hg; a3 = px; a4 = py; a5 = pz;
        val = 1.f;
    }
    if (t < 64) {
        flatS[e] = fl; validS[e] = val;
        if (slot == 0) cntS[e >> 3] = (float)cnt;
    }
    __syncthreads();

    int w = t >> 6;
    {
        int xk = (e >> 3) & 7;
        #pragma unroll
        for (int ci = 0; ci < 16; ++ci) {
            int c = w*16 + ci;
            f16x8 v;
            #pragma unroll
            for (int jj = 0; jj < 8; ++jj) {
                int k = c*8 + jj;
                f16x8 wv = *(const f16x8*)&w1s[k*8];
                float pre = (float)wv[6]
                    + a0*(float)wv[0] + a1*(float)wv[1] + a2*(float)wv[2]
                    + a3*(float)wv[3] + a4*(float)wv[4] + a5*(float)wv[5];
                v[jj] = (_Float16)gelu_f(pre);
            }
            *(f16x8*)&h1pool[e*520 + ((c ^ xk)*8)] = v;
        }
    }
    __syncthreads();

    int lane = t & 63;
    int l15 = lane & 15, g = lane >> 4;

    f32x4 acc2[4][4];
    #pragma unroll
    for (int nt = 0; nt < 4; ++nt) {
        float bb = b2[w*64 + nt*16 + l15];
        #pragma unroll
        for (int mt = 0; mt < 4; ++mt) acc2[mt][nt] = (f32x4){bb, bb, bb, bb};
    }
    #pragma unroll 4
    for (int kk = 0; kk < 16; ++kk) {
        f16x8 af[4];
        #pragma unroll
        for (int mt = 0; mt < 4; ++mt) {
            int ee = mt*16 + l15;
            af[mt] = *(const f16x8*)&h1pool[ee*520 + (((kk*4 + g) ^ ((ee>>3)&7))*8)];
        }
        #pragma unroll
        for (int nt = 0; nt < 4; ++nt) {
            f16x8 bf = *(const f16x8*)&w2T[(size_t)(w*64 + nt*16 + l15)*512 + kk*32 + g*8];
            #pragma unroll
            for (int mt = 0; mt < 4; ++mt)
                acc2[mt][nt] = __builtin_amdgcn_mfma_f32_16x16x32_f16(af[mt], bf, acc2[mt][nt], 0, 0, 0);
        }
    }
    __syncthreads();
    #pragma unroll
    for (int mt = 0; mt < 4; ++mt)
      #pragma unroll
      for (int nt = 0; nt < 4; ++nt) {
        int n = w*64 + nt*16 + l15;
        #pragma unroll
        for (int r = 0; r < 4; ++r) {
            int m = mt*16 + g*4 + r;
            h2h[m*264 + (((n>>3) ^ (m&7))*8) + (n&7)] = (_Float16)gelu_f(acc2[mt][nt][r]);
        }
      }
    __syncthreads();

    int o = w*16 + l15;
    f32x4 acc3[4];
    { float bb = b3[o];
      #pragma unroll
      for (int mt = 0; mt < 4; ++mt) acc3[mt] = (f32x4){bb, bb, bb, bb}; }
    #pragma unroll 2
    for (int kk2 = 0; kk2 < 8; ++kk2) {
        f16x8 bf = *(const f16x8*)&w3T[(size_t)o*256 + kk2*32 + g*8];
        #pragma unroll
        for (int mt = 0; mt < 4; ++mt) {
            int ee = mt*16 + l15;
            f16x8 af = *(const f16x8*)&h2h[ee*264 + (((kk2*4 + g) ^ (ee&7))*8)];
            acc3[mt] = __builtin_amdgcn_mfma_f32_16x16x32_f16(af, bf, acc3[mt], 0, 0, 0);
        }
    }

    #pragma unroll
    for (int mt = 0; mt < 4; ++mt) {
        float psum = 0.f;
        #pragma unroll
        for (int r = 0; r < 4; ++r) {
            int ee = mt*16 + g*4 + r;
            float fy = latent[(size_t)flatS[ee]*64 + o];
            psum += acc3[mt][r] * fy * validS[ee];
        }
        psum += __shfl_xor(psum, 16, 64);
        if ((g & 1) == 0) {
            int pt = mt*2 + (g >> 1);
            float den = fmaxf(cntS[pt], 1.0f);
            num[(size_t)(blockIdx.x*8 + pt)*64 + o] = psum / den;
        }
    }
}

// ---------------- projection: fp32 register-blocked 4x4 --------------------
// grid 256 x 64 points; thread = (pr = t&15 -> 4 pts, oc0 = t>>4; 4 oc-iters)
__global__ __launch_bounds__(256) void k_project(const float* __restrict__ num,
                                                 const float* __restrict__ pw1,
                                                 const float* __restrict__ pb1,
                                                 const float* __restrict__ pw2,
                                                 const float* __restrict__ pb2,
                                                 float* __restrict__ outp)
{
    __shared__ float w1s[64*260];      // 66.6 KB [k][o]
    __shared__ float xT[64*68];        // 17.4 KB [k][pt]
    __shared__ float w2s[256];
    __shared__ float b1s[256];
    __shared__ float red[64*4];
    int t = threadIdx.x;
    int p0 = blockIdx.x * 64;
    for (int i = t; i < 16384; i += 256) {
        int k = i >> 8, o = i & 255;
        w1s[k*260 + o] = pw1[i];
    }
    w2s[t] = pw2[t];
    b1s[t] = pb1[t];
    for (int i = t; i < 4096; i += 256) {
        int ptl = i >> 6, c = i & 63;
        xT[c*68 + ptl] = num[(size_t)(p0 + ptl)*64 + c];
    }
    __syncthreads();
    int pr = t & 15, oc0 = t >> 4;
    float psum[4] = {0.f, 0.f, 0.f, 0.f};
    for (int it = 0; it < 4; ++it) {
        int oc = it*16 + oc0;
        float a[4][4];
        #pragma unroll
        for (int pp = 0; pp < 4; ++pp)
            #pragma unroll
            for (int q = 0; q < 4; ++q) a[pp][q] = b1s[oc*4 + q];
        for (int i = 0; i < 64; ++i) {
            float4 xv = *(const float4*)&xT[i*68 + pr*4];
            float4 wv = *(const float4*)&w1s[i*260 + oc*4];
            #pragma unroll
            for (int q = 0; q < 4; ++q) {
                float wq = (&wv.x)[q];
                a[0][q] += xv.x*wq; a[1][q] += xv.y*wq;
                a[2][q] += xv.z*wq; a[3][q] += xv.w*wq;
            }
        }
        #pragma unroll
        for (int pp = 0; pp < 4; ++pp) {
            float s = 0.f;
            #pragma unroll
            for (int q = 0; q < 4; ++q) s += gelu_f(a[pp][q]) * w2s[oc*4 + q];
            psum[pp] += s;
        }
    }
    #pragma unroll
    for (int pp = 0; pp < 4; ++pp) {
        psum[pp] += __shfl_xor(psum[pp], 16, 64);
        psum[pp] += __shfl_xor(psum[pp], 32, 64);
    }
    int lane = t & 63, w = t >> 6;
    if (lane < 16) {
        #pragma unroll
        for (int pp = 0; pp < 4; ++pp) red[(lane*4 + pp)*4 + w] = psum[pp];
    }
    __syncthreads();
    if (t < 64)
        outp[p0 + t] = red[t*4+0] + red[t*4+1] + red[t*4+2] + red[t*4+3] + pb2[0];
}

// ---------------------------------------------------------------------------
extern "C" void kernel_launch(void* const* d_in, const int* in_sizes, int n_in,
                              void* d_out, int out_size, void* d_ws, size_t ws_size,
                              hipStream_t stream)
{
    const float* in_p = (const float*)d_in[0];
    const float* outp = (const float*)d_in[1];
    const float* f    = (const float*)d_in[2];
    const float* lw1  = (const float*)d_in[3];
    const float* lb1  = (const float*)d_in[4];
    const float* lw2  = (const float*)d_in[5];
    const float* lb2  = (const float*)d_in[6];
    const float* spw  = (const float*)d_in[7];
    const float* skw  = (const float*)d_in[8];
    const float* skb  = (const float*)d_in[9];
    const float* gw1  = (const float*)d_in[10];
    const float* gb1  = (const float*)d_in[11];
    const float* gw2  = (const float*)d_in[12];
    const float* gb2  = (const float*)d_in[13];
    const float* gw3  = (const float*)d_in[14];
    const float* gb3  = (const float*)d_in[15];
    const float* pw1  = (const float*)d_in[16];
    const float* pb1  = (const float*)d_in[17];
    const float* pw2  = (const float*)d_in[18];
    const float* pb2  = (const float*)d_in[19];

    float* ws   = (float*)d_ws;
    float* buf0 = ws;                          // c-major h / final latent pt-major
    float* buf1 = ws + 2097152;
    float* SC   = ws + 4194304;
    float2* F1 = (float2*)SC;                  // 262144 c64
    float2* Ft = (float2*)(SC + 524288);       // 131072 c64
    float2* Gt = (float2*)(SC + 786432);       // 131072 c64
    float* numb = SC;                          // 1048576 f (GNO phase only)
    _Float16* w2T  = (_Float16*)(SC + 1048576); // 131072 h
    _Float16* w3T  = (_Float16*)(SC + 1114112); // 16384 h
    _Float16* w1p  = (_Float16*)(SC + 1122304); // 4096 h
    _Float16* l2hi = (_Float16*)(SC + 1124352); // 16384 h
    _Float16* l2lo = (_Float16*)(SC + 1132544); // 16384 h

    k_prep_w<<<656, 256, 0, stream>>>(gw2, gw3, gw1, gb1, lw2,
                                      w2T, w3T, w1p, l2hi, l2lo);
    k_lift<<<512, 256, 0, stream>>>(f, in_p, lw1, lb1, l2hi, l2lo, lb2, buf0);

    for (int l = 0; l < 4; ++l) {
        const float* hin = (l & 1) ? buf1 : buf0;
        float* hout = (l & 1) ? buf0 : buf1;
        k_fwd_zy<<<256, 256, 0, stream>>>(hin, F1);
        k_fwd_x<<<128, 256, 0, stream>>>(F1, Ft);
        k_spec<<<512, 256, 0, stream>>>(Ft, spw, Gt, l);
        k_inv_skip<<<512, 256, 0, stream>>>(Gt, hin, skw, skb, hout, buf0, l);
    }
    // latent = buf0 (point-major, written by k_inv_skip at l=3)

    k_gno<<<2048, 256, 0, stream>>>(outp, w1p, w2T, gb2, w3T, gb3, buf0, numb);
    k_project<<<256, 256, 0, stream>>>(numb, pw1, pb1, pw2, pb2, (float*)d_out);
}

// Round 6
// 417.619 us; speedup vs baseline: 2.1047x; 1.0302x over previous
//
#include <hip/hip_runtime.h>
#include <math.h>

// ---------------------------------------------------------------------------
// FNO-GNO round 6: GNO global edge compaction (100% MFMA-tile utilization,
// was 4.5/8 = 56% with padded slots), scatter-free 3-kernel GNO; k_spec
// float4 weight loads. Lift/project/FNO-DFT kernels unchanged from r5.
//   k_gno_build : per-point scan, contiguous per-point edge ranges via
//                 atomicAdd base (per-point order fixed => deterministic out)
//   k_gno_mlp   : dense 64-edge tiles, fp16 MFMA layers 2/3, writes per-edge
//                 k*latent with plain coalesced stores (no atomics)
//   k_gno_reduce: per-point contiguous gather + mean
//
// Workspace (floats from ws): buf0 2097152 | buf1 2097152 | SC:
//   FNO view: F1 524288 | Ft 262144 | Gt 262144   (<= 1048576)
//   GNO: numb @0 (1048576, GNO phase only)
//   w2T @1048576 | w3T @1114112 | w1p @1122304 | l2hi @1124352 | l2lo @1132544
//   counter @1140736 | baseG @1140752 | cntG @1157136 | eFlat @1173520
//   eAgg @1304592 (131072*6) | kv @2091024 (131072*64)
// total ~= 58.7 MB << ws_size (1 GB)
// ---------------------------------------------------------------------------

#define ECAP 131072   // hard max: radius 0.033 < 2*h => <= 2 grid lines/axis => <= 8/point

typedef _Float16 f16x8 __attribute__((ext_vector_type(8)));
typedef float f32x4 __attribute__((ext_vector_type(4)));

// fast gelu: exact-gelu via A&S 7.1.26 erf (|err| <= 1.5e-7)
__device__ __forceinline__ float gelu_f(float x) {
    float t = fabsf(x) * 0.7071067811865475f;
    float k = __builtin_amdgcn_rcpf(1.0f + 0.3275911f * t);
    float e = __expf(-t * t);
    float y = k*(0.254829592f + k*(-0.284496736f + k*(1.421413741f +
              k*(-1.453152027f + k*1.061405429f))));
    float erfv = 1.0f - y * e;
    return 0.5f * x * (1.0f + copysignf(erfv, x));
}

// ---------------- weight prep: w2T/w3T/w1p fp16, lift-W2 split-fp16 --------
__global__ __launch_bounds__(256) void k_prep_w(const float* __restrict__ w2,
                                                const float* __restrict__ w3,
                                                const float* __restrict__ w1,
                                                const float* __restrict__ b1,
                                                const float* __restrict__ lw2,
                                                _Float16* __restrict__ w2T,
                                                _Float16* __restrict__ w3T,
                                                _Float16* __restrict__ w1p,
                                                _Float16* __restrict__ l2hi,
                                                _Float16* __restrict__ l2lo)
{
    int idx = blockIdx.x*256 + threadIdx.x;
    if (idx < 131072) {                       // w2 [512][256] -> w2T [256][512]
        int k = idx >> 8, n = idx & 255;
        w2T[n*512 + k] = (_Float16)w2[idx];
    } else if (idx < 147456) {                // w3 [256][64] -> w3T [64][256]
        int j = idx - 131072;
        int k = j >> 6, o = j & 63;
        w3T[o*256 + k] = (_Float16)w3[j];
    } else if (idx < 151552) {                // w1 [6][512]+b1 -> w1p [512][8]
        int j = idx - 147456;
        int k = j >> 3, d = j & 7;
        float v = d < 6 ? w1[d*512 + k] : (d == 6 ? b1[k] : 0.0f);
        w1p[k*8 + d] = (_Float16)v;
    } else if (idx < 167936) {                // lw2 [256][64] -> split [64][256]
        int j = idx - 151552;
        int o = j >> 8, k = j & 255;
        float v = lw2[k*64 + o];
        _Float16 hi = (_Float16)v;
        l2hi[j] = hi;
        l2lo[j] = (_Float16)(v - (float)hi);
    }
}

// ---------------- lifting via split-fp16 MFMA ------------------------------
__global__ __launch_bounds__(256) void k_lift(
    const float* __restrict__ f, const float* __restrict__ in_p,
    const float* __restrict__ w1, const float* __restrict__ b1,
    const _Float16* __restrict__ l2hi,
    const _Float16* __restrict__ l2lo,
    const float* __restrict__ b2,
    float* __restrict__ h)
{
    __shared__ __align__(16) _Float16 h1hi[64*264];
    __shared__ __align__(16) _Float16 h1lo[64*264];
    __shared__ float w1s[6*256];
    __shared__ float b1s[256];
    float* oT = (float*)h1hi;
    int t = threadIdx.x;
    for (int i = t; i < 1536; i += 256) w1s[i] = w1[i];
    b1s[t] = b1[t];
    int p0 = blockIdx.x * 64;
    int pt = t >> 2, jq = t & 3;
    int p = p0 + pt;
    float x0 = f[p*3+0], x1 = f[p*3+1], x2 = f[p*3+2];
    float x3 = in_p[p*3+0], x4 = in_p[p*3+1], x5 = in_p[p*3+2];
    __syncthreads();
    for (int r = 0; r < 8; ++r) {
        int j0 = jq*64 + r*8;
        f16x8 vh, vl;
        #pragma unroll
        for (int jj = 0; jj < 8; ++jj) {
            int j = j0 + jj;
            float a = b1s[j] + x0*w1s[j] + x1*w1s[256+j] + x2*w1s[512+j]
                    + x3*w1s[768+j] + x4*w1s[1024+j] + x5*w1s[1280+j];
            float g = gelu_f(a);
            _Float16 hi = (_Float16)g;
            vh[jj] = hi;
            vl[jj] = (_Float16)(g - (float)hi);
        }
        *(f16x8*)&h1hi[pt*264 + j0] = vh;
        *(f16x8*)&h1lo[pt*264 + j0] = vl;
    }
    __syncthreads();
    int w = t >> 6, lane = t & 63, l15 = lane & 15, g = lane >> 4;
    f32x4 acc[4];
    #pragma unroll
    for (int nt = 0; nt < 4; ++nt) {
        float bb = b2[nt*16 + l15];
        acc[nt] = (f32x4){bb, bb, bb, bb};
    }
    for (int kk = 0; kk < 8; ++kk) {
        f16x8 ah = *(const f16x8*)&h1hi[(w*16+l15)*264 + kk*32 + g*8];
        f16x8 al = *(const f16x8*)&h1lo[(w*16+l15)*264 + kk*32 + g*8];
        #pragma unroll
        for (int nt = 0; nt < 4; ++nt) {
            f16x8 bh = *(const f16x8*)&l2hi[(nt*16+l15)*256 + kk*32 + g*8];
            f16x8 bl = *(const f16x8*)&l2lo[(nt*16+l15)*256 + kk*32 + g*8];
            acc[nt] = __builtin_amdgcn_mfma_f32_16x16x32_f16(al, bh, acc[nt], 0, 0, 0);
            acc[nt] = __builtin_amdgcn_mfma_f32_16x16x32_f16(ah, bl, acc[nt], 0, 0, 0);
            acc[nt] = __builtin_amdgcn_mfma_f32_16x16x32_f16(ah, bh, acc[nt], 0, 0, 0);
        }
    }
    __syncthreads();
    #pragma unroll
    for (int nt = 0; nt < 4; ++nt)
        #pragma unroll
        for (int r = 0; r < 4; ++r)
            oT[(nt*16 + l15)*68 + w*16 + g*4 + r] = acc[nt][r];
    __syncthreads();
    for (int i = t; i < 4096; i += 256) {
        int c = i >> 6, ptl = i & 63;
        h[(size_t)c*32768 + p0 + ptl] = oT[c*68 + ptl];
    }
}

// ---------------- kA: fused z+y forward DFT --------------------------------
__global__ __launch_bounds__(256) void k_fwd_zy(const float* __restrict__ h,
                                                float2* __restrict__ F1)
{
    __shared__ float pl[8*1056];
    __shared__ float2 fz[32*73];
    __shared__ float twc[32], tws[32];
    int t = threadIdx.x;
    int x = blockIdx.x >> 3, cg = blockIdx.x & 7;
    for (int i = t; i < 8192; i += 256) {
        int c = i >> 10, yz = i & 1023;
        pl[c*1056 + (yz>>5)*33 + (yz&31)] = h[(cg*8 + c)*32768 + x*1024 + yz];
    }
    if (t < 32) { float th = (float)t*(6.283185307179586f/32.f); twc[t]=cosf(th); tws[t]=sinf(th); }
    __syncthreads();
    {
        int c = t >> 5, y = t & 31;
        float zv[32];
        #pragma unroll
        for (int z = 0; z < 32; ++z) zv[z] = pl[c*1056 + y*33 + z];
        const float inv = 1.0f/32768.0f;
        #pragma unroll
        for (int kz = 0; kz < 8; ++kz) {
            float re = 0.f, im = 0.f;
            #pragma unroll
            for (int z = 0; z < 32; ++z) {
                int ph = (kz*z)&31;
                re += zv[z]*twc[ph];
                im -= zv[z]*tws[ph];
            }
            fz[y*73 + kz*9 + c] = make_float2(re*inv, im*inv);
        }
    }
    __syncthreads();
    #pragma unroll
    for (int ko = 0; ko < 4; ++ko) {
        int idx = ko*256 + t;
        int kyi = idx >> 6, kz = (idx >> 3) & 7, c = idx & 7;
        int ky = kyi < 8 ? kyi : kyi + 16;
        float re = 0.f, im = 0.f;
        for (int y = 0; y < 32; ++y) {
            int ph = (ky*y)&31;
            float cc = twc[ph], ss = tws[ph];
            float2 a = fz[y*73 + kz*9 + c];
            re += a.x*cc + a.y*ss;
            im += a.y*cc - a.x*ss;
        }
        F1[((kyi*8 + kz)*32 + x)*64 + cg*8 + c] = make_float2(re, im);
    }
}

// ---------------- kAx: x forward DFT ---------------------------------------
__global__ __launch_bounds__(256) void k_fwd_x(const float2* __restrict__ F1,
                                               float2* __restrict__ Ft)
{
    __shared__ float2 fs[32*65];
    __shared__ float twc[32], tws[32];
    int t = threadIdx.x;
    int kyi = blockIdx.x >> 3, kz = blockIdx.x & 7;
    const float2* src = &F1[(size_t)((kyi*8 + kz)*32)*64];
    for (int i = t; i < 2048; i += 256) fs[(i>>6)*65 + (i&63)] = src[i];
    if (t < 32) { float th = (float)t*(6.283185307179586f/32.f); twc[t]=cosf(th); tws[t]=sinf(th); }
    __syncthreads();
    #pragma unroll
    for (int ko = 0; ko < 4; ++ko) {
        int idx = ko*256 + t;
        int kxi = idx >> 6, ii = idx & 63;
        int kx = kxi < 8 ? kxi : kxi + 16;
        float re = 0.f, im = 0.f;
        for (int xx = 0; xx < 32; ++xx) {
            int ph = (kx*xx)&31;
            float cc = twc[ph], ss = tws[ph];
            float2 a = fs[xx*65 + ii];
            re += a.x*cc + a.y*ss;
            im += a.y*cc - a.x*ss;
        }
        Ft[((kxi*16 + kyi)*8 + kz)*64 + ii] = make_float2(re, im);
    }
}

// ---------------- kB: spectral multiply, float4 W loads --------------------
// grid 256 = (og8 8) x (corner 4) x (mx 8); thread = (oq = t>>5, mp = t&31)
// each thread computes modes {2mp, 2mp+1} for o = og8*8+oq; W load = float4
// (1KB/wave). ft rows split: row(mode) = (mode>>1) + 32*(mode&1) => 2-way max.
__global__ __launch_bounds__(256) void k_spec(const float2* __restrict__ Ft,
                                              const float* __restrict__ spw,
                                              float2* __restrict__ Gt, int l)
{
    __shared__ float2 ft2[64*65];
    int t = threadIdx.x;
    int og8 = blockIdx.x >> 5, corner = (blockIdx.x >> 3) & 3, mx = blockIdx.x & 7;
    int kxi = mx + (corner >> 1)*8;
    int kyB = (corner & 1)*8;
    {   // stage Ft rows, transposed to [row(mode)][i]
        int m = t >> 2, iq = t & 3;
        int my = m >> 3, mz = m & 7;
        int rho = (m >> 1) + ((m & 1) << 5);
        const float2* src = &Ft[(size_t)((kxi*16 + kyB + my)*8 + mz)*64];
        #pragma unroll
        for (int ii = 0; ii < 16; ++ii) {
            int i = iq*16 + ii;
            ft2[rho*65 + i] = src[i];
        }
    }
    __syncthreads();
    int mp = t & 31, oq = t >> 5;
    int o = og8*8 + oq;
    int m0 = 2*mp;
    size_t wbase = (size_t)(l*4 + corner)*4194304 + (size_t)o*1024
                 + (size_t)mx*128 + m0*2;
    float ar0 = 0.f, ai0 = 0.f, ar1 = 0.f, ai1 = 0.f;
    for (int i8 = 0; i8 < 64; i8 += 8) {
        float4 wv[8];
        #pragma unroll
        for (int u = 0; u < 8; ++u)
            wv[u] = *(const float4*)&spw[wbase + (size_t)(i8+u)*65536];
        #pragma unroll
        for (int u = 0; u < 8; ++u) {
            float2 f0 = ft2[mp*65 + i8 + u];          // row(2mp)   = mp
            float2 f1 = ft2[(32 + mp)*65 + i8 + u];   // row(2mp+1) = 32+mp
            ar0 += f0.x*wv[u].x - f0.y*wv[u].y;
            ai0 += f0.x*wv[u].y + f0.y*wv[u].x;
            ar1 += f1.x*wv[u].z - f1.y*wv[u].w;
            ai1 += f1.x*wv[u].w + f1.y*wv[u].z;
        }
    }
    size_t gbase = (size_t)(o >> 2)*8192 + (size_t)(corner*8 + mx)*256 + (o & 3);
    Gt[gbase + (size_t)m0*4]       = make_float2(ar0, ai0);
    Gt[gbase + (size_t)(m0+1)*4]   = make_float2(ar1, ai1);
}

// ---------------- kC: fused inv-x + inv-y + inv-z + skip + gelu ------------
__global__ __launch_bounds__(256) void k_inv_skip(const float2* __restrict__ Gt,
                                                  const float* __restrict__ hold,
                                                  const float* __restrict__ skw,
                                                  const float* __restrict__ skb,
                                                  float* __restrict__ hnew,
                                                  float* __restrict__ latent,
                                                  int l)
{
    __shared__ float2 gt[8192];
    __shared__ float2 s1[16*8*4];
    __shared__ float2 s2[32*8*4];
    __shared__ float  skws[256];
    __shared__ float twc[32], tws[32];
    int t = threadIdx.x;
    int x = blockIdx.x >> 4, og = blockIdx.x & 15;
    const float2* gsrc = &Gt[(size_t)og*8192];
    for (int i = t; i < 8192; i += 256) gt[i] = gsrc[i];
    skws[t] = skw[l*4096 + (t>>2)*64 + og*4 + (t&3)];
    if (t < 32) { float th = (float)t*(6.283185307179586f/32.f); twc[t]=cosf(th); tws[t]=sinf(th); }
    __syncthreads();
    #pragma unroll
    for (int ko = 0; ko < 2; ++ko) {
        int idx = ko*256 + t;
        int kyi = idx >> 5, kz = (idx >> 2) & 7, o = idx & 3;
        int cy = kyi >> 3, my = kyi & 7;
        float re = 0.f, im = 0.f;
        #pragma unroll
        for (int cxh = 0; cxh < 2; ++cxh) {
            int corner = cxh*2 + cy;
            #pragma unroll
            for (int mxx = 0; mxx < 8; ++mxx) {
                int kxi = cxh*8 + mxx;
                int kx = kxi < 8 ? kxi : kxi + 16;
                int ph = (kx * x) & 31;
                float cc = twc[ph], ss = tws[ph];
                float2 a = gt[((corner*8 + mxx)*64 + my*8 + kz)*4 + o];
                re += a.x*cc - a.y*ss;
                im += a.x*ss + a.y*cc;
            }
        }
        s1[(kyi*8 + kz)*4 + o] = make_float2(re, im);
    }
    __syncthreads();
    #pragma unroll
    for (int ko = 0; ko < 4; ++ko) {
        int idx = ko*256 + t;
        int y = idx >> 5, kz = (idx >> 2) & 7, o = idx & 3;
        float re = 0.f, im = 0.f;
        #pragma unroll
        for (int kyi = 0; kyi < 16; ++kyi) {
            int ky = kyi < 8 ? kyi : kyi + 16;
            int ph = (ky*y) & 31;
            float cc = twc[ph], ss = tws[ph];
            float2 a = s1[(kyi*8 + kz)*4 + o];
            re += a.x*cc - a.y*ss;
            im += a.x*ss + a.y*cc;
        }
        s2[(y*8 + kz)*4 + o] = make_float2(re, im);
    }
    __syncthreads();
    float acc[4][4];
    #pragma unroll
    for (int pp = 0; pp < 4; ++pp)
        #pragma unroll
        for (int o = 0; o < 4; ++o) acc[pp][o] = skb[l*64 + og*4 + o];
    const float* hsrc = &hold[x*1024 + t*4];
    for (int i = 0; i < 64; ++i) {
        float4 hv = *(const float4*)&hsrc[(size_t)i*32768];
        #pragma unroll
        for (int o = 0; o < 4; ++o) {
            float wv = skws[i*4 + o];
            acc[0][o] += hv.x*wv; acc[1][o] += hv.y*wv;
            acc[2][o] += hv.z*wv; acc[3][o] += hv.w*wv;
        }
    }
    float outv[4][4];
    #pragma unroll
    for (int pp = 0; pp < 4; ++pp) {
        int pt = t*4 + pp;
        int y = pt >> 5, z = pt & 31;
        #pragma unroll
        for (int o = 0; o < 4; ++o) {
            float s = s2[(y*8)*4 + o].x;
            #pragma unroll
            for (int kz = 1; kz < 8; ++kz) {
                int ph = (kz*z) & 31;
                float2 a = s2[(y*8 + kz)*4 + o];
                s += 2.0f*(a.x*twc[ph] - a.y*tws[ph]);
            }
            float v = s + acc[pp][o];
            outv[pp][o] = (l < 3) ? gelu_f(v) : v;
        }
    }
    if (l < 3) {
        #pragma unroll
        for (int o = 0; o < 4; ++o) {
            float4 w4 = make_float4(outv[0][o], outv[1][o], outv[2][o], outv[3][o]);
            *(float4*)&hnew[(size_t)(og*4 + o)*32768 + x*1024 + t*4] = w4;
        }
    } else {
        #pragma unroll
        for (int pp = 0; pp < 4; ++pp) {
            float4 w4 = make_float4(outv[pp][0], outv[pp][1], outv[pp][2], outv[pp][3]);
            *(float4*)&latent[(size_t)(x*1024 + t*4 + pp)*64 + og*4] = w4;
        }
    }
}

// ---------------- GNO stage 1: edge build (compaction) ---------------------
// 16384 threads; per-point contiguous ranges via atomicAdd (per-point edge
// order fixed => per-point sums bitwise deterministic regardless of base).
__global__ __launch_bounds__(256) void k_gno_build(const float* __restrict__ out_p,
                                                   int* __restrict__ counter,
                                                   int* __restrict__ baseG,
                                                   int* __restrict__ cntG,
                                                   int* __restrict__ eFlat,
                                                   float* __restrict__ eAgg)
{
    int n = blockIdx.x*256 + threadIdx.x;
    const float hg = 1.0f/31.0f;
    const float r2 = (float)(0.033*0.033);
    float px = out_p[n*3+0], py = out_p[n*3+1], pz = out_p[n*3+2];
    int ix = (int)rintf(px*31.f), iy = (int)rintf(py*31.f), iz = (int)rintf(pz*31.f);
    unsigned msk = 0; int cnt = 0;
    for (int j = 0; j < 27; ++j) {
        int dx = j/9 - 1, dy = (j/3)%3 - 1, dz = j%3 - 1;
        int cx = ix+dx, cy = iy+dy, cz = iz+dz;
        bool inb = (cx>=0)&&(cx<32)&&(cy>=0)&&(cy<32)&&(cz>=0)&&(cz<32);
        int qx = min(max(cx,0),31), qy = min(max(cy,0),31), qz = min(max(cz,0),31);
        float yx = qx*hg, yy = qy*hg, yz = qz*hg;
        float d2 = (px-yx)*(px-yx) + (py-yy)*(py-yy) + (pz-yz)*(pz-yz);
        if (inb && d2 <= r2) { msk |= 1u<<j; cnt++; }
    }
    int base = atomicAdd(counter, cnt);
    baseG[n] = base; cntG[n] = cnt;
    int k = 0;
    for (int j = 0; j < 27; ++j) if (msk & (1u<<j)) {
        int dx = j/9 - 1, dy = (j/3)%3 - 1, dz = j%3 - 1;
        int cx = ix+dx, cy = iy+dy, cz = iz+dz;
        int e = base + k;
        eFlat[e] = (cx*32 + cy)*32 + cz;
        eAgg[e*6+0] = cx*hg; eAgg[e*6+1] = cy*hg; eAgg[e*6+2] = cz*hg;
        eAgg[e*6+3] = px;    eAgg[e*6+4] = py;    eAgg[e*6+5] = pz;
        ++k;
    }
}

// ---------------- GNO stage 2: dense 64-edge MLP tiles ---------------------
// layer1 fp32 VALU -> fp16 LDS (XOR-swizzled); layers 2/3 fp16 MFMA;
// writes kv[e][o] = k(e,o) * latent[flat(e)][o], coalesced, no atomics.
__global__ __launch_bounds__(256, 2) void k_gno_mlp(
    const int* __restrict__ counter,
    const int* __restrict__ eFlat,
    const float* __restrict__ eAgg,
    const _Float16* __restrict__ w1p,  // [512][8] {w0..w5,b,0}
    const _Float16* __restrict__ w2T,  // [256][512]
    const float* __restrict__ b2,      // [256]
    const _Float16* __restrict__ w3T,  // [64][256]
    const float* __restrict__ b3,      // [64]
    const float* __restrict__ latent,  // [32768][64]
    float* __restrict__ kv)            // [ECAP][64]
{
    __shared__ __align__(16) _Float16 h1pool[64*520];
    __shared__ __align__(16) _Float16 w1s[512*8];
    __shared__ float aggs[64][6];
    __shared__ int   flatS[64];
    _Float16* h2h = h1pool;

    int t = threadIdx.x;
    int E = counter[0]; if (E > ECAP) E = ECAP;
    int s = blockIdx.x * 64;
    if (s >= E) return;
    int ne = min(64, E - s);

    for (int i = t; i < 512; i += 256)
        ((int4*)w1s)[i] = ((const int4*)w1p)[i];
    for (int i = t; i < 384; i += 256)
        aggs[i/6][i - (i/6)*6] = (i < ne*6) ? eAgg[(size_t)s*6 + i] : 0.0f;
    if (t < 64) flatS[t] = (t < ne) ? eFlat[s + t] : 0;
    __syncthreads();

    int e = t & 63;
    int w = t >> 6;
    // ---- layer1: edge e, channel quarter w; w1 reads wave-uniform ----
    {
        float a0 = aggs[e][0], a1 = aggs[e][1], a2 = aggs[e][2];
        float a3 = aggs[e][3], a4 = aggs[e][4], a5 = aggs[e][5];
        int xk = (e >> 3) & 7;
        #pragma unroll
        for (int ci = 0; ci < 16; ++ci) {
            int c = w*16 + ci;
            f16x8 v;
            #pragma unroll
            for (int jj = 0; jj < 8; ++jj) {
                int k = c*8 + jj;
                f16x8 wv = *(const f16x8*)&w1s[k*8];
                float pre = (float)wv[6]
                    + a0*(float)wv[0] + a1*(float)wv[1] + a2*(float)wv[2]
                    + a3*(float)wv[3] + a4*(float)wv[4] + a5*(float)wv[5];
                v[jj] = (_Float16)gelu_f(pre);
            }
            *(f16x8*)&h1pool[e*520 + ((c ^ xk)*8)] = v;
        }
    }
    __syncthreads();

    int lane = t & 63;
    int l15 = lane & 15, g = lane >> 4;

    // ---- layer2: [64x512] x [512 x 64-per-wave] fp16 MFMA ----
    f32x4 acc2[4][4];
    #pragma unroll
    for (int nt = 0; nt < 4; ++nt) {
        float bb = b2[w*64 + nt*16 + l15];
        #pragma unroll
        for (int mt = 0; mt < 4; ++mt) acc2[mt][nt] = (f32x4){bb, bb, bb, bb};
    }
    #pragma unroll 4
    for (int kk = 0; kk < 16; ++kk) {
        f16x8 af[4];
        #pragma unroll
        for (int mt = 0; mt < 4; ++mt) {
            int ee = mt*16 + l15;
            af[mt] = *(const f16x8*)&h1pool[ee*520 + (((kk*4 + g) ^ ((ee>>3)&7))*8)];
        }
        #pragma unroll
        for (int nt = 0; nt < 4; ++nt) {
            f16x8 bf = *(const f16x8*)&w2T[(size_t)(w*64 + nt*16 + l15)*512 + kk*32 + g*8];
            #pragma unroll
            for (int mt = 0; mt < 4; ++mt)
                acc2[mt][nt] = __builtin_amdgcn_mfma_f32_16x16x32_f16(af[mt], bf, acc2[mt][nt], 0, 0, 0);
        }
    }
    __syncthreads();
    #pragma unroll
    for (int mt = 0; mt < 4; ++mt)
      #pragma unroll
      for (int nt = 0; nt < 4; ++nt) {
        int n = w*64 + nt*16 + l15;
        #pragma unroll
        for (int r = 0; r < 4; ++r) {
            int m = mt*16 + g*4 + r;
            h2h[m*264 + (((n>>3) ^ (m&7))*8) + (n&7)] = (_Float16)gelu_f(acc2[mt][nt][r]);
        }
      }
    __syncthreads();

    // ---- layer3: [64x256] x [256 x 16-per-wave] ----
    int o = w*16 + l15;
    f32x4 acc3[4];
    { float bb = b3[o];
      #pragma unroll
      for (int mt = 0; mt < 4; ++mt) acc3[mt] = (f32x4){bb, bb, bb, bb}; }
    #pragma unroll 2
    for (int kk2 = 0; kk2 < 8; ++kk2) {
        f16x8 bf = *(const f16x8*)&w3T[(size_t)o*256 + kk2*32 + g*8];
        #pragma unroll
        for (int mt = 0; mt < 4; ++mt) {
            int ee = mt*16 + l15;
            f16x8 af = *(const f16x8*)&h2h[ee*264 + (((kk2*4 + g) ^ (ee&7))*8)];
            acc3[mt] = __builtin_amdgcn_mfma_f32_16x16x32_f16(af, bf, acc3[mt], 0, 0, 0);
        }
    }

    // ---- epilogue: kv[e][o] = k * latent[flat][o], plain stores ----
    #pragma unroll
    for (int mt = 0; mt < 4; ++mt) {
        #pragma unroll
        for (int r = 0; r < 4; ++r) {
            int ee = mt*16 + g*4 + r;
            if (ee < ne) {
                float fy = latent[(size_t)flatS[ee]*64 + o];
                kv[(size_t)(s + ee)*64 + o] = acc3[mt][r] * fy;
            }
        }
    }
}

// ---------------- GNO stage 3: per-point gather + mean ---------------------
// block = 16 points; thread (pt = t>>4, cg = t&15) sums cnt contiguous edges.
__global__ __launch_bounds__(256) void k_gno_reduce(const int* __restrict__ baseG,
                                                    const int* __restrict__ cntG,
                                                    const float* __restrict__ kv,
                                                    float* __restrict__ num)
{
    int t = threadIdx.x;
    int p = blockIdx.x*16 + (t >> 4);
    int cg = t & 15;
    int base = baseG[p], cnt = cntG[p];
    float4 acc = make_float4(0.f, 0.f, 0.f, 0.f);
    for (int j = 0; j < cnt; ++j) {
        float4 v = *(const float4*)&kv[(size_t)(base + j)*64 + cg*4];
        acc.x += v.x; acc.y += v.y; acc.z += v.z; acc.w += v.w;
    }
    float inv = 1.0f / fmaxf((float)cnt, 1.0f);
    acc.x *= inv; acc.y *= inv; acc.z *= inv; acc.w *= inv;
    *(float4*)&num[(size_t)p*64 + cg*4] = acc;
}

// ---------------- projection: fp32 register-blocked 4x4 --------------------
__global__ __launch_bounds__(256) void k_project(const float* __restrict__ num,
                                                 const float* __restrict__ pw1,
                                                 const float* __restrict__ pb1,
                                                 const float* __restrict__ pw2,
                                                 const float* __restrict__ pb2,
                                                 float* __restrict__ outp)
{
    __shared__ float w1s[64*260];
    __shared__ float xT[64*68];
    __shared__ float w2s[256];
    __shared__ float b1s[256];
    __shared__ float red[64*4];
    int t = threadIdx.x;
    int p0 = blockIdx.x * 64;
    for (int i = t; i < 16384; i += 256) {
        int k = i >> 8, o = i & 255;
        w1s[k*260 + o] = pw1[i];
    }
    w2s[t] = pw2[t];
    b1s[t] = pb1[t];
    for (int i = t; i < 4096; i += 256) {
        int ptl = i >> 6, c = i & 63;
        xT[c*68 + ptl] = num[(size_t)(p0 + ptl)*64 + c];
    }
    __syncthreads();
    int pr = t & 15, oc0 = t >> 4;
    float psum[4] = {0.f, 0.f, 0.f, 0.f};
    for (int it = 0; it < 4; ++it) {
        int oc = it*16 + oc0;
        float a[4][4];
        #pragma unroll
        for (int pp = 0; pp < 4; ++pp)
            #pragma unroll
            for (int q = 0; q < 4; ++q) a[pp][q] = b1s[oc*4 + q];
        for (int i = 0; i < 64; ++i) {
            float4 xv = *(const float4*)&xT[i*68 + pr*4];
            float4 wv = *(const float4*)&w1s[i*260 + oc*4];
            #pragma unroll
            for (int q = 0; q < 4; ++q) {
                float wq = (&wv.x)[q];
                a[0][q] += xv.x*wq; a[1][q] += xv.y*wq;
                a[2][q] += xv.z*wq; a[3][q] += xv.w*wq;
            }
        }
        #pragma unroll
        for (int pp = 0; pp < 4; ++pp) {
            float s = 0.f;
            #pragma unroll
            for (int q = 0; q < 4; ++q) s += gelu_f(a[pp][q]) * w2s[oc*4 + q];
            psum[pp] += s;
        }
    }
    #pragma unroll
    for (int pp = 0; pp < 4; ++pp) {
        psum[pp] += __shfl_xor(psum[pp], 16, 64);
        psum[pp] += __shfl_xor(psum[pp], 32, 64);
    }
    int lane = t & 63, w = t >> 6;
    if (lane < 16) {
        #pragma unroll
        for (int pp = 0; pp < 4; ++pp) red[(lane*4 + pp)*4 + w] = psum[pp];
    }
    __syncthreads();
    if (t < 64)
        outp[p0 + t] = red[t*4+0] + red[t*4+1] + red[t*4+2] + red[t*4+3] + pb2[0];
}

// ---------------------------------------------------------------------------
extern "C" void kernel_launch(void* const* d_in, const int* in_sizes, int n_in,
                              void* d_out, int out_size, void* d_ws, size_t ws_size,
                              hipStream_t stream)
{
    const float* in_p = (const float*)d_in[0];
    const float* outp = (const float*)d_in[1];
    const float* f    = (const float*)d_in[2];
    const float* lw1  = (const float*)d_in[3];
    const float* lb1  = (const float*)d_in[4];
    const float* lw2  = (const float*)d_in[5];
    const float* lb2  = (const float*)d_in[6];
    const float* spw  = (const float*)d_in[7];
    const float* skw  = (const float*)d_in[8];
    const float* skb  = (const float*)d_in[9];
    const float* gw1  = (const float*)d_in[10];
    const float* gb1  = (const float*)d_in[11];
    const float* gw2  = (const float*)d_in[12];
    const float* gb2  = (const float*)d_in[13];
    const float* gw3  = (const float*)d_in[14];
    const float* gb3  = (const float*)d_in[15];
    const float* pw1  = (const float*)d_in[16];
    const float* pb1  = (const float*)d_in[17];
    const float* pw2  = (const float*)d_in[18];
    const float* pb2  = (const float*)d_in[19];

    float* ws   = (float*)d_ws;
    float* buf0 = ws;                           // c-major h / latent pt-major
    float* buf1 = ws + 2097152;
    float* SC   = ws + 4194304;
    float2* F1 = (float2*)SC;                   // FNO phase
    float2* Ft = (float2*)(SC + 524288);
    float2* Gt = (float2*)(SC + 786432);
    float* numb = SC;                           // GNO phase (aliases FNO bufs)
    _Float16* w2T  = (_Float16*)(SC + 1048576);
    _Float16* w3T  = (_Float16*)(SC + 1114112);
    _Float16* w1p  = (_Float16*)(SC + 1122304);
    _Float16* l2hi = (_Float16*)(SC + 1124352);
    _Float16* l2lo = (_Float16*)(SC + 1132544);
    int*   counter = (int*)(SC + 1140736);
    int*   baseG   = (int*)(SC + 1140752);
    int*   cntG    = (int*)(SC + 1157136);
    int*   eFlat   = (int*)(SC + 1173520);
    float* eAgg    = SC + 1304592;              // 131072*6
    float* kv      = SC + 2091024;              // 131072*64 (16B-aligned)

    k_prep_w<<<656, 256, 0, stream>>>(gw2, gw3, gw1, gb1, lw2,
                                      w2T, w3T, w1p, l2hi, l2lo);
    k_lift<<<512, 256, 0, stream>>>(f, in_p, lw1, lb1, l2hi, l2lo, lb2, buf0);

    hipMemsetAsync(counter, 0, sizeof(int), stream);
    k_gno_build<<<64, 256, 0, stream>>>(outp, counter, baseG, cntG, eFlat, eAgg);

    for (int l = 0; l < 4; ++l) {
        const float* hin = (l & 1) ? buf1 : buf0;
        float* hout = (l & 1) ? buf0 : buf1;
        k_fwd_zy<<<256, 256, 0, stream>>>(hin, F1);
        k_fwd_x<<<128, 256, 0, stream>>>(F1, Ft);
        k_spec<<<256, 256, 0, stream>>>(Ft, spw, Gt, l);
        k_inv_skip<<<512, 256, 0, stream>>>(Gt, hin, skw, skb, hout, buf0, l);
    }
    // latent = buf0 (point-major, written by k_inv_skip at l=3)

    k_gno_mlp<<<ECAP/64, 256, 0, stream>>>(counter, eFlat, eAgg,
                                           w1p, w2T, gb2, w3T, gb3, buf0, kv);
    k_gno_reduce<<<1024, 256, 0, stream>>>(baseG, cntG, kv, numb);
    k_project<<<256, 256, 0, stream>>>(numb, pw1, pb1, pw2, pb2, (float*)d_out);
}

// Round 7
// 415.667 us; speedup vs baseline: 2.1146x; 1.0047x over previous
//
#include <hip/hip_runtime.h>
#include <math.h>

// ---------------------------------------------------------------------------
// FNO-GNO round 7: kill k_inv_skip's 16x h re-read (128 MB/layer L3 traffic).
//  - skip GEMM moved to split-fp16 MFMA, co-launched as extra blocks inside
//    k_spec (spec = HBM-bound, skip = MFMA-bound -> overlap). h read ONCE.
//  - k_inv reads Gt + its own 4-channel hsk slice (16 KB/block).
//  - k_gno_build fused into k_prep (extra blocks); k_gno_reduce fused into
//    k_project (direct kv gather). Dispatches 23 -> 21, num round-trip gone.
//  - lift / fwd_zy / fwd_x / gno_mlp unchanged from r6 (passing, 2.44e-4).
// ---------------------------------------------------------------------------

#define ECAP 131072

typedef _Float16 f16x8 __attribute__((ext_vector_type(8)));
typedef float f32x4 __attribute__((ext_vector_type(4)));

__device__ __forceinline__ float gelu_f(float x) {
    float t = fabsf(x) * 0.7071067811865475f;
    float k = __builtin_amdgcn_rcpf(1.0f + 0.3275911f * t);
    float e = __expf(-t * t);
    float y = k*(0.254829592f + k*(-0.284496736f + k*(1.421413741f +
              k*(-1.453152027f + k*1.061405429f))));
    float erfv = 1.0f - y * e;
    return 0.5f * x * (1.0f + copysignf(erfv, x));
}

// ---------------- prep (weights) + GNO edge build, fused --------------------
// blocks [0,720): weight prep; blocks [720,784): edge build (counter pre-zeroed)
__global__ __launch_bounds__(256) void k_prep(const float* __restrict__ w2,
                                              const float* __restrict__ w3,
                                              const float* __restrict__ w1,
                                              const float* __restrict__ b1,
                                              const float* __restrict__ lw2,
                                              const float* __restrict__ skw,
                                              const float* __restrict__ out_p,
                                              _Float16* __restrict__ w2T,
                                              _Float16* __restrict__ w3T,
                                              _Float16* __restrict__ w1p,
                                              _Float16* __restrict__ l2hi,
                                              _Float16* __restrict__ l2lo,
                                              _Float16* __restrict__ skwH,
                                              _Float16* __restrict__ skwL,
                                              int* __restrict__ counter,
                                              int* __restrict__ baseG,
                                              int* __restrict__ cntG,
                                              int* __restrict__ eFlat,
                                              float* __restrict__ eAgg)
{
    if (blockIdx.x >= 720) {            // ---- GNO edge build ----
        int n = (blockIdx.x - 720)*256 + threadIdx.x;
        const float hg = 1.0f/31.0f;
        const float r2 = (float)(0.033*0.033);
        float px = out_p[n*3+0], py = out_p[n*3+1], pz = out_p[n*3+2];
        int ix = (int)rintf(px*31.f), iy = (int)rintf(py*31.f), iz = (int)rintf(pz*31.f);
        unsigned msk = 0; int cnt = 0;
        for (int j = 0; j < 27; ++j) {
            int dx = j/9 - 1, dy = (j/3)%3 - 1, dz = j%3 - 1;
            int cx = ix+dx, cy = iy+dy, cz = iz+dz;
            bool inb = (cx>=0)&&(cx<32)&&(cy>=0)&&(cy<32)&&(cz>=0)&&(cz<32);
            int qx = min(max(cx,0),31), qy = min(max(cy,0),31), qz = min(max(cz,0),31);
            float yx = qx*hg, yy = qy*hg, yz = qz*hg;
            float d2 = (px-yx)*(px-yx) + (py-yy)*(py-yy) + (pz-yz)*(pz-yz);
            if (inb && d2 <= r2) { msk |= 1u<<j; cnt++; }
        }
        int base = atomicAdd(counter, cnt);
        baseG[n] = base; cntG[n] = cnt;
        int k = 0;
        for (int j = 0; j < 27; ++j) if (msk & (1u<<j)) {
            int dx = j/9 - 1, dy = (j/3)%3 - 1, dz = j%3 - 1;
            int cx = ix+dx, cy = iy+dy, cz = iz+dz;
            int e = base + k;
            eFlat[e] = (cx*32 + cy)*32 + cz;
            eAgg[e*6+0] = cx*hg; eAgg[e*6+1] = cy*hg; eAgg[e*6+2] = cz*hg;
            eAgg[e*6+3] = px;    eAgg[e*6+4] = py;    eAgg[e*6+5] = pz;
            ++k;
        }
        return;
    }
    int idx = blockIdx.x*256 + threadIdx.x;
    if (idx < 131072) {                       // w2 [512][256] -> w2T [256][512]
        int k = idx >> 8, n = idx & 255;
        w2T[n*512 + k] = (_Float16)w2[idx];
    } else if (idx < 147456) {                // w3 [256][64] -> w3T [64][256]
        int j = idx - 131072;
        int k = j >> 6, o = j & 63;
        w3T[o*256 + k] = (_Float16)w3[j];
    } else if (idx < 151552) {                // w1 [6][512]+b1 -> w1p [512][8]
        int j = idx - 147456;
        int k = j >> 3, d = j & 7;
        float v = d < 6 ? w1[d*512 + k] : (d == 6 ? b1[k] : 0.0f);
        w1p[k*8 + d] = (_Float16)v;
    } else if (idx < 167936) {                // lw2 [256][64] -> split [64][256]
        int j = idx - 151552;
        int o = j >> 8, k = j & 255;
        float v = lw2[k*64 + o];
        _Float16 hi = (_Float16)v;
        l2hi[j] = hi;
        l2lo[j] = (_Float16)(v - (float)hi);
    } else if (idx < 184320) {                // skw [4][64ci][64co] -> split [4][co][ci]
        int j = idx - 167936;
        int l = j >> 12, r = j & 4095;
        int co = r >> 6, ci = r & 63;
        float v = skw[l*4096 + ci*64 + co];
        _Float16 hi = (_Float16)v;
        skwH[j] = hi;
        skwL[j] = (_Float16)(v - (float)hi);
    }
}

// ---------------- lifting via split-fp16 MFMA (r5, unchanged) --------------
__global__ __launch_bounds__(256) void k_lift(
    const float* __restrict__ f, const float* __restrict__ in_p,
    const float* __restrict__ w1, const float* __restrict__ b1,
    const _Float16* __restrict__ l2hi,
    const _Float16* __restrict__ l2lo,
    const float* __restrict__ b2,
    float* __restrict__ h)
{
    __shared__ __align__(16) _Float16 h1hi[64*264];
    __shared__ __align__(16) _Float16 h1lo[64*264];
    __shared__ float w1s[6*256];
    __shared__ float b1s[256];
    float* oT = (float*)h1hi;
    int t = threadIdx.x;
    for (int i = t; i < 1536; i += 256) w1s[i] = w1[i];
    b1s[t] = b1[t];
    int p0 = blockIdx.x * 64;
    int pt = t >> 2, jq = t & 3;
    int p = p0 + pt;
    float x0 = f[p*3+0], x1 = f[p*3+1], x2 = f[p*3+2];
    float x3 = in_p[p*3+0], x4 = in_p[p*3+1], x5 = in_p[p*3+2];
    __syncthreads();
    for (int r = 0; r < 8; ++r) {
        int j0 = jq*64 + r*8;
        f16x8 vh, vl;
        #pragma unroll
        for (int jj = 0; jj < 8; ++jj) {
            int j = j0 + jj;
            float a = b1s[j] + x0*w1s[j] + x1*w1s[256+j] + x2*w1s[512+j]
                    + x3*w1s[768+j] + x4*w1s[1024+j] + x5*w1s[1280+j];
            float g = gelu_f(a);
            _Float16 hi = (_Float16)g;
            vh[jj] = hi;
            vl[jj] = (_Float16)(g - (float)hi);
        }
        *(f16x8*)&h1hi[pt*264 + j0] = vh;
        *(f16x8*)&h1lo[pt*264 + j0] = vl;
    }
    __syncthreads();
    int w = t >> 6, lane = t & 63, l15 = lane & 15, g = lane >> 4;
    f32x4 acc[4];
    #pragma unroll
    for (int nt = 0; nt < 4; ++nt) {
        float bb = b2[nt*16 + l15];
        acc[nt] = (f32x4){bb, bb, bb, bb};
    }
    for (int kk = 0; kk < 8; ++kk) {
        f16x8 ah = *(const f16x8*)&h1hi[(w*16+l15)*264 + kk*32 + g*8];
        f16x8 al = *(const f16x8*)&h1lo[(w*16+l15)*264 + kk*32 + g*8];
        #pragma unroll
        for (int nt = 0; nt < 4; ++nt) {
            f16x8 bh = *(const f16x8*)&l2hi[(nt*16+l15)*256 + kk*32 + g*8];
            f16x8 bl = *(const f16x8*)&l2lo[(nt*16+l15)*256 + kk*32 + g*8];
            acc[nt] = __builtin_amdgcn_mfma_f32_16x16x32_f16(al, bh, acc[nt], 0, 0, 0);
            acc[nt] = __builtin_amdgcn_mfma_f32_16x16x32_f16(ah, bl, acc[nt], 0, 0, 0);
            acc[nt] = __builtin_amdgcn_mfma_f32_16x16x32_f16(ah, bh, acc[nt], 0, 0, 0);
        }
    }
    __syncthreads();
    #pragma unroll
    for (int nt = 0; nt < 4; ++nt)
        #pragma unroll
        for (int r = 0; r < 4; ++r)
            oT[(nt*16 + l15)*68 + w*16 + g*4 + r] = acc[nt][r];
    __syncthreads();
    for (int i = t; i < 4096; i += 256) {
        int c = i >> 6, ptl = i & 63;
        h[(size_t)c*32768 + p0 + ptl] = oT[c*68 + ptl];
    }
}

// ---------------- kA: fused z+y forward DFT (unchanged) --------------------
__global__ __launch_bounds__(256) void k_fwd_zy(const float* __restrict__ h,
                                                float2* __restrict__ F1)
{
    __shared__ float pl[8*1056];
    __shared__ float2 fz[32*73];
    __shared__ float twc[32], tws[32];
    int t = threadIdx.x;
    int x = blockIdx.x >> 3, cg = blockIdx.x & 7;
    for (int i = t; i < 8192; i += 256) {
        int c = i >> 10, yz = i & 1023;
        pl[c*1056 + (yz>>5)*33 + (yz&31)] = h[(cg*8 + c)*32768 + x*1024 + yz];
    }
    if (t < 32) { float th = (float)t*(6.283185307179586f/32.f); twc[t]=cosf(th); tws[t]=sinf(th); }
    __syncthreads();
    {
        int c = t >> 5, y = t & 31;
        float zv[32];
        #pragma unroll
        for (int z = 0; z < 32; ++z) zv[z] = pl[c*1056 + y*33 + z];
        const float inv = 1.0f/32768.0f;
        #pragma unroll
        for (int kz = 0; kz < 8; ++kz) {
            float re = 0.f, im = 0.f;
            #pragma unroll
            for (int z = 0; z < 32; ++z) {
                int ph = (kz*z)&31;
                re += zv[z]*twc[ph];
                im -= zv[z]*tws[ph];
            }
            fz[y*73 + kz*9 + c] = make_float2(re*inv, im*inv);
        }
    }
    __syncthreads();
    #pragma unroll
    for (int ko = 0; ko < 4; ++ko) {
        int idx = ko*256 + t;
        int kyi = idx >> 6, kz = (idx >> 3) & 7, c = idx & 7;
        int ky = kyi < 8 ? kyi : kyi + 16;
        float re = 0.f, im = 0.f;
        for (int y = 0; y < 32; ++y) {
            int ph = (ky*y)&31;
            float cc = twc[ph], ss = tws[ph];
            float2 a = fz[y*73 + kz*9 + c];
            re += a.x*cc + a.y*ss;
            im += a.y*cc - a.x*ss;
        }
        F1[((kyi*8 + kz)*32 + x)*64 + cg*8 + c] = make_float2(re, im);
    }
}

// ---------------- kAx: x forward DFT (unchanged) ---------------------------
__global__ __launch_bounds__(256) void k_fwd_x(const float2* __restrict__ F1,
                                               float2* __restrict__ Ft)
{
    __shared__ float2 fs[32*65];
    __shared__ float twc[32], tws[32];
    int t = threadIdx.x;
    int kyi = blockIdx.x >> 3, kz = blockIdx.x & 7;
    const float2* src = &F1[(size_t)((kyi*8 + kz)*32)*64];
    for (int i = t; i < 2048; i += 256) fs[(i>>6)*65 + (i&63)] = src[i];
    if (t < 32) { float th = (float)t*(6.283185307179586f/32.f); twc[t]=cosf(th); tws[t]=sinf(th); }
    __syncthreads();
    #pragma unroll
    for (int ko = 0; ko < 4; ++ko) {
        int idx = ko*256 + t;
        int kxi = idx >> 6, ii = idx & 63;
        int kx = kxi < 8 ? kxi : kxi + 16;
        float re = 0.f, im = 0.f;
        for (int xx = 0; xx < 32; ++xx) {
            int ph = (kx*xx)&31;
            float cc = twc[ph], ss = tws[ph];
            float2 a = fs[xx*65 + ii];
            re += a.x*cc + a.y*ss;
            im += a.y*cc - a.x*ss;
        }
        Ft[((kxi*16 + kyi)*8 + kz)*64 + ii] = make_float2(re, im);
    }
}

// ---------------- kB: spectral multiply (blocks 0-255) + skip GEMM (256-511)
// spec path identical to r6. skip path: hsk[co][pt] = sum_ci skw[ci][co]*h[ci][pt]
// via split-fp16 MFMA (hi/lo on both operands, 3 MFMA). No bias (added in kC).
__global__ __launch_bounds__(256) void k_spec_skip(const float2* __restrict__ Ft,
                                                   const float* __restrict__ spw,
                                                   const float* __restrict__ hold,
                                                   const _Float16* __restrict__ skwH,
                                                   const _Float16* __restrict__ skwL,
                                                   float2* __restrict__ Gt,
                                                   float* __restrict__ hsk,
                                                   int l)
{
    __shared__ float2 ft2[64*65];                       // spec path
    __shared__ __align__(16) _Float16 shi[128*72];      // skip path
    __shared__ __align__(16) _Float16 slo[128*72];
    int t = threadIdx.x;
    if (blockIdx.x >= 256) {
        // ---------------- skip GEMM path ----------------
        int pt0 = (blockIdx.x - 256) * 128;
        for (int i = t; i < 2048; i += 256) {
            int ci = i >> 5, q = i & 31;
            float4 v = *(const float4*)&hold[(size_t)ci*32768 + pt0 + q*4];
            #pragma unroll
            for (int j = 0; j < 4; ++j) {
                float fv = (&v.x)[j];
                _Float16 hi = (_Float16)fv;
                shi[(q*4+j)*72 + ci] = hi;
                slo[(q*4+j)*72 + ci] = (_Float16)(fv - (float)hi);
            }
        }
        __syncthreads();
        int w = t >> 6, lane = t & 63, l15 = lane & 15, g = lane >> 4;
        f32x4 acc[8];
        #pragma unroll
        for (int nt = 0; nt < 8; ++nt) acc[nt] = (f32x4){0.f, 0.f, 0.f, 0.f};
        #pragma unroll
        for (int kk = 0; kk < 2; ++kk) {
            f16x8 ah = *(const f16x8*)&skwH[l*4096 + (w*16+l15)*64 + kk*32 + g*8];
            f16x8 al = *(const f16x8*)&skwL[l*4096 + (w*16+l15)*64 + kk*32 + g*8];
            #pragma unroll
            for (int nt = 0; nt < 8; ++nt) {
                f16x8 bh = *(const f16x8*)&shi[(nt*16+l15)*72 + kk*32 + g*8];
                f16x8 bl = *(const f16x8*)&slo[(nt*16+l15)*72 + kk*32 + g*8];
                acc[nt] = __builtin_amdgcn_mfma_f32_16x16x32_f16(al, bh, acc[nt], 0, 0, 0);
                acc[nt] = __builtin_amdgcn_mfma_f32_16x16x32_f16(ah, bl, acc[nt], 0, 0, 0);
                acc[nt] = __builtin_amdgcn_mfma_f32_16x16x32_f16(ah, bh, acc[nt], 0, 0, 0);
            }
        }
        #pragma unroll
        for (int nt = 0; nt < 8; ++nt)
            #pragma unroll
            for (int r = 0; r < 4; ++r)
                hsk[(size_t)(w*16 + g*4 + r)*32768 + pt0 + nt*16 + l15] = acc[nt][r];
        return;
    }
    // ---------------- spectral path (r6 k_spec) ----------------
    int og8 = blockIdx.x >> 5, corner = (blockIdx.x >> 3) & 3, mx = blockIdx.x & 7;
    int kxi = mx + (corner >> 1)*8;
    int kyB = (corner & 1)*8;
    {
        int m = t >> 2, iq = t & 3;
        int my = m >> 3, mz = m & 7;
        int rho = (m >> 1) + ((m & 1) << 5);
        const float2* src = &Ft[(size_t)((kxi*16 + kyB + my)*8 + mz)*64];
        #pragma unroll
        for (int ii = 0; ii < 16; ++ii) {
            int i = iq*16 + ii;
            ft2[rho*65 + i] = src[i];
        }
    }
    __syncthreads();
    int mp = t & 31, oq = t >> 5;
    int o = og8*8 + oq;
    int m0 = 2*mp;
    size_t wbase = (size_t)(l*4 + corner)*4194304 + (size_t)o*1024
                 + (size_t)mx*128 + m0*2;
    float ar0 = 0.f, ai0 = 0.f, ar1 = 0.f, ai1 = 0.f;
    for (int i8 = 0; i8 < 64; i8 += 8) {
        float4 wv[8];
        #pragma unroll
        for (int u = 0; u < 8; ++u)
            wv[u] = *(const float4*)&spw[wbase + (size_t)(i8+u)*65536];
        #pragma unroll
        for (int u = 0; u < 8; ++u) {
            float2 f0 = ft2[mp*65 + i8 + u];
            float2 f1 = ft2[(32 + mp)*65 + i8 + u];
            ar0 += f0.x*wv[u].x - f0.y*wv[u].y;
            ai0 += f0.x*wv[u].y + f0.y*wv[u].x;
            ar1 += f1.x*wv[u].z - f1.y*wv[u].w;
            ai1 += f1.x*wv[u].w + f1.y*wv[u].z;
        }
    }
    size_t gbase = (size_t)(o >> 2)*8192 + (size_t)(corner*8 + mx)*256 + (o & 3);
    Gt[gbase + (size_t)m0*4]       = make_float2(ar0, ai0);
    Gt[gbase + (size_t)(m0+1)*4]   = make_float2(ar1, ai1);
}

// ---------------- kC: fused inv-x + inv-y + inv-z + (hsk add) + gelu -------
__global__ __launch_bounds__(256) void k_inv(const float2* __restrict__ Gt,
                                             const float* __restrict__ hsk,
                                             const float* __restrict__ skb,
                                             float* __restrict__ hnew,
                                             float* __restrict__ latent,
                                             int l)
{
    __shared__ float2 gt[8192];
    __shared__ float2 s1[16*8*4];
    __shared__ float2 s2[32*8*4];
    __shared__ float twc[32], tws[32];
    int t = threadIdx.x;
    int x = blockIdx.x >> 4, og = blockIdx.x & 15;
    const float2* gsrc = &Gt[(size_t)og*8192];
    for (int i = t; i < 8192; i += 256) gt[i] = gsrc[i];
    if (t < 32) { float th = (float)t*(6.283185307179586f/32.f); twc[t]=cosf(th); tws[t]=sinf(th); }
    __syncthreads();
    #pragma unroll
    for (int ko = 0; ko < 2; ++ko) {
        int idx = ko*256 + t;
        int kyi = idx >> 5, kz = (idx >> 2) & 7, o = idx & 3;
        int cy = kyi >> 3, my = kyi & 7;
        float re = 0.f, im = 0.f;
        #pragma unroll
        for (int cxh = 0; cxh < 2; ++cxh) {
            int corner = cxh*2 + cy;
            #pragma unroll
            for (int mxx = 0; mxx < 8; ++mxx) {
                int kxi = cxh*8 + mxx;
                int kx = kxi < 8 ? kxi : kxi + 16;
                int ph = (kx * x) & 31;
                float cc = twc[ph], ss = tws[ph];
                float2 a = gt[((corner*8 + mxx)*64 + my*8 + kz)*4 + o];
                re += a.x*cc - a.y*ss;
                im += a.x*ss + a.y*cc;
            }
        }
        s1[(kyi*8 + kz)*4 + o] = make_float2(re, im);
    }
    __syncthreads();
    #pragma unroll
    for (int ko = 0; ko < 4; ++ko) {
        int idx = ko*256 + t;
        int y = idx >> 5, kz = (idx >> 2) & 7, o = idx & 3;
        float re = 0.f, im = 0.f;
        #pragma unroll
        for (int kyi = 0; kyi < 16; ++kyi) {
            int ky = kyi < 8 ? kyi : kyi + 16;
            int ph = (ky*y) & 31;
            float cc = twc[ph], ss = tws[ph];
            float2 a = s1[(kyi*8 + kz)*4 + o];
            re += a.x*cc - a.y*ss;
            im += a.x*ss + a.y*cc;
        }
        s2[(y*8 + kz)*4 + o] = make_float2(re, im);
    }
    __syncthreads();
    float acc[4][4];
    #pragma unroll
    for (int o = 0; o < 4; ++o) {
        float bb = skb[l*64 + og*4 + o];
        float4 hv = *(const float4*)&hsk[(size_t)(og*4+o)*32768 + x*1024 + t*4];
        acc[0][o] = bb + hv.x; acc[1][o] = bb + hv.y;
        acc[2][o] = bb + hv.z; acc[3][o] = bb + hv.w;
    }
    float outv[4][4];
    #pragma unroll
    for (int pp = 0; pp < 4; ++pp) {
        int pt = t*4 + pp;
        int y = pt >> 5, z = pt & 31;
        #pragma unroll
        for (int o = 0; o < 4; ++o) {
            float s = s2[(y*8)*4 + o].x;
            #pragma unroll
            for (int kz = 1; kz < 8; ++kz) {
                int ph = (kz*z) & 31;
                float2 a = s2[(y*8 + kz)*4 + o];
                s += 2.0f*(a.x*twc[ph] - a.y*tws[ph]);
            }
            float v = s + acc[pp][o];
            outv[pp][o] = (l < 3) ? gelu_f(v) : v;
        }
    }
    if (l < 3) {
        #pragma unroll
        for (int o = 0; o < 4; ++o) {
            float4 w4 = make_float4(outv[0][o], outv[1][o], outv[2][o], outv[3][o]);
            *(float4*)&hnew[(size_t)(og*4 + o)*32768 + x*1024 + t*4] = w4;
        }
    } else {
        #pragma unroll
        for (int pp = 0; pp < 4; ++pp) {
            float4 w4 = make_float4(outv[pp][0], outv[pp][1], outv[pp][2], outv[pp][3]);
            *(float4*)&latent[(size_t)(x*1024 + t*4 + pp)*64 + og*4] = w4;
        }
    }
}

// ---------------- GNO stage 2: dense 64-edge MLP tiles (unchanged) ---------
__global__ __launch_bounds__(256, 2) void k_gno_mlp(
    const int* __restrict__ counter,
    const int* __restrict__ eFlat,
    const float* __restrict__ eAgg,
    const _Float16* __restrict__ w1p,
    const _Float16* __restrict__ w2T,
    const float* __restrict__ b2,
    const _Float16* __restrict__ w3T,
    const float* __restrict__ b3,
    const float* __restrict__ latent,
    float* __restrict__ kv)
{
    __shared__ __align__(16) _Float16 h1pool[64*520];
    __shared__ __align__(16) _Float16 w1s[512*8];
    __shared__ float aggs[64][6];
    __shared__ int   flatS[64];
    _Float16* h2h = h1pool;

    int t = threadIdx.x;
    int E = counter[0]; if (E > ECAP) E = ECAP;
    int s = blockIdx.x * 64;
    if (s >= E) return;
    int ne = min(64, E - s);

    for (int i = t; i < 512; i += 256)
        ((int4*)w1s)[i] = ((const int4*)w1p)[i];
    for (int i = t; i < 384; i += 256)
        aggs[i/6][i - (i/6)*6] = (i < ne*6) ? eAgg[(size_t)s*6 + i] : 0.0f;
    if (t < 64) flatS[t] = (t < ne) ? eFlat[s + t] : 0;
    __syncthreads();

    int e = t & 63;
    int w = t >> 6;
    {
        float a0 = aggs[e][0], a1 = aggs[e][1], a2 = aggs[e][2];
        float a3 = aggs[e][3], a4 = aggs[e][4], a5 = aggs[e][5];
        int xk = (e >> 3) & 7;
        #pragma unroll
        for (int ci = 0; ci < 16; ++ci) {
            int c = w*16 + ci;
            f16x8 v;
            #pragma unroll
            for (int jj = 0; jj < 8; ++jj) {
                int k = c*8 + jj;
                f16x8 wv = *(const f16x8*)&w1s[k*8];
                float pre = (float)wv[6]
                    + a0*(float)wv[0] + a1*(float)wv[1] + a2*(float)wv[2]
                    + a3*(float)wv[3] + a4*(float)wv[4] + a5*(float)wv[5];
                v[jj] = (_Float16)gelu_f(pre);
            }
            *(f16x8*)&h1pool[e*520 + ((c ^ xk)*8)] = v;
        }
    }
    __syncthreads();

    int lane = t & 63;
    int l15 = lane & 15, g = lane >> 4;

    f32x4 acc2[4][4];
    #pragma unroll
    for (int nt = 0; nt < 4; ++nt) {
        float bb = b2[w*64 + nt*16 + l15];
        #pragma unroll
        for (int mt = 0; mt < 4; ++mt) acc2[mt][nt] = (f32x4){bb, bb, bb, bb};
    }
    #pragma unroll 4
    for (int kk = 0; kk < 16; ++kk) {
        f16x8 af[4];
        #pragma unroll
        for (int mt = 0; mt < 4; ++mt) {
            int ee = mt*16 + l15;
            af[mt] = *(const f16x8*)&h1pool[ee*520 + (((kk*4 + g) ^ ((ee>>3)&7))*8)];
        }
        #pragma unroll
        for (int nt = 0; nt < 4; ++nt) {
            f16x8 bf = *(const f16x8*)&w2T[(size_t)(w*64 + nt*16 + l15)*512 + kk*32 + g*8];
            #pragma unroll
            for (int mt = 0; mt < 4; ++mt)
                acc2[mt][nt] = __builtin_amdgcn_mfma_f32_16x16x32_f16(af[mt], bf, acc2[mt][nt], 0, 0, 0);
        }
    }
    __syncthreads();
    #pragma unroll
    for (int mt = 0; mt < 4; ++mt)
      #pragma unroll
      for (int nt = 0; nt < 4; ++nt) {
        int n = w*64 + nt*16 + l15;
        #pragma unroll
        for (int r = 0; r < 4; ++r) {
            int m = mt*16 + g*4 + r;
            h2h[m*264 + (((n>>3) ^ (m&7))*8) + (n&7)] = (_Float16)gelu_f(acc2[mt][nt][r]);
        }
      }
    __syncthreads();

    int o = w*16 + l15;
    f32x4 acc3[4];
    { float bb = b3[o];
      #pragma unroll
      for (int mt = 0; mt < 4; ++mt) acc3[mt] = (f32x4){bb, bb, bb, bb}; }
    #pragma unroll 2
    for (int kk2 = 0; kk2 < 8; ++kk2) {
        f16x8 bf = *(const f16x8*)&w3T[(size_t)o*256 + kk2*32 + g*8];
        #pragma unroll
        for (int mt = 0; mt < 4; ++mt) {
            int ee = mt*16 + l15;
            f16x8 af = *(const f16x8*)&h2h[ee*264 + (((kk2*4 + g) ^ (ee&7))*8)];
            acc3[mt] = __builtin_amdgcn_mfma_f32_16x16x32_f16(af, bf, acc3[mt], 0, 0, 0);
        }
    }

    #pragma unroll
    for (int mt = 0; mt < 4; ++mt) {
        #pragma unroll
        for (int r = 0; r < 4; ++r) {
            int ee = mt*16 + g*4 + r;
            if (ee < ne) {
                float fy = latent[(size_t)flatS[ee]*64 + o];
                kv[(size_t)(s + ee)*64 + o] = acc3[mt][r] * fy;
            }
        }
    }
}

// ---------------- projection, fused with per-point kv gather ---------------
__global__ __launch_bounds__(256) void k_project(const int* __restrict__ baseG,
                                                 const int* __restrict__ cntG,
                                                 const float* __restrict__ kv,
                                                 const float* __restrict__ pw1,
                                                 const float* __restrict__ pb1,
                                                 const float* __restrict__ pw2,
                                                 const float* __restrict__ pb2,
                                                 float* __restrict__ outp)
{
    __shared__ float w1s[64*260];
    __shared__ float xT[64*68];
    __shared__ float w2s[256];
    __shared__ float b1s[256];
    __shared__ float red[64*4];
    int t = threadIdx.x;
    int p0 = blockIdx.x * 64;
    for (int i = t; i < 16384; i += 256) {
        int k = i >> 8, o = i & 255;
        w1s[k*260 + o] = pw1[i];
    }
    w2s[t] = pw2[t];
    b1s[t] = pb1[t];
    for (int i = t; i < 4096; i += 256) {      // gather-reduce: num on the fly
        int ptl = i >> 6, c = i & 63;
        int p = p0 + ptl;
        int base = baseG[p], cnt = cntG[p];
        float acc = 0.f;
        for (int j = 0; j < cnt; ++j) acc += kv[(size_t)(base + j)*64 + c];
        xT[c*68 + ptl] = acc / fmaxf((float)cnt, 1.0f);
    }
    __syncthreads();
    int pr = t & 15, oc0 = t >> 4;
    float psum[4] = {0.f, 0.f, 0.f, 0.f};
    for (int it = 0; it < 4; ++it) {
        int oc = it*16 + oc0;
        float a[4][4];
        #pragma unroll
        for (int pp = 0; pp < 4; ++pp)
            #pragma unroll
            for (int q = 0; q < 4; ++q) a[pp][q] = b1s[oc*4 + q];
        for (int i = 0; i < 64; ++i) {
            float4 xv = *(const float4*)&xT[i*68 + pr*4];
            float4 wv = *(const float4*)&w1s[i*260 + oc*4];
            #pragma unroll
            for (int q = 0; q < 4; ++q) {
                float wq = (&wv.x)[q];
                a[0][q] += xv.x*wq; a[1][q] += xv.y*wq;
                a[2][q] += xv.z*wq; a[3][q] += xv.w*wq;
            }
        }
        #pragma unroll
        for (int pp = 0; pp < 4; ++pp) {
            float s = 0.f;
            #pragma unroll
            for (int q = 0; q < 4; ++q) s += gelu_f(a[pp][q]) * w2s[oc*4 + q];
            psum[pp] += s;
        }
    }
    #pragma unroll
    for (int pp = 0; pp < 4; ++pp) {
        psum[pp] += __shfl_xor(psum[pp], 16, 64);
        psum[pp] += __shfl_xor(psum[pp], 32, 64);
    }
    int lane = t & 63, w = t >> 6;
    if (lane < 16) {
        #pragma unroll
        for (int pp = 0; pp < 4; ++pp) red[(lane*4 + pp)*4 + w] = psum[pp];
    }
    __syncthreads();
    if (t < 64)
        outp[p0 + t] = red[t*4+0] + red[t*4+1] + red[t*4+2] + red[t*4+3] + pb2[0];
}

// ---------------------------------------------------------------------------
extern "C" void kernel_launch(void* const* d_in, const int* in_sizes, int n_in,
                              void* d_out, int out_size, void* d_ws, size_t ws_size,
                              hipStream_t stream)
{
    const float* in_p = (const float*)d_in[0];
    const float* outp = (const float*)d_in[1];
    const float* f    = (const float*)d_in[2];
    const float* lw1  = (const float*)d_in[3];
    const float* lb1  = (const float*)d_in[4];
    const float* lw2  = (const float*)d_in[5];
    const float* lb2  = (const float*)d_in[6];
    const float* spw  = (const float*)d_in[7];
    const float* skw  = (const float*)d_in[8];
    const float* skb  = (const float*)d_in[9];
    const float* gw1  = (const float*)d_in[10];
    const float* gb1  = (const float*)d_in[11];
    const float* gw2  = (const float*)d_in[12];
    const float* gb2  = (const float*)d_in[13];
    const float* gw3  = (const float*)d_in[14];
    const float* gb3  = (const float*)d_in[15];
    const float* pw1  = (const float*)d_in[16];
    const float* pb1  = (const float*)d_in[17];
    const float* pw2  = (const float*)d_in[18];
    const float* pb2  = (const float*)d_in[19];

    float* ws   = (float*)d_ws;
    float* buf0 = ws;                           // c-major h / latent pt-major
    float* buf1 = ws + 2097152;
    float* SC   = ws + 4194304;
    float2* F1 = (float2*)SC;                   // FNO phase scratch
    float2* Ft = (float2*)(SC + 524288);
    float2* Gt = (float2*)(SC + 786432);
    _Float16* w2T  = (_Float16*)(SC + 1048576);
    _Float16* w3T  = (_Float16*)(SC + 1114112);
    _Float16* w1p  = (_Float16*)(SC + 1122304);
    _Float16* l2hi = (_Float16*)(SC + 1124352);
    _Float16* l2lo = (_Float16*)(SC + 1132544);
    _Float16* skwH = (_Float16*)(SC + 1140736); // 16384 halves
    _Float16* skwL = (_Float16*)(SC + 1148928); // 16384 halves
    int*   counter = (int*)(SC + 1157120);
    int*   baseG   = (int*)(SC + 1157136);
    int*   cntG    = (int*)(SC + 1173520);
    int*   eFlat   = (int*)(SC + 1189904);
    float* eAgg    = SC + 1320976;              // 131072*6
    float* kv      = SC + 2107408;              // 131072*64
    float* hsk     = SC + 10496016;             // 2097152 (skip GEMM out, c-major)

    hipMemsetAsync(counter, 0, sizeof(int), stream);
    k_prep<<<784, 256, 0, stream>>>(gw2, gw3, gw1, gb1, lw2, skw, outp,
                                    w2T, w3T, w1p, l2hi, l2lo, skwH, skwL,
                                    counter, baseG, cntG, eFlat, eAgg);
    k_lift<<<512, 256, 0, stream>>>(f, in_p, lw1, lb1, l2hi, l2lo, lb2, buf0);

    for (int l = 0; l < 4; ++l) {
        const float* hin = (l & 1) ? buf1 : buf0;
        float* hout = (l & 1) ? buf0 : buf1;
        k_fwd_zy<<<256, 256, 0, stream>>>(hin, F1);
        k_fwd_x<<<128, 256, 0, stream>>>(F1, Ft);
        k_spec_skip<<<512, 256, 0, stream>>>(Ft, spw, hin, skwH, skwL, Gt, hsk, l);
        k_inv<<<512, 256, 0, stream>>>(Gt, hsk, skb, hout, buf0, l);
    }
    // latent = buf0 (point-major, written by k_inv at l=3)

    k_gno_mlp<<<ECAP/64, 256, 0, stream>>>(counter, eFlat, eAgg,
                                           w1p, w2T, gb2, w3T, gb3, buf0, kv);
    k_project<<<256, 256, 0, stream>>>(baseG, cntG, kv, pw1, pb1, pw2, pb2,
                                       (float*)d_out);
}

// Round 8
// 357.666 us; speedup vs baseline: 2.4575x; 1.1622x over previous
//
#include <hip/hip_runtime.h>
#include <math.h>

// ---------------------------------------------------------------------------
// FNO-GNO round 8: occupancy + dispatch-count attack.
//  - k_inv_zy: inv-x/y/z + skip-add + gelu FUSED with next layer's z+y fwd
//    DFT (both touch only x-column x). 512 thr, Gt read direct from L2
//    (old 64 KB LDS staging was single-use), h never re-read from global.
//  - k_spec_skip: LDS overlay (union of spec/skip branches) 69 -> 36 KB.
//  - k_fwd_x: 256 blocks (i-dim split), was 128.
//  - Dispatches 22 -> 18.
//  - lift / prep / gno_mlp / project unchanged from r7 (passing, 2.44e-4).
// ---------------------------------------------------------------------------

#define ECAP 131072

typedef _Float16 f16x8 __attribute__((ext_vector_type(8)));
typedef float f32x4 __attribute__((ext_vector_type(4)));

__device__ __forceinline__ float gelu_f(float x) {
    float t = fabsf(x) * 0.7071067811865475f;
    float k = __builtin_amdgcn_rcpf(1.0f + 0.3275911f * t);
    float e = __expf(-t * t);
    float y = k*(0.254829592f + k*(-0.284496736f + k*(1.421413741f +
              k*(-1.453152027f + k*1.061405429f))));
    float erfv = 1.0f - y * e;
    return 0.5f * x * (1.0f + copysignf(erfv, x));
}

// ---------------- prep (weights) + GNO edge build, fused (r7) ---------------
__global__ __launch_bounds__(256) void k_prep(const float* __restrict__ w2,
                                              const float* __restrict__ w3,
                                              const float* __restrict__ w1,
                                              const float* __restrict__ b1,
                                              const float* __restrict__ lw2,
                                              const float* __restrict__ skw,
                                              const float* __restrict__ out_p,
                                              _Float16* __restrict__ w2T,
                                              _Float16* __restrict__ w3T,
                                              _Float16* __restrict__ w1p,
                                              _Float16* __restrict__ l2hi,
                                              _Float16* __restrict__ l2lo,
                                              _Float16* __restrict__ skwH,
                                              _Float16* __restrict__ skwL,
                                              int* __restrict__ counter,
                                              int* __restrict__ baseG,
                                              int* __restrict__ cntG,
                                              int* __restrict__ eFlat,
                                              float* __restrict__ eAgg)
{
    if (blockIdx.x >= 720) {
        int n = (blockIdx.x - 720)*256 + threadIdx.x;
        const float hg = 1.0f/31.0f;
        const float r2 = (float)(0.033*0.033);
        float px = out_p[n*3+0], py = out_p[n*3+1], pz = out_p[n*3+2];
        int ix = (int)rintf(px*31.f), iy = (int)rintf(py*31.f), iz = (int)rintf(pz*31.f);
        unsigned msk = 0; int cnt = 0;
        for (int j = 0; j < 27; ++j) {
            int dx = j/9 - 1, dy = (j/3)%3 - 1, dz = j%3 - 1;
            int cx = ix+dx, cy = iy+dy, cz = iz+dz;
            bool inb = (cx>=0)&&(cx<32)&&(cy>=0)&&(cy<32)&&(cz>=0)&&(cz<32);
            int qx = min(max(cx,0),31), qy = min(max(cy,0),31), qz = min(max(cz,0),31);
            float yx = qx*hg, yy = qy*hg, yz = qz*hg;
            float d2 = (px-yx)*(px-yx) + (py-yy)*(py-yy) + (pz-yz)*(pz-yz);
            if (inb && d2 <= r2) { msk |= 1u<<j; cnt++; }
        }
        int base = atomicAdd(counter, cnt);
        baseG[n] = base; cntG[n] = cnt;
        int k = 0;
        for (int j = 0; j < 27; ++j) if (msk & (1u<<j)) {
            int dx = j/9 - 1, dy = (j/3)%3 - 1, dz = j%3 - 1;
            int cx = ix+dx, cy = iy+dy, cz = iz+dz;
            int e = base + k;
            eFlat[e] = (cx*32 + cy)*32 + cz;
            eAgg[e*6+0] = cx*hg; eAgg[e*6+1] = cy*hg; eAgg[e*6+2] = cz*hg;
            eAgg[e*6+3] = px;    eAgg[e*6+4] = py;    eAgg[e*6+5] = pz;
            ++k;
        }
        return;
    }
    int idx = blockIdx.x*256 + threadIdx.x;
    if (idx < 131072) {
        int k = idx >> 8, n = idx & 255;
        w2T[n*512 + k] = (_Float16)w2[idx];
    } else if (idx < 147456) {
        int j = idx - 131072;
        int k = j >> 6, o = j & 63;
        w3T[o*256 + k] = (_Float16)w3[j];
    } else if (idx < 151552) {
        int j = idx - 147456;
        int k = j >> 3, d = j & 7;
        float v = d < 6 ? w1[d*512 + k] : (d == 6 ? b1[k] : 0.0f);
        w1p[k*8 + d] = (_Float16)v;
    } else if (idx < 167936) {
        int j = idx - 151552;
        int o = j >> 8, k = j & 255;
        float v = lw2[k*64 + o];
        _Float16 hi = (_Float16)v;
        l2hi[j] = hi;
        l2lo[j] = (_Float16)(v - (float)hi);
    } else if (idx < 184320) {
        int j = idx - 167936;
        int l = j >> 12, r = j & 4095;
        int co = r >> 6, ci = r & 63;
        float v = skw[l*4096 + ci*64 + co];
        _Float16 hi = (_Float16)v;
        skwH[j] = hi;
        skwL[j] = (_Float16)(v - (float)hi);
    }
}

// ---------------- lifting via split-fp16 MFMA (unchanged) ------------------
__global__ __launch_bounds__(256) void k_lift(
    const float* __restrict__ f, const float* __restrict__ in_p,
    const float* __restrict__ w1, const float* __restrict__ b1,
    const _Float16* __restrict__ l2hi,
    const _Float16* __restrict__ l2lo,
    const float* __restrict__ b2,
    float* __restrict__ h)
{
    __shared__ __align__(16) _Float16 h1hi[64*264];
    __shared__ __align__(16) _Float16 h1lo[64*264];
    __shared__ float w1s[6*256];
    __shared__ float b1s[256];
    float* oT = (float*)h1hi;
    int t = threadIdx.x;
    for (int i = t; i < 1536; i += 256) w1s[i] = w1[i];
    b1s[t] = b1[t];
    int p0 = blockIdx.x * 64;
    int pt = t >> 2, jq = t & 3;
    int p = p0 + pt;
    float x0 = f[p*3+0], x1 = f[p*3+1], x2 = f[p*3+2];
    float x3 = in_p[p*3+0], x4 = in_p[p*3+1], x5 = in_p[p*3+2];
    __syncthreads();
    for (int r = 0; r < 8; ++r) {
        int j0 = jq*64 + r*8;
        f16x8 vh, vl;
        #pragma unroll
        for (int jj = 0; jj < 8; ++jj) {
            int j = j0 + jj;
            float a = b1s[j] + x0*w1s[j] + x1*w1s[256+j] + x2*w1s[512+j]
                    + x3*w1s[768+j] + x4*w1s[1024+j] + x5*w1s[1280+j];
            float g = gelu_f(a);
            _Float16 hi = (_Float16)g;
            vh[jj] = hi;
            vl[jj] = (_Float16)(g - (float)hi);
        }
        *(f16x8*)&h1hi[pt*264 + j0] = vh;
        *(f16x8*)&h1lo[pt*264 + j0] = vl;
    }
    __syncthreads();
    int w = t >> 6, lane = t & 63, l15 = lane & 15, g = lane >> 4;
    f32x4 acc[4];
    #pragma unroll
    for (int nt = 0; nt < 4; ++nt) {
        float bb = b2[nt*16 + l15];
        acc[nt] = (f32x4){bb, bb, bb, bb};
    }
    for (int kk = 0; kk < 8; ++kk) {
        f16x8 ah = *(const f16x8*)&h1hi[(w*16+l15)*264 + kk*32 + g*8];
        f16x8 al = *(const f16x8*)&h1lo[(w*16+l15)*264 + kk*32 + g*8];
        #pragma unroll
        for (int nt = 0; nt < 4; ++nt) {
            f16x8 bh = *(const f16x8*)&l2hi[(nt*16+l15)*256 + kk*32 + g*8];
            f16x8 bl = *(const f16x8*)&l2lo[(nt*16+l15)*256 + kk*32 + g*8];
            acc[nt] = __builtin_amdgcn_mfma_f32_16x16x32_f16(al, bh, acc[nt], 0, 0, 0);
            acc[nt] = __builtin_amdgcn_mfma_f32_16x16x32_f16(ah, bl, acc[nt], 0, 0, 0);
            acc[nt] = __builtin_amdgcn_mfma_f32_16x16x32_f16(ah, bh, acc[nt], 0, 0, 0);
        }
    }
    __syncthreads();
    #pragma unroll
    for (int nt = 0; nt < 4; ++nt)
        #pragma unroll
        for (int r = 0; r < 4; ++r)
            oT[(nt*16 + l15)*68 + w*16 + g*4 + r] = acc[nt][r];
    __syncthreads();
    for (int i = t; i < 4096; i += 256) {
        int c = i >> 6, ptl = i & 63;
        h[(size_t)c*32768 + p0 + ptl] = oT[c*68 + ptl];
    }
}

// ---------------- kA: fused z+y forward DFT (layer 0 only) -----------------
__global__ __launch_bounds__(256) void k_fwd_zy(const float* __restrict__ h,
                                                float2* __restrict__ F1)
{
    __shared__ float pl[8*1056];
    __shared__ float2 fz[32*73];
    __shared__ float twc[32], tws[32];
    int t = threadIdx.x;
    int x = blockIdx.x >> 3, cg = blockIdx.x & 7;
    for (int i = t; i < 8192; i += 256) {
        int c = i >> 10, yz = i & 1023;
        pl[c*1056 + (yz>>5)*33 + (yz&31)] = h[(cg*8 + c)*32768 + x*1024 + yz];
    }
    if (t < 32) { float th = (float)t*(6.283185307179586f/32.f); twc[t]=cosf(th); tws[t]=sinf(th); }
    __syncthreads();
    {
        int c = t >> 5, y = t & 31;
        float zv[32];
        #pragma unroll
        for (int z = 0; z < 32; ++z) zv[z] = pl[c*1056 + y*33 + z];
        const float inv = 1.0f/32768.0f;
        #pragma unroll
        for (int kz = 0; kz < 8; ++kz) {
            float re = 0.f, im = 0.f;
            #pragma unroll
            for (int z = 0; z < 32; ++z) {
                int ph = (kz*z)&31;
                re += zv[z]*twc[ph];
                im -= zv[z]*tws[ph];
            }
            fz[y*73 + kz*9 + c] = make_float2(re*inv, im*inv);
        }
    }
    __syncthreads();
    #pragma unroll
    for (int ko = 0; ko < 4; ++ko) {
        int idx = ko*256 + t;
        int kyi = idx >> 6, kz = (idx >> 3) & 7, c = idx & 7;
        int ky = kyi < 8 ? kyi : kyi + 16;
        float re = 0.f, im = 0.f;
        for (int y = 0; y < 32; ++y) {
            int ph = (ky*y)&31;
            float cc = twc[ph], ss = tws[ph];
            float2 a = fz[y*73 + kz*9 + c];
            re += a.x*cc + a.y*ss;
            im += a.y*cc - a.x*ss;
        }
        F1[((kyi*8 + kz)*32 + x)*64 + cg*8 + c] = make_float2(re, im);
    }
}

// ---------------- kAx: x forward DFT, 256 blocks (i-dim split) -------------
__global__ __launch_bounds__(256) void k_fwd_x(const float2* __restrict__ F1,
                                               float2* __restrict__ Ft)
{
    __shared__ float2 fs[32*33];
    __shared__ float twc[32], tws[32];
    int t = threadIdx.x;
    int b = blockIdx.x;
    int kyi = b >> 4, kz = (b >> 1) & 7, ih = b & 1;
    const float2* src = &F1[(size_t)((kyi*8 + kz)*32)*64 + ih*32];
    for (int i = t; i < 1024; i += 256) {
        int xx = i >> 5, il = i & 31;
        fs[xx*33 + il] = src[xx*64 + il];
    }
    if (t < 32) { float th = (float)t*(6.283185307179586f/32.f); twc[t]=cosf(th); tws[t]=sinf(th); }
    __syncthreads();
    #pragma unroll
    for (int ko = 0; ko < 2; ++ko) {
        int idx = ko*256 + t;
        int kxi = idx >> 5, il = idx & 31;
        int kx = kxi < 8 ? kxi : kxi + 16;
        float re = 0.f, im = 0.f;
        for (int xx = 0; xx < 32; ++xx) {
            int ph = (kx*xx)&31;
            float cc = twc[ph], ss = tws[ph];
            float2 a = fs[xx*33 + il];
            re += a.x*cc + a.y*ss;
            im += a.y*cc - a.x*ss;
        }
        Ft[((kxi*16 + kyi)*8 + kz)*64 + ih*32 + il] = make_float2(re, im);
    }
}

// ---------------- kB: spectral (0-255) + skip GEMM (256-511), LDS overlay --
__global__ __launch_bounds__(256) void k_spec_skip(const float2* __restrict__ Ft,
                                                   const float* __restrict__ spw,
                                                   const float* __restrict__ hold,
                                                   const _Float16* __restrict__ skwH,
                                                   const _Float16* __restrict__ skwL,
                                                   float2* __restrict__ Gt,
                                                   float* __restrict__ hsk,
                                                   int l)
{
    __shared__ __align__(16) char pool[36864];
    int t = threadIdx.x;
    if (blockIdx.x >= 256) {
        _Float16* shi = (_Float16*)pool;              // 128*72 halves
        _Float16* slo = (_Float16*)(pool + 18432);
        int pt0 = (blockIdx.x - 256) * 128;
        for (int i = t; i < 2048; i += 256) {
            int ci = i >> 5, q = i & 31;
            float4 v = *(const float4*)&hold[(size_t)ci*32768 + pt0 + q*4];
            #pragma unroll
            for (int j = 0; j < 4; ++j) {
                float fv = (&v.x)[j];
                _Float16 hi = (_Float16)fv;
                shi[(q*4+j)*72 + ci] = hi;
                slo[(q*4+j)*72 + ci] = (_Float16)(fv - (float)hi);
            }
        }
        __syncthreads();
        int w = t >> 6, lane = t & 63, l15 = lane & 15, g = lane >> 4;
        f32x4 acc[8];
        #pragma unroll
        for (int nt = 0; nt < 8; ++nt) acc[nt] = (f32x4){0.f, 0.f, 0.f, 0.f};
        #pragma unroll
        for (int kk = 0; kk < 2; ++kk) {
            f16x8 ah = *(const f16x8*)&skwH[l*4096 + (w*16+l15)*64 + kk*32 + g*8];
            f16x8 al = *(const f16x8*)&skwL[l*4096 + (w*16+l15)*64 + kk*32 + g*8];
            #pragma unroll
            for (int nt = 0; nt < 8; ++nt) {
                f16x8 bh = *(const f16x8*)&shi[(nt*16+l15)*72 + kk*32 + g*8];
                f16x8 bl = *(const f16x8*)&slo[(nt*16+l15)*72 + kk*32 + g*8];
                acc[nt] = __builtin_amdgcn_mfma_f32_16x16x32_f16(al, bh, acc[nt], 0, 0, 0);
                acc[nt] = __builtin_amdgcn_mfma_f32_16x16x32_f16(ah, bl, acc[nt], 0, 0, 0);
                acc[nt] = __builtin_amdgcn_mfma_f32_16x16x32_f16(ah, bh, acc[nt], 0, 0, 0);
            }
        }
        #pragma unroll
        for (int nt = 0; nt < 8; ++nt)
            #pragma unroll
            for (int r = 0; r < 4; ++r)
                hsk[(size_t)(w*16 + g*4 + r)*32768 + pt0 + nt*16 + l15] = acc[nt][r];
        return;
    }
    float2* ft2 = (float2*)pool;                      // 64*65 float2 = 33280 B
    int og8 = blockIdx.x >> 5, corner = (blockIdx.x >> 3) & 3, mx = blockIdx.x & 7;
    int kxi = mx + (corner >> 1)*8;
    int kyB = (corner & 1)*8;
    {
        int m = t >> 2, iq = t & 3;
        int my = m >> 3, mz = m & 7;
        int rho = (m >> 1) + ((m & 1) << 5);
        const float2* src = &Ft[(size_t)((kxi*16 + kyB + my)*8 + mz)*64];
        #pragma unroll
        for (int ii = 0; ii < 16; ++ii) {
            int i = iq*16 + ii;
            ft2[rho*65 + i] = src[i];
        }
    }
    __syncthreads();
    int mp = t & 31, oq = t >> 5;
    int o = og8*8 + oq;
    int m0 = 2*mp;
    size_t wbase = (size_t)(l*4 + corner)*4194304 + (size_t)o*1024
                 + (size_t)mx*128 + m0*2;
    float ar0 = 0.f, ai0 = 0.f, ar1 = 0.f, ai1 = 0.f;
    for (int i8 = 0; i8 < 64; i8 += 8) {
        float4 wv[8];
        #pragma unroll
        for (int u = 0; u < 8; ++u)
            wv[u] = *(const float4*)&spw[wbase + (size_t)(i8+u)*65536];
        #pragma unroll
        for (int u = 0; u < 8; ++u) {
            float2 f0 = ft2[mp*65 + i8 + u];
            float2 f1 = ft2[(32 + mp)*65 + i8 + u];
            ar0 += f0.x*wv[u].x - f0.y*wv[u].y;
            ai0 += f0.x*wv[u].y + f0.y*wv[u].x;
            ar1 += f1.x*wv[u].z - f1.y*wv[u].w;
            ai1 += f1.x*wv[u].w + f1.y*wv[u].z;
        }
    }
    size_t gbase = (size_t)(o >> 2)*8192 + (size_t)(corner*8 + mx)*256 + (o & 3);
    Gt[gbase + (size_t)m0*4]       = make_float2(ar0, ai0);
    Gt[gbase + (size_t)(m0+1)*4]   = make_float2(ar1, ai1);
}

// ---------------- kC: inv-x/y/z + skip-add + gelu + NEXT-LAYER z+y DFT -----
// grid 256 = (x 32) x (cg 8); 512 threads. Gt read direct (L2). For l<3 the
// fused fwd z+y stage reads h from LDS (pl), writes F1; h also stored to
// global (hnew) for the next layer's skip GEMM. l==3: writes latent, no DFT.
__global__ __launch_bounds__(512) void k_inv_zy(const float2* __restrict__ Gt,
                                                const float* __restrict__ hsk,
                                                const float* __restrict__ skb,
                                                float* __restrict__ hnew,
                                                float* __restrict__ latent,
                                                float2* __restrict__ F1,
                                                int l, int do_zy)
{
    __shared__ __align__(16) char pool[58368];
    __shared__ float twc[32], tws[32];
    float2* s1 = (float2*)pool;                  // [kyi16][kz8][o8]   8 KB
    float2* s2 = (float2*)(pool + 8192);         // [y32][kz8][o8]    16 KB
    float*  pl = (float*)(pool + 24576);         // [c8][y32][z33]  33.8 KB
    float2* fz = (float2*)pool;                  // [y32][kz8*9+c]  18.7 KB (aliases s1/s2 after C)

    int t = threadIdx.x;
    int x = blockIdx.x >> 3, cg = blockIdx.x & 7;
    if (t < 32) { float th = (float)t*(6.283185307179586f/32.f); twc[t]=cosf(th); tws[t]=sinf(th); }
    __syncthreads();
    // phase A: inv-x, direct Gt reads
    #pragma unroll
    for (int ko = 0; ko < 2; ++ko) {
        int idx = ko*512 + t;                    // = (kyi*8+kz)*8 + o
        int kyi = idx >> 6, kz = (idx >> 3) & 7, o = idx & 7;
        int cy = kyi >> 3, my = kyi & 7;
        const float2* gb = Gt + (size_t)(cg*2 + (o>>2))*8192 + my*32 + kz*4 + (o&3);
        float re = 0.f, im = 0.f;
        #pragma unroll
        for (int cxh = 0; cxh < 2; ++cxh) {
            int corner = cxh*2 + cy;
            #pragma unroll
            for (int mxx = 0; mxx < 8; ++mxx) {
                int kxi = cxh*8 + mxx;
                int kx = kxi < 8 ? kxi : kxi + 16;
                int ph = (kx * x) & 31;
                float cc = twc[ph], ss = tws[ph];
                float2 a = gb[(corner*8 + mxx)*256];
                re += a.x*cc - a.y*ss;
                im += a.x*ss + a.y*cc;
            }
        }
        s1[idx] = make_float2(re, im);
    }
    __syncthreads();
    // phase B: inv-y
    #pragma unroll
    for (int ko = 0; ko < 4; ++ko) {
        int idx = ko*512 + t;                    // = (y*8+kz)*8 + o
        int y = idx >> 6, kz = (idx >> 3) & 7, o = idx & 7;
        float re = 0.f, im = 0.f;
        #pragma unroll
        for (int kyi = 0; kyi < 16; ++kyi) {
            int ky = kyi < 8 ? kyi : kyi + 16;
            int ph = (ky*y) & 31;
            float cc = twc[ph], ss = tws[ph];
            float2 a = s1[kyi*64 + kz*8 + o];
            re += a.x*cc - a.y*ss;
            im += a.x*ss + a.y*cc;
        }
        s2[idx] = make_float2(re, im);
    }
    __syncthreads();
    // phase C: inv-z + skip-add + gelu; thread owns 2 points x 8 channels
    {
        float outv[2][8];
        #pragma unroll
        for (int o = 0; o < 8; ++o) {
            float bb = skb[l*64 + cg*8 + o];
            float2 hv = *(const float2*)&hsk[(size_t)(cg*8+o)*32768 + x*1024 + t*2];
            outv[0][o] = bb + hv.x;
            outv[1][o] = bb + hv.y;
        }
        #pragma unroll
        for (int pp = 0; pp < 2; ++pp) {
            int pt = t*2 + pp;
            int y = pt >> 5, z = pt & 31;
            #pragma unroll
            for (int o = 0; o < 8; ++o) {
                float s = s2[y*64 + o].x;        // kz=0 (imag discarded)
                #pragma unroll
                for (int kz = 1; kz < 8; ++kz) {
                    int ph = (kz*z) & 31;
                    float2 a = s2[y*64 + kz*8 + o];
                    s += 2.0f*(a.x*twc[ph] - a.y*tws[ph]);
                }
                float v = s + outv[pp][o];
                outv[pp][o] = (l < 3) ? gelu_f(v) : v;
            }
        }
        if (l < 3) {
            #pragma unroll
            for (int o = 0; o < 8; ++o) {
                int pt = t*2;
                int y = pt >> 5, z = pt & 31;
                pl[o*1056 + y*33 + z]     = outv[0][o];
                pl[o*1056 + y*33 + z + 1] = outv[1][o];   // pt, pt+1 share y (z,z+1)
                *(float2*)&hnew[(size_t)(cg*8+o)*32768 + x*1024 + pt] =
                    make_float2(outv[0][o], outv[1][o]);
            }
        } else {
            #pragma unroll
            for (int pp = 0; pp < 2; ++pp) {
                int pt = t*2 + pp;
                float4 w0 = make_float4(outv[pp][0], outv[pp][1], outv[pp][2], outv[pp][3]);
                float4 w1 = make_float4(outv[pp][4], outv[pp][5], outv[pp][6], outv[pp][7]);
                *(float4*)&latent[(size_t)(x*1024 + pt)*64 + cg*8]     = w0;
                *(float4*)&latent[(size_t)(x*1024 + pt)*64 + cg*8 + 4] = w1;
            }
        }
    }
    if (!do_zy) return;
    __syncthreads();
    // fused next-layer z-stage (h from pl, never global)
    {
        int c = t >> 6, y = t & 31, sub = (t >> 5) & 1;
        float zv[32];
        #pragma unroll
        for (int z = 0; z < 32; ++z) zv[z] = pl[c*1056 + y*33 + z];
        const float inv = 1.0f/32768.0f;
        #pragma unroll
        for (int kq = 0; kq < 4; ++kq) {
            int kz = sub*4 + kq;
            float re = 0.f, im = 0.f;
            #pragma unroll
            for (int z = 0; z < 32; ++z) {
                int ph = (kz*z)&31;
                re += zv[z]*twc[ph];
                im -= zv[z]*tws[ph];
            }
            fz[y*73 + kz*9 + c] = make_float2(re*inv, im*inv);
        }
    }
    __syncthreads();
    // fused next-layer y-stage -> F1
    #pragma unroll
    for (int ko = 0; ko < 2; ++ko) {
        int idx = ko*512 + t;
        int kyi = idx >> 6, kz = (idx >> 3) & 7, c = idx & 7;
        int ky = kyi < 8 ? kyi : kyi + 16;
        float re = 0.f, im = 0.f;
        for (int y = 0; y < 32; ++y) {
            int ph = (ky*y)&31;
            float cc = twc[ph], ss = tws[ph];
            float2 a = fz[y*73 + kz*9 + c];
            re += a.x*cc + a.y*ss;
            im += a.y*cc - a.x*ss;
        }
        F1[((kyi*8 + kz)*32 + x)*64 + cg*8 + c] = make_float2(re, im);
    }
}

// ---------------- GNO stage 2: dense 64-edge MLP tiles (unchanged) ---------
__global__ __launch_bounds__(256, 2) void k_gno_mlp(
    const int* __restrict__ counter,
    const int* __restrict__ eFlat,
    const float* __restrict__ eAgg,
    const _Float16* __restrict__ w1p,
    const _Float16* __restrict__ w2T,
    const float* __restrict__ b2,
    const _Float16* __restrict__ w3T,
    const float* __restrict__ b3,
    const float* __restrict__ latent,
    float* __restrict__ kv)
{
    __shared__ __align__(16) _Float16 h1pool[64*520];
    __shared__ __align__(16) _Float16 w1s[512*8];
    __shared__ float aggs[64][6];
    __shared__ int   flatS[64];
    _Float16* h2h = h1pool;

    int t = threadIdx.x;
    int E = counter[0]; if (E > ECAP) E = ECAP;
    int s = blockIdx.x * 64;
    if (s >= E) return;
    int ne = min(64, E - s);

    for (int i = t; i < 512; i += 256)
        ((int4*)w1s)[i] = ((const int4*)w1p)[i];
    for (int i = t; i < 384; i += 256)
        aggs[i/6][i - (i/6)*6] = (i < ne*6) ? eAgg[(size_t)s*6 + i] : 0.0f;
    if (t < 64) flatS[t] = (t < ne) ? eFlat[s + t] : 0;
    __syncthreads();

    int e = t & 63;
    int w = t >> 6;
    {
        float a0 = aggs[e][0], a1 = aggs[e][1], a2 = aggs[e][2];
        float a3 = aggs[e][3], a4 = aggs[e][4], a5 = aggs[e][5];
        int xk = (e >> 3) & 7;
        #pragma unroll
        for (int ci = 0; ci < 16; ++ci) {
            int c = w*16 + ci;
            f16x8 v;
            #pragma unroll
            for (int jj = 0; jj < 8; ++jj) {
                int k = c*8 + jj;
                f16x8 wv = *(const f16x8*)&w1s[k*8];
                float pre = (float)wv[6]
                    + a0*(float)wv[0] + a1*(float)wv[1] + a2*(float)wv[2]
                    + a3*(float)wv[3] + a4*(float)wv[4] + a5*(float)wv[5];
                v[jj] = (_Float16)gelu_f(pre);
            }
            *(f16x8*)&h1pool[e*520 + ((c ^ xk)*8)] = v;
        }
    }
    __syncthreads();

    int lane = t & 63;
    int l15 = lane & 15, g = lane >> 4;

    f32x4 acc2[4][4];
    #pragma unroll
    for (int nt = 0; nt < 4; ++nt) {
        float bb = b2[w*64 + nt*16 + l15];
        #pragma unroll
        for (int mt = 0; mt < 4; ++mt) acc2[mt][nt] = (f32x4){bb, bb, bb, bb};
    }
    #pragma unroll 4
    for (int kk = 0; kk < 16; ++kk) {
        f16x8 af[4];
        #pragma unroll
        for (int mt = 0; mt < 4; ++mt) {
            int ee = mt*16 + l15;
            af[mt] = *(const f16x8*)&h1pool[ee*520 + (((kk*4 + g) ^ ((ee>>3)&7))*8)];
        }
        #pragma unroll
        for (int nt = 0; nt < 4; ++nt) {
            f16x8 bf = *(const f16x8*)&w2T[(size_t)(w*64 + nt*16 + l15)*512 + kk*32 + g*8];
            #pragma unroll
            for (int mt = 0; mt < 4; ++mt)
                acc2[mt][nt] = __builtin_amdgcn_mfma_f32_16x16x32_f16(af[mt], bf, acc2[mt][nt], 0, 0, 0);
        }
    }
    __syncthreads();
    #pragma unroll
    for (int mt = 0; mt < 4; ++mt)
      #pragma unroll
      for (int nt = 0; nt < 4; ++nt) {
        int n = w*64 + nt*16 + l15;
        #pragma unroll
        for (int r = 0; r < 4; ++r) {
            int m = mt*16 + g*4 + r;
            h2h[m*264 + (((n>>3) ^ (m&7))*8) + (n&7)] = (_Float16)gelu_f(acc2[mt][nt][r]);
        }
      }
    __syncthreads();

    int o = w*16 + l15;
    f32x4 acc3[4];
    { float bb = b3[o];
      #pragma unroll
      for (int mt = 0; mt < 4; ++mt) acc3[mt] = (f32x4){bb, bb, bb, bb}; }
    #pragma unroll 2
    for (int kk2 = 0; kk2 < 8; ++kk2) {
        f16x8 bf = *(const f16x8*)&w3T[(size_t)o*256 + kk2*32 + g*8];
        #pragma unroll
        for (int mt = 0; mt < 4; ++mt) {
            int ee = mt*16 + l15;
            f16x8 af = *(const f16x8*)&h2h[ee*264 + (((kk2*4 + g) ^ (ee&7))*8)];
            acc3[mt] = __builtin_amdgcn_mfma_f32_16x16x32_f16(af, bf, acc3[mt], 0, 0, 0);
        }
    }

    #pragma unroll
    for (int mt = 0; mt < 4; ++mt) {
        #pragma unroll
        for (int r = 0; r < 4; ++r) {
            int ee = mt*16 + g*4 + r;
            if (ee < ne) {
                float fy = latent[(size_t)flatS[ee]*64 + o];
                kv[(size_t)(s + ee)*64 + o] = acc3[mt][r] * fy;
            }
        }
    }
}

// ---------------- projection + kv gather (unchanged) -----------------------
__global__ __launch_bounds__(256) void k_project(const int* __restrict__ baseG,
                                                 const int* __restrict__ cntG,
                                                 const float* __restrict__ kv,
                                                 const float* __restrict__ pw1,
                                                 const float* __restrict__ pb1,
                                                 const float* __restrict__ pw2,
                                                 const float* __restrict__ pb2,
                                                 float* __restrict__ outp)
{
    __shared__ float w1s[64*260];
    __shared__ float xT[64*68];
    __shared__ float w2s[256];
    __shared__ float b1s[256];
    __shared__ float red[64*4];
    int t = threadIdx.x;
    int p0 = blockIdx.x * 64;
    for (int i = t; i < 16384; i += 256) {
        int k = i >> 8, o = i & 255;
        w1s[k*260 + o] = pw1[i];
    }
    w2s[t] = pw2[t];
    b1s[t] = pb1[t];
    for (int i = t; i < 4096; i += 256) {
        int ptl = i >> 6, c = i & 63;
        int p = p0 + ptl;
        int base = baseG[p], cnt = cntG[p];
        float acc = 0.f;
        for (int j = 0; j < cnt; ++j) acc += kv[(size_t)(base + j)*64 + c];
        xT[c*68 + ptl] = acc / fmaxf((float)cnt, 1.0f);
    }
    __syncthreads();
    int pr = t & 15, oc0 = t >> 4;
    float psum[4] = {0.f, 0.f, 0.f, 0.f};
    for (int it = 0; it < 4; ++it) {
        int oc = it*16 + oc0;
        float a[4][4];
        #pragma unroll
        for (int pp = 0; pp < 4; ++pp)
            #pragma unroll
            for (int q = 0; q < 4; ++q) a[pp][q] = b1s[oc*4 + q];
        for (int i = 0; i < 64; ++i) {
            float4 xv = *(const float4*)&xT[i*68 + pr*4];
            float4 wv = *(const float4*)&w1s[i*260 + oc*4];
            #pragma unroll
            for (int q = 0; q < 4; ++q) {
                float wq = (&wv.x)[q];
                a[0][q] += xv.x*wq; a[1][q] += xv.y*wq;
                a[2][q] += xv.z*wq; a[3][q] += xv.w*wq;
            }
        }
        #pragma unroll
        for (int pp = 0; pp < 4; ++pp) {
            float s = 0.f;
            #pragma unroll
            for (int q = 0; q < 4; ++q) s += gelu_f(a[pp][q]) * w2s[oc*4 + q];
            psum[pp] += s;
        }
    }
    #pragma unroll
    for (int pp = 0; pp < 4; ++pp) {
        psum[pp] += __shfl_xor(psum[pp], 16, 64);
        psum[pp] += __shfl_xor(psum[pp], 32, 64);
    }
    int lane = t & 63, w = t >> 6;
    if (lane < 16) {
        #pragma unroll
        for (int pp = 0; pp < 4; ++pp) red[(lane*4 + pp)*4 + w] = psum[pp];
    }
    __syncthreads();
    if (t < 64)
        outp[p0 + t] = red[t*4+0] + red[t*4+1] + red[t*4+2] + red[t*4+3] + pb2[0];
}

// ---------------------------------------------------------------------------
extern "C" void kernel_launch(void* const* d_in, const int* in_sizes, int n_in,
                              void* d_out, int out_size, void* d_ws, size_t ws_size,
                              hipStream_t stream)
{
    const float* in_p = (const float*)d_in[0];
    const float* outp = (const float*)d_in[1];
    const float* f    = (const float*)d_in[2];
    const float* lw1  = (const float*)d_in[3];
    const float* lb1  = (const float*)d_in[4];
    const float* lw2  = (const float*)d_in[5];
    const float* lb2  = (const float*)d_in[6];
    const float* spw  = (const float*)d_in[7];
    const float* skw  = (const float*)d_in[8];
    const float* skb  = (const float*)d_in[9];
    const float* gw1  = (const float*)d_in[10];
    const float* gb1  = (const float*)d_in[11];
    const float* gw2  = (const float*)d_in[12];
    const float* gb2  = (const float*)d_in[13];
    const float* gw3  = (const float*)d_in[14];
    const float* gb3  = (const float*)d_in[15];
    const float* pw1  = (const float*)d_in[16];
    const float* pb1  = (const float*)d_in[17];
    const float* pw2  = (const float*)d_in[18];
    const float* pb2  = (const float*)d_in[19];

    float* ws   = (float*)d_ws;
    float* buf0 = ws;
    float* buf1 = ws + 2097152;
    float* SC   = ws + 4194304;
    float2* F1 = (float2*)SC;
    float2* Ft = (float2*)(SC + 524288);
    float2* Gt = (float2*)(SC + 786432);
    _Float16* w2T  = (_Float16*)(SC + 1048576);
    _Float16* w3T  = (_Float16*)(SC + 1114112);
    _Float16* w1p  = (_Float16*)(SC + 1122304);
    _Float16* l2hi = (_Float16*)(SC + 1124352);
    _Float16* l2lo = (_Float16*)(SC + 1132544);
    _Float16* skwH = (_Float16*)(SC + 1140736);
    _Float16* skwL = (_Float16*)(SC + 1148928);
    int*   counter = (int*)(SC + 1157120);
    int*   baseG   = (int*)(SC + 1157136);
    int*   cntG    = (int*)(SC + 1173520);
    int*   eFlat   = (int*)(SC + 1189904);
    float* eAgg    = SC + 1320976;
    float* kv      = SC + 2107408;
    float* hsk     = SC + 10496016;

    hipMemsetAsync(counter, 0, sizeof(int), stream);
    k_prep<<<784, 256, 0, stream>>>(gw2, gw3, gw1, gb1, lw2, skw, outp,
                                    w2T, w3T, w1p, l2hi, l2lo, skwH, skwL,
                                    counter, baseG, cntG, eFlat, eAgg);
    k_lift<<<512, 256, 0, stream>>>(f, in_p, lw1, lb1, l2hi, l2lo, lb2, buf0);

    k_fwd_zy<<<256, 256, 0, stream>>>(buf0, F1);
    for (int l = 0; l < 4; ++l) {
        const float* hin = (l & 1) ? buf1 : buf0;
        float* hout = (l & 1) ? buf0 : buf1;
        k_fwd_x<<<256, 256, 0, stream>>>(F1, Ft);
        k_spec_skip<<<512, 256, 0, stream>>>(Ft, spw, hin, skwH, skwL, Gt, hsk, l);
        k_inv_zy<<<256, 512, 0, stream>>>(Gt, hsk, skb, hout, buf0, F1,
                                          l, (l < 3) ? 1 : 0);
    }
    // latent = buf0 (point-major, written by k_inv_zy at l=3)

    k_gno_mlp<<<ECAP/64, 256, 0, stream>>>(counter, eFlat, eAgg,
                                           w1p, w2T, gb2, w3T, gb3, buf0, kv);
    k_project<<<256, 256, 0, stream>>>(baseG, cntG, kv, pw1, pb1, pw2, pb2,
                                       (float*)d_out);
}